// Round 1
// baseline (3859.126 us; speedup 1.0000x reference)
//
#include <hip/hip_runtime.h>
#include <hip/hip_bf16.h>

#define NEG_SLOPE 0.2f
#define EPSI 1e-5f

__device__ __forceinline__ float wred_sum(float v){
#pragma unroll
  for (int o = 32; o > 0; o >>= 1) v += __shfl_xor(v, o);
  return v;
}
__device__ __forceinline__ float wred_max(float v){
#pragma unroll
  for (int o = 32; o > 0; o >>= 1) v = fmaxf(v, __shfl_xor(v, o));
  return v;
}

// ---------------- CSR build (by dst), deterministic ----------------
__global__ __launch_bounds__(256) void k_count(const int* __restrict__ ei, int* __restrict__ deg,
                                               int E, int EP){
  int e = blockIdx.x * 256 + threadIdx.x;
  if (e >= EP) return;
  int d = (e < E) ? ei[E + e] : (e - E);
  atomicAdd(&deg[d], 1);
}

__global__ __launch_bounds__(256) void k_scan(const int* __restrict__ deg, int* __restrict__ rowptr, int n){
  __shared__ int part[256];
  int t = threadIdx.x;
  int L = (n + 255) / 256;
  int lo = t * L, hi = min(lo + L, n);
  int s = 0;
  for (int i = lo; i < hi; i++) s += deg[i];
  part[t] = s;
  __syncthreads();
  if (t == 0){
    int acc = 0;
    for (int i = 0; i < 256; i++){ int v = part[i]; part[i] = acc; acc += v; }
  }
  __syncthreads();
  int acc = part[t];
  for (int i = lo; i < hi; i++){ rowptr[i] = acc; acc += deg[i]; }
  if (t == 255) rowptr[n] = acc;
}

__global__ __launch_bounds__(256) void k_copy(const int* __restrict__ a, int* __restrict__ b, int n){
  int i = blockIdx.x * 256 + threadIdx.x;
  if (i < n) b[i] = a[i];
}

__global__ __launch_bounds__(256) void k_fill(const int* __restrict__ ei, int* __restrict__ cursor,
                                              int* __restrict__ srcn, int* __restrict__ eidv,
                                              int E, int EP){
  int e = blockIdx.x * 256 + threadIdx.x;
  if (e >= EP) return;
  int s, d;
  if (e < E){ s = ei[e]; d = ei[E + e]; } else { s = d = e - E; }
  int pos = atomicAdd(&cursor[d], 1);
  srcn[pos] = s;
  eidv[pos] = e;
}

// ---------------- tiled fp32 GEMM: C[M,Ncol] = A[M,K] @ W[K,Ncol] + bias ----------------
#define BM 64
#define BN 64
#define BK 16
__global__ __launch_bounds__(256) void k_gemm_bias(const float* __restrict__ A,
                                                   const float* __restrict__ W,
                                                   const float* __restrict__ bias,
                                                   float* __restrict__ C,
                                                   int M, int K, int Ncol){
  __shared__ float As[BM][BK + 1];
  __shared__ float Ws[BK][BN];
  int tx = threadIdx.x % 16, ty = threadIdx.x / 16;
  int row0 = blockIdx.y * BM, col0 = blockIdx.x * BN;
  float acc[4][4] = {};
  for (int k0 = 0; k0 < K; k0 += BK){
    for (int l = threadIdx.x; l < BM * BK; l += 256){
      int r = l >> 4, cc = l & 15;
      int gr = row0 + r;
      As[r][cc] = (gr < M) ? A[(size_t)gr * K + k0 + cc] : 0.f;
    }
    for (int l = threadIdx.x; l < BK * BN; l += 256){
      int r = l >> 6, cc = l & 63;
      Ws[r][cc] = W[(size_t)(k0 + r) * Ncol + col0 + cc];
    }
    __syncthreads();
#pragma unroll
    for (int kk = 0; kk < BK; kk++){
      float a[4], wv[4];
#pragma unroll
      for (int i = 0; i < 4; i++) a[i] = As[ty * 4 + i][kk];
#pragma unroll
      for (int j = 0; j < 4; j++) wv[j] = Ws[kk][tx * 4 + j];
#pragma unroll
      for (int i = 0; i < 4; i++)
#pragma unroll
        for (int j = 0; j < 4; j++) acc[i][j] += a[i] * wv[j];
    }
    __syncthreads();
  }
  for (int i = 0; i < 4; i++){
    int gr = row0 + ty * 4 + i;
    if (gr >= M) continue;
    for (int j = 0; j < 4; j++){
      int gc = col0 + tx * 4 + j;
      C[(size_t)gr * Ncol + gc] = acc[i][j] + bias[gc];
    }
  }
}

// ---------------- per-edge GATv2 logits (one wave per edge) ----------------
__global__ __launch_bounds__(256) void k_edge_logit(const float* __restrict__ xl,
                                                    const float* __restrict__ xr,
                                                    const float* __restrict__ att,
                                                    const int* __restrict__ ei,
                                                    float* __restrict__ logit,
                                                    int E, int EP, int heads, int OD){
  int wid = (blockIdx.x * 256 + threadIdx.x) >> 6;
  int lane = threadIdx.x & 63;
  if (wid >= EP) return;
  int s, d;
  if (wid < E){ s = ei[wid]; d = ei[E + wid]; } else { s = d = wid - E; }
  for (int h = 0; h < heads; h++){
    float v = xl[(size_t)s * OD + h * 64 + lane] + xr[(size_t)d * OD + h * 64 + lane];
    v = (v > 0.f) ? v : NEG_SLOPE * v;
    v *= att[h * 64 + lane];
    v = wred_sum(v);
    if (lane == 0) logit[(size_t)wid * heads + h] = v;
  }
}

// ---------------- softmax + aggregate per (node, head), one wave each ----------------
__global__ __launch_bounds__(256) void k_aggregate(const float* __restrict__ xl,
                                                   const float* __restrict__ logit,
                                                   const int* __restrict__ rowptr,
                                                   const int* __restrict__ srcn,
                                                   const int* __restrict__ eidv,
                                                   const float* __restrict__ bias,
                                                   float* __restrict__ out,
                                                   int N, int heads, int OD){
  int wid = (blockIdx.x * 256 + threadIdx.x) >> 6;
  int lane = threadIdx.x & 63;
  int node = wid / heads, h = wid - node * heads;
  if (node >= N) return;
  int e0 = rowptr[node], e1 = rowptr[node + 1];
  float m = -1e30f;
  for (int k = e0 + lane; k < e1; k += 64) m = fmaxf(m, logit[(size_t)eidv[k] * heads + h]);
  m = wred_max(m);
  float s = 0.f;
  for (int k = e0 + lane; k < e1; k += 64) s += expf(logit[(size_t)eidv[k] * heads + h] - m);
  s = wred_sum(s);
  float inv = 1.0f / s;
  float acc = 0.f;
  for (int k = e0; k < e1; k++){
    float w = expf(logit[(size_t)eidv[k] * heads + h] - m) * inv;
    acc += w * xl[(size_t)srcn[k] * OD + h * 64 + lane];
  }
  out[(size_t)node * OD + h * 64 + lane] = acc + bias[h * 64 + lane];
}

// ---------------- GraphNorm (+optional residual, +optional ELU) ----------------
__global__ __launch_bounds__(64) void k_gnorm(const float* __restrict__ t,
                                              const float* __restrict__ res,
                                              const float* __restrict__ w,
                                              const float* __restrict__ b,
                                              const float* __restrict__ ms,
                                              const int* __restrict__ ptrg,
                                              float* __restrict__ out,
                                              int OD, int do_elu){
  int g = blockIdx.x;
  int c = blockIdx.y * 64 + threadIdx.x;
  int lo = ptrg[g], hi = ptrg[g + 1];
  float cnt = (float)(hi - lo);
  float sum = 0.f;
  for (int i = lo; i < hi; i++){
    float y = t[(size_t)i * OD + c];
    if (res) y += res[(size_t)i * OD + c];
    sum += y;
  }
  float mean = sum / cnt;
  float msv = ms[c];
  float var = 0.f;
  for (int i = lo; i < hi; i++){
    float y = t[(size_t)i * OD + c];
    if (res) y += res[(size_t)i * OD + c];
    float cen = y - msv * mean;
    var += cen * cen;
  }
  var /= cnt;
  float scale = w[c] * rsqrtf(var + EPSI);
  float bb = b[c];
  for (int i = lo; i < hi; i++){
    float y = t[(size_t)i * OD + c];
    if (res) y += res[(size_t)i * OD + c];
    float o = scale * (y - msv * mean) + bb;
    if (do_elu) o = (o > 0.f) ? o : (expf(o) - 1.f);
    out[(size_t)i * OD + c] = o;
  }
}

// ---------------- extract summary rows into JK concat buffer ----------------
__global__ __launch_bounds__(64) void k_extract(const float* __restrict__ srcb,
                                                float* __restrict__ cat,
                                                const int* __restrict__ ptrg,
                                                int OD, int off, int FD){
  int g = blockIdx.x;
  int c = blockIdx.y * 64 + threadIdx.x;
  cat[(size_t)g * FD + off + c] = srcb[(size_t)ptrg[g] * OD + c];
}

// ---------------- final linear on 50 summary rows ----------------
__global__ __launch_bounds__(256) void k_final(const float* __restrict__ cat,
                                               const float* __restrict__ lin_w,
                                               const float* __restrict__ lin_b,
                                               float* __restrict__ out, int FD){
  int g = blockIdx.x;
  float s = 0.f;
  for (int c = threadIdx.x; c < FD; c += 256) s += cat[(size_t)g * FD + c] * lin_w[c];
  s = wred_sum(s);
  __shared__ float sm[4];
  if ((threadIdx.x & 63) == 0) sm[threadIdx.x >> 6] = s;
  __syncthreads();
  if (threadIdx.x == 0) out[g] = sm[0] + sm[1] + sm[2] + sm[3] + lin_b[0];
}

extern "C" void kernel_launch(void* const* d_in, const int* in_sizes, int n_in,
                              void* d_out, int out_size, void* d_ws, size_t ws_size,
                              hipStream_t stream) {
  const int TD = 768, HC = 64, H = 8;
  const float* x     = (const float*)d_in[0];
  const int*   ei    = (const int*)d_in[1];
  const int*   ptrg  = (const int*)d_in[3];
  const float* tp_w  = (const float*)d_in[4];
  const float* tp_b  = (const float*)d_in[5];
  const float* lin_w = (const float*)d_in[6];
  const float* lin_b = (const float*)d_in[7];
  const float* cw[4][6]; // wl, bl, wr, br, att, bias
  for (int l = 0; l < 4; l++)
    for (int j = 0; j < 6; j++) cw[l][j] = (const float*)d_in[8 + 6 * l + j];
  const float* nw[4][3]; // w, b, ms
  for (int l = 0; l < 4; l++)
    for (int j = 0; j < 3; j++) nw[l][j] = (const float*)d_in[32 + 3 * l + j];

  const int N  = in_sizes[0] / TD;   // 20000
  const int E  = in_sizes[1] / 2;    // 240000
  const int EP = E + N;              // 260000 (with self-loops)
  const int G  = in_sizes[3] - 1;    // 50
  const int FD = 3 * HC * H + HC;    // 1600

  char* wsp = (char*)d_ws;
  size_t off = 0;
  auto alloc = [&](size_t b) -> void* {
    void* p = wsp + off;
    off += (b + 255) & ~(size_t)255;
    return p;
  };
  float* xl    = (float*)alloc((size_t)N * 512 * 4);
  float* xr    = (float*)alloc((size_t)N * 512 * 4);  // also conv output (aliased after logits)
  float* bufP  = (float*)alloc((size_t)N * 512 * 4);
  float* bufQ  = (float*)alloc((size_t)N * 512 * 4);
  float* h0    = (float*)alloc((size_t)N * 64 * 4);   // proj out; reused for h4 post-norm
  float* logit = (float*)alloc((size_t)EP * H * 4);
  int*   rowptr= (int*)alloc((size_t)(N + 1) * 4);
  int*   cursor= (int*)alloc((size_t)N * 4);
  int*   srcn  = (int*)alloc((size_t)EP * 4);
  int*   eidv  = (int*)alloc((size_t)EP * 4);
  float* cat   = (float*)alloc((size_t)G * FD * 4);
  (void)ws_size; (void)n_in; (void)out_size;

  float* out = (float*)d_out;

  // ---- CSR build (shared by all 4 layers) ----
  hipMemsetAsync(cursor, 0, (size_t)N * 4, stream);
  int eblk = (EP + 255) / 256;
  k_count<<<eblk, 256, 0, stream>>>(ei, cursor, E, EP);
  k_scan<<<1, 256, 0, stream>>>(cursor, rowptr, N);
  k_copy<<<(N + 255) / 256, 256, 0, stream>>>(rowptr, cursor, N);
  k_fill<<<eblk, 256, 0, stream>>>(ei, cursor, srcn, eidv, E, EP);

  const int rowBlocks = (N + BM - 1) / BM;  // 313
  int ewav = (EP + 3) / 4;                  // wave-per-edge blocks

  // ---- text projection: h0 = x @ tp_w + tp_b ----
  k_gemm_bias<<<dim3(1, rowBlocks), 256, 0, stream>>>(x, tp_w, tp_b, h0, N, TD, 64);

  // ---- layer 1 (in=64, heads=8, concat) ----
  k_gemm_bias<<<dim3(8, rowBlocks), 256, 0, stream>>>(h0, cw[0][0], cw[0][1], xl, N, 64, 512);
  k_gemm_bias<<<dim3(8, rowBlocks), 256, 0, stream>>>(h0, cw[0][2], cw[0][3], xr, N, 64, 512);
  k_edge_logit<<<ewav, 256, 0, stream>>>(xl, xr, cw[0][4], ei, logit, E, EP, 8, 512);
  k_aggregate<<<(N * 8 + 3) / 4, 256, 0, stream>>>(xl, logit, rowptr, srcn, eidv, cw[0][5], xr, N, 8, 512);
  k_gnorm<<<dim3(G, 8), 64, 0, stream>>>(xr, nullptr, nw[0][0], nw[0][1], nw[0][2], ptrg, bufP, 512, 1);
  k_extract<<<dim3(G, 8), 64, 0, stream>>>(bufP, cat, ptrg, 512, 0, FD);

  // ---- layer 2 (in=512, heads=8, concat, residual) ----
  k_gemm_bias<<<dim3(8, rowBlocks), 256, 0, stream>>>(bufP, cw[1][0], cw[1][1], xl, N, 512, 512);
  k_gemm_bias<<<dim3(8, rowBlocks), 256, 0, stream>>>(bufP, cw[1][2], cw[1][3], xr, N, 512, 512);
  k_edge_logit<<<ewav, 256, 0, stream>>>(xl, xr, cw[1][4], ei, logit, E, EP, 8, 512);
  k_aggregate<<<(N * 8 + 3) / 4, 256, 0, stream>>>(xl, logit, rowptr, srcn, eidv, cw[1][5], xr, N, 8, 512);
  k_gnorm<<<dim3(G, 8), 64, 0, stream>>>(xr, bufP, nw[1][0], nw[1][1], nw[1][2], ptrg, bufQ, 512, 1);
  k_extract<<<dim3(G, 8), 64, 0, stream>>>(bufQ, cat, ptrg, 512, 512, FD);

  // ---- layer 3 (in=512, heads=8, concat, residual) ----
  k_gemm_bias<<<dim3(8, rowBlocks), 256, 0, stream>>>(bufQ, cw[2][0], cw[2][1], xl, N, 512, 512);
  k_gemm_bias<<<dim3(8, rowBlocks), 256, 0, stream>>>(bufQ, cw[2][2], cw[2][3], xr, N, 512, 512);
  k_edge_logit<<<ewav, 256, 0, stream>>>(xl, xr, cw[2][4], ei, logit, E, EP, 8, 512);
  k_aggregate<<<(N * 8 + 3) / 4, 256, 0, stream>>>(xl, logit, rowptr, srcn, eidv, cw[2][5], xr, N, 8, 512);
  k_gnorm<<<dim3(G, 8), 64, 0, stream>>>(xr, bufQ, nw[2][0], nw[2][1], nw[2][2], ptrg, bufP, 512, 1);
  k_extract<<<dim3(G, 8), 64, 0, stream>>>(bufP, cat, ptrg, 512, 1024, FD);

  // ---- layer 4 (in=512, heads=1, no concat, no residual, no elu) ----
  k_gemm_bias<<<dim3(1, rowBlocks), 256, 0, stream>>>(bufP, cw[3][0], cw[3][1], xl, N, 512, 64);
  k_gemm_bias<<<dim3(1, rowBlocks), 256, 0, stream>>>(bufP, cw[3][2], cw[3][3], xr, N, 512, 64);
  k_edge_logit<<<ewav, 256, 0, stream>>>(xl, xr, cw[3][4], ei, logit, E, EP, 1, 64);
  k_aggregate<<<(N + 3) / 4, 256, 0, stream>>>(xl, logit, rowptr, srcn, eidv, cw[3][5], xr, N, 1, 64);
  k_gnorm<<<dim3(G, 1), 64, 0, stream>>>(xr, nullptr, nw[3][0], nw[3][1], nw[3][2], ptrg, h0, 64, 0);
  k_extract<<<dim3(G, 1), 64, 0, stream>>>(h0, cat, ptrg, 64, 1536, FD);

  // ---- final linear on the 50 summary rows ----
  k_final<<<G, 256, 0, stream>>>(cat, lin_w, lin_b, out, FD);
}

// Round 2
// 2263.942 us; speedup vs baseline: 1.7046x; 1.7046x over previous
//
#include <hip/hip_runtime.h>
#include <hip/hip_bf16.h>

#define NEG_SLOPE 0.2f
#define EPSI 1e-5f

__device__ __forceinline__ float wred_sum(float v){
#pragma unroll
  for (int o = 32; o > 0; o >>= 1) v += __shfl_xor(v, o);
  return v;
}
__device__ __forceinline__ float wred_max(float v){
#pragma unroll
  for (int o = 32; o > 0; o >>= 1) v = fmaxf(v, __shfl_xor(v, o));
  return v;
}

// ---------------- CSR build (by dst), deterministic ----------------
__global__ __launch_bounds__(256) void k_count(const int* __restrict__ ei, int* __restrict__ deg,
                                               int E, int EP){
  int e = blockIdx.x * 256 + threadIdx.x;
  if (e >= EP) return;
  int d = (e < E) ? ei[E + e] : (e - E);
  atomicAdd(&deg[d], 1);
}

__global__ __launch_bounds__(256) void k_scan(const int* __restrict__ deg, int* __restrict__ rowptr, int n){
  __shared__ int part[256];
  int t = threadIdx.x;
  int L = (n + 255) / 256;
  int lo = t * L, hi = min(lo + L, n);
  int s = 0;
  for (int i = lo; i < hi; i++) s += deg[i];
  part[t] = s;
  __syncthreads();
  if (t == 0){
    int acc = 0;
    for (int i = 0; i < 256; i++){ int v = part[i]; part[i] = acc; acc += v; }
  }
  __syncthreads();
  int acc = part[t];
  for (int i = lo; i < hi; i++){ rowptr[i] = acc; acc += deg[i]; }
  if (t == 255) rowptr[n] = acc;
}

__global__ __launch_bounds__(256) void k_copy(const int* __restrict__ a, int* __restrict__ b, int n){
  int i = blockIdx.x * 256 + threadIdx.x;
  if (i < n) b[i] = a[i];
}

__global__ __launch_bounds__(256) void k_fill(const int* __restrict__ ei, int* __restrict__ cursor,
                                              int* __restrict__ srcn, int* __restrict__ eidv,
                                              int E, int EP){
  int e = blockIdx.x * 256 + threadIdx.x;
  if (e >= EP) return;
  int s, d;
  if (e < E){ s = ei[e]; d = ei[E + e]; } else { s = d = e - E; }
  int pos = atomicAdd(&cursor[d], 1);
  srcn[pos] = s;
  eidv[pos] = e;
}

// ---------------- fp32 GEMM: C[M,Ncol] = A[M,K] @ W[K,Ncol] + bias ----------------
// 128x64 tile, BK=16, 256 threads, 8x4 acc/thread, transposed-A LDS, float4 everywhere.
#define GBM 128
#define GBN 64
#define GBK 16
__global__ __launch_bounds__(256) void k_gemm2(const float* __restrict__ A,
                                               const float* __restrict__ W,
                                               const float* __restrict__ bias,
                                               float* __restrict__ C,
                                               int M, int K, int Ncol){
  __shared__ float Ast[GBK][GBM + 4];
  __shared__ float Ws[GBK][GBN];
  const int tid = threadIdx.x;
  const int tx = tid & 15;        // 16 col groups * 4 cols
  const int ty = tid >> 4;        // 16 row groups * 8 rows
  const int row0 = blockIdx.y * GBM, col0 = blockIdx.x * GBN;
  float acc[8][4] = {};

  for (int k0 = 0; k0 < K; k0 += GBK){
    // A tile: 128 rows x 16 k -> Ast[k][r] (transposed), float4 global loads
#pragma unroll
    for (int l = tid; l < 512; l += 256){
      int r = l >> 2, kq = l & 3;
      int gr = row0 + r;
      float4 v = make_float4(0.f, 0.f, 0.f, 0.f);
      if (gr < M) v = *(const float4*)&A[(size_t)gr * K + k0 + kq * 4];
      Ast[kq * 4 + 0][r] = v.x;
      Ast[kq * 4 + 1][r] = v.y;
      Ast[kq * 4 + 2][r] = v.z;
      Ast[kq * 4 + 3][r] = v.w;
    }
    // W tile: 16 x 64, one float4 per thread
    {
      int r = tid >> 4, cq = tid & 15;
      float4 v = *(const float4*)&W[(size_t)(k0 + r) * Ncol + col0 + cq * 4];
      *(float4*)&Ws[r][cq * 4] = v;
    }
    __syncthreads();
#pragma unroll
    for (int kk = 0; kk < GBK; kk++){
      float4 a0 = *(const float4*)&Ast[kk][ty * 8];
      float4 a1 = *(const float4*)&Ast[kk][ty * 8 + 4];
      float4 wv = *(const float4*)&Ws[kk][tx * 4];
      float a[8] = {a0.x, a0.y, a0.z, a0.w, a1.x, a1.y, a1.z, a1.w};
      float wb[4] = {wv.x, wv.y, wv.z, wv.w};
#pragma unroll
      for (int i = 0; i < 8; i++)
#pragma unroll
        for (int j = 0; j < 4; j++) acc[i][j] += a[i] * wb[j];
    }
    __syncthreads();
  }
  float4 bv = *(const float4*)&bias[col0 + tx * 4];
#pragma unroll
  for (int i = 0; i < 8; i++){
    int gr = row0 + ty * 8 + i;
    if (gr >= M) continue;
    float4 o;
    o.x = acc[i][0] + bv.x; o.y = acc[i][1] + bv.y;
    o.z = acc[i][2] + bv.z; o.w = acc[i][3] + bv.w;
    *(float4*)&C[(size_t)gr * Ncol + col0 + tx * 4] = o;
  }
}

// ---------------- per-edge GATv2 logits (one wave per edge) ----------------
__global__ __launch_bounds__(256) void k_edge_logit(const float* __restrict__ xl,
                                                    const float* __restrict__ xr,
                                                    const float* __restrict__ att,
                                                    const int* __restrict__ ei,
                                                    float* __restrict__ logit,
                                                    int E, int EP, int heads, int OD){
  int wid = (blockIdx.x * 256 + threadIdx.x) >> 6;
  int lane = threadIdx.x & 63;
  if (wid >= EP) return;
  int s, d;
  if (wid < E){ s = ei[wid]; d = ei[E + wid]; } else { s = d = wid - E; }
  for (int h = 0; h < heads; h++){
    float v = xl[(size_t)s * OD + h * 64 + lane] + xr[(size_t)d * OD + h * 64 + lane];
    v = (v > 0.f) ? v : NEG_SLOPE * v;
    v *= att[h * 64 + lane];
    v = wred_sum(v);
    if (lane == 0) logit[(size_t)wid * heads + h] = v;
  }
}

// ---------------- softmax + aggregate per (node, head), one wave; fused residual ----------------
__global__ __launch_bounds__(256) void k_aggregate(const float* __restrict__ xl,
                                                   const float* __restrict__ logit,
                                                   const int* __restrict__ rowptr,
                                                   const int* __restrict__ srcn,
                                                   const int* __restrict__ eidv,
                                                   const float* __restrict__ bias,
                                                   const float* __restrict__ res,
                                                   float* __restrict__ out,
                                                   int N, int heads, int OD){
  int wid = (blockIdx.x * 256 + threadIdx.x) >> 6;
  int lane = threadIdx.x & 63;
  int node = wid / heads, h = wid - node * heads;
  if (node >= N) return;
  int e0 = rowptr[node], e1 = rowptr[node + 1];
  float m = -1e30f;
  for (int k = e0 + lane; k < e1; k += 64) m = fmaxf(m, logit[(size_t)eidv[k] * heads + h]);
  m = wred_max(m);
  float s = 0.f;
  for (int k = e0 + lane; k < e1; k += 64) s += expf(logit[(size_t)eidv[k] * heads + h] - m);
  s = wred_sum(s);
  float inv = 1.0f / s;
  float acc = 0.f;
  for (int k = e0; k < e1; k++){
    float w = expf(logit[(size_t)eidv[k] * heads + h] - m) * inv;
    acc += w * xl[(size_t)srcn[k] * OD + h * 64 + lane];
  }
  size_t o = (size_t)node * OD + h * 64 + lane;
  float r_ = res ? res[o] : 0.f;
  out[o] = acc + bias[h * 64 + lane] + r_;
}

// ---------------- GraphNorm: chunked stats -> coef -> vectorized apply ----------------
#define NCHUNK 16
__global__ __launch_bounds__(256) void k_gnorm_stats(const float* __restrict__ y,
                                                     const int* __restrict__ ptrg,
                                                     float* __restrict__ psum,
                                                     float* __restrict__ psq,
                                                     int OD){
  int g = blockIdx.x, chunk = blockIdx.z;
  int lane = threadIdx.x & 63, sub = threadIdx.x >> 6;
  int c = blockIdx.y * 64 + lane;
  int lo = ptrg[g], hi = ptrg[g + 1], len = hi - lo;
  int c0 = lo + (len * chunk) / NCHUNK, c1 = lo + (len * (chunk + 1)) / NCHUNK;
  float s = 0.f, q = 0.f;
  for (int i = c0 + sub; i < c1; i += 4){
    float v = y[(size_t)i * OD + c];
    s += v; q += v * v;
  }
  __shared__ float sm[4][64], sq2[4][64];
  sm[sub][lane] = s; sq2[sub][lane] = q;
  __syncthreads();
  if (sub == 0){
    s = sm[0][lane] + sm[1][lane] + sm[2][lane] + sm[3][lane];
    q = sq2[0][lane] + sq2[1][lane] + sq2[2][lane] + sq2[3][lane];
    size_t o = (size_t)(g * NCHUNK + chunk) * OD + c;
    psum[o] = s; psq[o] = q;
  }
}

__global__ __launch_bounds__(256) void k_gnorm_coef(const float* __restrict__ psum,
                                                    const float* __restrict__ psq,
                                                    const float* __restrict__ w,
                                                    const float* __restrict__ b,
                                                    const float* __restrict__ ms,
                                                    const int* __restrict__ ptrg,
                                                    float* __restrict__ cA,
                                                    float* __restrict__ cC,
                                                    int OD){
  int g = blockIdx.x;
  int len = ptrg[g + 1] - ptrg[g];
  float inv_n = 1.f / (float)len;
  for (int c = threadIdx.x; c < OD; c += 256){
    float s = 0.f, q = 0.f;
    for (int k = 0; k < NCHUNK; k++){
      size_t o = (size_t)(g * NCHUNK + k) * OD + c;
      s += psum[o]; q += psq[o];
    }
    float mean = s * inv_n, ey2 = q * inv_n;
    float m = ms[c];
    // E[(y - m*mean)^2] = E[y^2] - mean^2 * (2m - m^2)
    float var = ey2 - mean * mean * (2.f * m - m * m);
    float inv = rsqrtf(var + EPSI);
    float A = w[c] * inv;
    cA[(size_t)g * OD + c] = A;
    cC[(size_t)g * OD + c] = b[c] - A * m * mean;
  }
}

__global__ __launch_bounds__(256) void k_gnorm_apply(const float* __restrict__ y,
                                                     const int* __restrict__ batch,
                                                     const float* __restrict__ cA,
                                                     const float* __restrict__ cC,
                                                     float* __restrict__ out,
                                                     int OD, int total4, int do_elu){
  int idx = blockIdx.x * 256 + threadIdx.x;
  if (idx >= total4) return;
  int od4 = OD >> 2;
  int node = idx / od4;
  int c = (idx - node * od4) << 2;
  int g = batch[node];
  float4 v = ((const float4*)y)[idx];
  float4 A = *(const float4*)&cA[(size_t)g * OD + c];
  float4 Cc = *(const float4*)&cC[(size_t)g * OD + c];
  float4 r;
  r.x = A.x * v.x + Cc.x;
  r.y = A.y * v.y + Cc.y;
  r.z = A.z * v.z + Cc.z;
  r.w = A.w * v.w + Cc.w;
  if (do_elu){
    r.x = r.x > 0.f ? r.x : expf(r.x) - 1.f;
    r.y = r.y > 0.f ? r.y : expf(r.y) - 1.f;
    r.z = r.z > 0.f ? r.z : expf(r.z) - 1.f;
    r.w = r.w > 0.f ? r.w : expf(r.w) - 1.f;
  }
  ((float4*)out)[idx] = r;
}

// ---------------- extract summary rows into JK concat buffer ----------------
__global__ __launch_bounds__(64) void k_extract(const float* __restrict__ srcb,
                                                float* __restrict__ cat,
                                                const int* __restrict__ ptrg,
                                                int OD, int off, int FD){
  int g = blockIdx.x;
  int c = blockIdx.y * 64 + threadIdx.x;
  cat[(size_t)g * FD + off + c] = srcb[(size_t)ptrg[g] * OD + c];
}

// ---------------- final linear on 50 summary rows ----------------
__global__ __launch_bounds__(256) void k_final(const float* __restrict__ cat,
                                               const float* __restrict__ lin_w,
                                               const float* __restrict__ lin_b,
                                               float* __restrict__ out, int FD){
  int g = blockIdx.x;
  float s = 0.f;
  for (int c = threadIdx.x; c < FD; c += 256) s += cat[(size_t)g * FD + c] * lin_w[c];
  s = wred_sum(s);
  __shared__ float sm[4];
  if ((threadIdx.x & 63) == 0) sm[threadIdx.x >> 6] = s;
  __syncthreads();
  if (threadIdx.x == 0) out[g] = sm[0] + sm[1] + sm[2] + sm[3] + lin_b[0];
}

extern "C" void kernel_launch(void* const* d_in, const int* in_sizes, int n_in,
                              void* d_out, int out_size, void* d_ws, size_t ws_size,
                              hipStream_t stream) {
  const int TD = 768, HC = 64, H = 8;
  const float* x     = (const float*)d_in[0];
  const int*   ei    = (const int*)d_in[1];
  const int*   batch = (const int*)d_in[2];
  const int*   ptrg  = (const int*)d_in[3];
  const float* tp_w  = (const float*)d_in[4];
  const float* tp_b  = (const float*)d_in[5];
  const float* lin_w = (const float*)d_in[6];
  const float* lin_b = (const float*)d_in[7];
  const float* cw[4][6]; // wl, bl, wr, br, att, bias
  for (int l = 0; l < 4; l++)
    for (int j = 0; j < 6; j++) cw[l][j] = (const float*)d_in[8 + 6 * l + j];
  const float* nw[4][3]; // w, b, ms
  for (int l = 0; l < 4; l++)
    for (int j = 0; j < 3; j++) nw[l][j] = (const float*)d_in[32 + 3 * l + j];

  const int N  = in_sizes[0] / TD;   // 20000
  const int E  = in_sizes[1] / 2;    // 240000
  const int EP = E + N;              // 260000 (with self-loops)
  const int G  = in_sizes[3] - 1;    // 50
  const int FD = 3 * HC * H + HC;    // 1600

  char* wsp = (char*)d_ws;
  size_t off = 0;
  auto alloc = [&](size_t b) -> void* {
    void* p = wsp + off;
    off += (b + 255) & ~(size_t)255;
    return p;
  };
  float* xl    = (float*)alloc((size_t)N * 512 * 4);
  float* xr    = (float*)alloc((size_t)N * 512 * 4);  // also conv output (aliased after logits)
  float* bufP  = (float*)alloc((size_t)N * 512 * 4);
  float* bufQ  = (float*)alloc((size_t)N * 512 * 4);
  float* h0    = (float*)alloc((size_t)N * 64 * 4);
  float* logit = (float*)alloc((size_t)EP * H * 4);
  int*   rowptr= (int*)alloc((size_t)(N + 1) * 4);
  int*   cursor= (int*)alloc((size_t)N * 4);
  int*   srcn  = (int*)alloc((size_t)EP * 4);
  int*   eidv  = (int*)alloc((size_t)EP * 4);
  float* cat   = (float*)alloc((size_t)G * FD * 4);
  float* psum  = (float*)alloc((size_t)G * NCHUNK * 512 * 4);
  float* psq   = (float*)alloc((size_t)G * NCHUNK * 512 * 4);
  float* cA    = (float*)alloc((size_t)G * 512 * 4);
  float* cC    = (float*)alloc((size_t)G * 512 * 4);
  (void)ws_size; (void)n_in; (void)out_size;

  float* out = (float*)d_out;

  // ---- CSR build (shared by all 4 layers) ----
  hipMemsetAsync(cursor, 0, (size_t)N * 4, stream);
  int eblk = (EP + 255) / 256;
  k_count<<<eblk, 256, 0, stream>>>(ei, cursor, E, EP);
  k_scan<<<1, 256, 0, stream>>>(cursor, rowptr, N);
  k_copy<<<(N + 255) / 256, 256, 0, stream>>>(rowptr, cursor, N);
  k_fill<<<eblk, 256, 0, stream>>>(ei, cursor, srcn, eidv, E, EP);

  const int rowBlocks = (N + GBM - 1) / GBM;  // 157
  int ewav = (EP + 3) / 4;

  // ---- text projection: h0 = x @ tp_w + tp_b ----
  k_gemm2<<<dim3(1, rowBlocks), 256, 0, stream>>>(x, tp_w, tp_b, h0, N, TD, 64);

  auto layer = [&](const float* hin, int l, int heads, int OD, const float* res,
                   float* yout, int catoff, int do_elu, int Kin){
    k_gemm2<<<dim3(OD / GBN, rowBlocks), 256, 0, stream>>>(hin, cw[l][0], cw[l][1], xl, N, Kin, OD);
    k_gemm2<<<dim3(OD / GBN, rowBlocks), 256, 0, stream>>>(hin, cw[l][2], cw[l][3], xr, N, Kin, OD);
    k_edge_logit<<<ewav, 256, 0, stream>>>(xl, xr, cw[l][4], ei, logit, E, EP, heads, OD);
    k_aggregate<<<(N * heads + 3) / 4, 256, 0, stream>>>(xl, logit, rowptr, srcn, eidv,
                                                         cw[l][5], res, xr, N, heads, OD);
    k_gnorm_stats<<<dim3(G, OD / 64, NCHUNK), 256, 0, stream>>>(xr, ptrg, psum, psq, OD);
    k_gnorm_coef<<<G, 256, 0, stream>>>(psum, psq, nw[l][0], nw[l][1], nw[l][2], ptrg, cA, cC, OD);
    int total4 = N * (OD >> 2);
    k_gnorm_apply<<<(total4 + 255) / 256, 256, 0, stream>>>(xr, batch, cA, cC, yout, OD, total4, do_elu);
    k_extract<<<dim3(G, OD / 64), 64, 0, stream>>>(yout, cat, ptrg, OD, catoff, FD);
  };

  // layer 1: in h0 (64), heads=8, no residual, ELU
  layer(h0, 0, 8, 512, nullptr, bufP, 0, 1, 64);
  // layer 2: in bufP (512), residual bufP, ELU
  layer(bufP, 1, 8, 512, bufP, bufQ, 512, 1, 512);
  // layer 3: in bufQ (512), residual bufQ, ELU
  layer(bufQ, 2, 8, 512, bufQ, bufP, 1024, 1, 512);
  // layer 4: in bufP (512), heads=1 mean->OD=64, no residual, no ELU
  layer(bufP, 3, 1, 64, nullptr, h0, 1536, 0, 512);

  // ---- final linear on the 50 summary rows ----
  k_final<<<G, 256, 0, stream>>>(cat, lin_w, lin_b, out, FD);
}

// Round 3
// 1748.060 us; speedup vs baseline: 2.2077x; 1.2951x over previous
//
#include <hip/hip_runtime.h>
#include <hip/hip_bf16.h>

#define NEG_SLOPE 0.2f
#define EPSI 1e-5f

__device__ __forceinline__ float wred_sum(float v){
#pragma unroll
  for (int o = 32; o > 0; o >>= 1) v += __shfl_xor(v, o);
  return v;
}
__device__ __forceinline__ float wred_max(float v){
#pragma unroll
  for (int o = 32; o > 0; o >>= 1) v = fmaxf(v, __shfl_xor(v, o));
  return v;
}

// monotone float<->uint encoding for atomicMax
__device__ __forceinline__ unsigned int fenc(float x){
  unsigned int u = __float_as_uint(x);
  return (u & 0x80000000u) ? ~u : (u | 0x80000000u);
}
__device__ __forceinline__ float fdec(unsigned int e){
  return __uint_as_float((e & 0x80000000u) ? (e ^ 0x80000000u) : ~e);
}

// ---------------- CSR build (by dst), deterministic ----------------
__global__ __launch_bounds__(256) void k_count(const int* __restrict__ ei, int* __restrict__ deg,
                                               int E, int EP){
  int e = blockIdx.x * 256 + threadIdx.x;
  if (e >= EP) return;
  int d = (e < E) ? ei[E + e] : (e - E);
  atomicAdd(&deg[d], 1);
}

__global__ __launch_bounds__(256) void k_scan(const int* __restrict__ deg, int* __restrict__ rowptr, int n){
  __shared__ int part[256];
  int t = threadIdx.x;
  int L = (n + 255) / 256;
  int lo = t * L, hi = min(lo + L, n);
  int s = 0;
  for (int i = lo; i < hi; i++) s += deg[i];
  part[t] = s;
  __syncthreads();
  if (t == 0){
    int acc = 0;
    for (int i = 0; i < 256; i++){ int v = part[i]; part[i] = acc; acc += v; }
  }
  __syncthreads();
  int acc = part[t];
  for (int i = lo; i < hi; i++){ rowptr[i] = acc; acc += deg[i]; }
  if (t == 255) rowptr[n] = acc;
}

__global__ __launch_bounds__(256) void k_copy(const int* __restrict__ a, int* __restrict__ b, int n){
  int i = blockIdx.x * 256 + threadIdx.x;
  if (i < n) b[i] = a[i];
}

__global__ __launch_bounds__(256) void k_fill(const int* __restrict__ ei, int* __restrict__ cursor,
                                              int* __restrict__ srcn, int* __restrict__ eidv,
                                              int E, int EP){
  int e = blockIdx.x * 256 + threadIdx.x;
  if (e >= EP) return;
  int s, d;
  if (e < E){ s = ei[e]; d = ei[E + e]; } else { s = d = e - E; }
  int pos = atomicAdd(&cursor[d], 1);
  srcn[pos] = s;
  eidv[pos] = e;
}

// ---------------- fp32 GEMM: C[M,Ncol] = A[M,K] @ W[K,Ncol] + bias ----------------
#define GBM 128
#define GBN 64
#define GBK 16
__global__ __launch_bounds__(256) void k_gemm2(const float* __restrict__ A,
                                               const float* __restrict__ W,
                                               const float* __restrict__ bias,
                                               float* __restrict__ C,
                                               int M, int K, int Ncol){
  __shared__ float Ast[GBK][GBM + 4];
  __shared__ float Ws[GBK][GBN];
  const int tid = threadIdx.x;
  const int tx = tid & 15;
  const int ty = tid >> 4;
  const int row0 = blockIdx.y * GBM, col0 = blockIdx.x * GBN;
  float acc[8][4] = {};

  for (int k0 = 0; k0 < K; k0 += GBK){
#pragma unroll
    for (int l = tid; l < 512; l += 256){
      int r = l >> 2, kq = l & 3;
      int gr = row0 + r;
      float4 v = make_float4(0.f, 0.f, 0.f, 0.f);
      if (gr < M) v = *(const float4*)&A[(size_t)gr * K + k0 + kq * 4];
      Ast[kq * 4 + 0][r] = v.x;
      Ast[kq * 4 + 1][r] = v.y;
      Ast[kq * 4 + 2][r] = v.z;
      Ast[kq * 4 + 3][r] = v.w;
    }
    {
      int r = tid >> 4, cq = tid & 15;
      float4 v = *(const float4*)&W[(size_t)(k0 + r) * Ncol + col0 + cq * 4];
      *(float4*)&Ws[r][cq * 4] = v;
    }
    __syncthreads();
#pragma unroll
    for (int kk = 0; kk < GBK; kk++){
      float4 a0 = *(const float4*)&Ast[kk][ty * 8];
      float4 a1 = *(const float4*)&Ast[kk][ty * 8 + 4];
      float4 wv = *(const float4*)&Ws[kk][tx * 4];
      float a[8] = {a0.x, a0.y, a0.z, a0.w, a1.x, a1.y, a1.z, a1.w};
      float wb[4] = {wv.x, wv.y, wv.z, wv.w};
#pragma unroll
      for (int i = 0; i < 8; i++)
#pragma unroll
        for (int j = 0; j < 4; j++) acc[i][j] += a[i] * wb[j];
    }
    __syncthreads();
  }
  float4 bv = *(const float4*)&bias[col0 + tx * 4];
#pragma unroll
  for (int i = 0; i < 8; i++){
    int gr = row0 + ty * 8 + i;
    if (gr >= M) continue;
    float4 o;
    o.x = acc[i][0] + bv.x; o.y = acc[i][1] + bv.y;
    o.z = acc[i][2] + bv.z; o.w = acc[i][3] + bv.w;
    *(float4*)&C[(size_t)gr * Ncol + col0 + tx * 4] = o;
  }
}

// ---------------- edge logits, 8 heads, OD=512: one wave/edge, float4 rows ----------------
__global__ __launch_bounds__(256) void k_edge_logit8(const float* __restrict__ xl,
                                                     const float* __restrict__ xr,
                                                     const float* __restrict__ att,
                                                     const int* __restrict__ ei,
                                                     float* __restrict__ logit,
                                                     unsigned int* __restrict__ maxb,
                                                     int E, int EP){
  int wid = (blockIdx.x * 256 + threadIdx.x) >> 6;
  int lane = threadIdx.x & 63;
  if (wid >= EP) return;
  int s, d;
  if (wid < E){ s = ei[wid]; d = ei[E + wid]; } else { s = d = wid - E; }
  const float4* pl = (const float4*)&xl[(size_t)s * 512 + lane * 8];
  const float4* pr = (const float4*)&xr[(size_t)d * 512 + lane * 8];
  const float4* pa = (const float4*)&att[lane * 8];
  float4 a0 = pl[0], a1 = pl[1];
  float4 b0 = pr[0], b1 = pr[1];
  float4 w0 = pa[0], w1 = pa[1];
  float t, sum = 0.f;
  t = a0.x + b0.x; t = t > 0.f ? t : NEG_SLOPE * t; sum += t * w0.x;
  t = a0.y + b0.y; t = t > 0.f ? t : NEG_SLOPE * t; sum += t * w0.y;
  t = a0.z + b0.z; t = t > 0.f ? t : NEG_SLOPE * t; sum += t * w0.z;
  t = a0.w + b0.w; t = t > 0.f ? t : NEG_SLOPE * t; sum += t * w0.w;
  t = a1.x + b1.x; t = t > 0.f ? t : NEG_SLOPE * t; sum += t * w1.x;
  t = a1.y + b1.y; t = t > 0.f ? t : NEG_SLOPE * t; sum += t * w1.y;
  t = a1.z + b1.z; t = t > 0.f ? t : NEG_SLOPE * t; sum += t * w1.z;
  t = a1.w + b1.w; t = t > 0.f ? t : NEG_SLOPE * t; sum += t * w1.w;
  sum += __shfl_xor(sum, 1);
  sum += __shfl_xor(sum, 2);
  sum += __shfl_xor(sum, 4);
  int h = lane >> 3;
  if ((lane & 7) == 0){
    logit[(size_t)wid * 8 + h] = sum;
    atomicMax(&maxb[(size_t)d * 8 + h], fenc(sum));
  }
}

// ---------------- aggregate, 8 heads, OD=512: one wave/node, fused softmax ----------------
__global__ __launch_bounds__(256) void k_aggregate8(const float* __restrict__ xl,
                                                    const float* __restrict__ logit,
                                                    const unsigned int* __restrict__ maxb,
                                                    const int* __restrict__ rowptr,
                                                    const int* __restrict__ srcn,
                                                    const int* __restrict__ eidv,
                                                    const float* __restrict__ bias,
                                                    const float* __restrict__ res,
                                                    float* __restrict__ out,
                                                    int N){
  int node = (blockIdx.x * 256 + threadIdx.x) >> 6;
  int lane = threadIdx.x & 63;
  if (node >= N) return;
  int h = lane >> 3;
  int e0 = rowptr[node], e1 = rowptr[node + 1];
  float m = fdec(maxb[(size_t)node * 8 + h]);
  float s = 0.f;
  float acc[8] = {};
  for (int base = e0; base < e1; base += 64){
    int cnt = min(64, e1 - base);
    int eid = 0, sn = 0;
    if (lane < cnt){
      eid = eidv[base + lane];
      sn  = srcn[base + lane];
    }
    for (int k = 0; k < cnt; k++){
      int ek = __shfl(eid, k);
      int sk = __shfl(sn, k);
      float p = __expf(logit[(size_t)ek * 8 + h] - m);
      s += p;
      const float4* px = (const float4*)&xl[(size_t)sk * 512 + lane * 8];
      float4 v0 = px[0], v1 = px[1];
      acc[0] += p * v0.x; acc[1] += p * v0.y; acc[2] += p * v0.z; acc[3] += p * v0.w;
      acc[4] += p * v1.x; acc[5] += p * v1.y; acc[6] += p * v1.z; acc[7] += p * v1.w;
    }
  }
  float inv = 1.f / s;
  size_t o = (size_t)node * 512 + lane * 8;
  float4 bv0 = *(const float4*)&bias[lane * 8];
  float4 bv1 = *(const float4*)&bias[lane * 8 + 4];
  float4 r0 = make_float4(0.f,0.f,0.f,0.f), r1 = make_float4(0.f,0.f,0.f,0.f);
  if (res){ r0 = *(const float4*)&res[o]; r1 = *(const float4*)&res[o + 4]; }
  float4 o0, o1;
  o0.x = acc[0] * inv + bv0.x + r0.x;
  o0.y = acc[1] * inv + bv0.y + r0.y;
  o0.z = acc[2] * inv + bv0.z + r0.z;
  o0.w = acc[3] * inv + bv0.w + r0.w;
  o1.x = acc[4] * inv + bv1.x + r1.x;
  o1.y = acc[5] * inv + bv1.y + r1.y;
  o1.z = acc[6] * inv + bv1.z + r1.z;
  o1.w = acc[7] * inv + bv1.w + r1.w;
  *(float4*)&out[o] = o0;
  *(float4*)&out[o + 4] = o1;
}

// ---------------- generic per-edge logits (layer 4: heads=1, OD=64) ----------------
__global__ __launch_bounds__(256) void k_edge_logit(const float* __restrict__ xl,
                                                    const float* __restrict__ xr,
                                                    const float* __restrict__ att,
                                                    const int* __restrict__ ei,
                                                    float* __restrict__ logit,
                                                    int E, int EP, int heads, int OD){
  int wid = (blockIdx.x * 256 + threadIdx.x) >> 6;
  int lane = threadIdx.x & 63;
  if (wid >= EP) return;
  int s, d;
  if (wid < E){ s = ei[wid]; d = ei[E + wid]; } else { s = d = wid - E; }
  for (int h = 0; h < heads; h++){
    float v = xl[(size_t)s * OD + h * 64 + lane] + xr[(size_t)d * OD + h * 64 + lane];
    v = (v > 0.f) ? v : NEG_SLOPE * v;
    v *= att[h * 64 + lane];
    v = wred_sum(v);
    if (lane == 0) logit[(size_t)wid * heads + h] = v;
  }
}

// ---------------- generic aggregate (layer 4: heads=1, OD=64) ----------------
__global__ __launch_bounds__(256) void k_aggregate(const float* __restrict__ xl,
                                                   const float* __restrict__ logit,
                                                   const int* __restrict__ rowptr,
                                                   const int* __restrict__ srcn,
                                                   const int* __restrict__ eidv,
                                                   const float* __restrict__ bias,
                                                   const float* __restrict__ res,
                                                   float* __restrict__ out,
                                                   int N, int heads, int OD){
  int wid = (blockIdx.x * 256 + threadIdx.x) >> 6;
  int lane = threadIdx.x & 63;
  int node = wid / heads, h = wid - node * heads;
  if (node >= N) return;
  int e0 = rowptr[node], e1 = rowptr[node + 1];
  float m = -1e30f;
  for (int k = e0 + lane; k < e1; k += 64) m = fmaxf(m, logit[(size_t)eidv[k] * heads + h]);
  m = wred_max(m);
  float s = 0.f;
  for (int k = e0 + lane; k < e1; k += 64) s += __expf(logit[(size_t)eidv[k] * heads + h] - m);
  s = wred_sum(s);
  float inv = 1.0f / s;
  float acc = 0.f;
  for (int k = e0; k < e1; k++){
    float w = __expf(logit[(size_t)eidv[k] * heads + h] - m) * inv;
    acc += w * xl[(size_t)srcn[k] * OD + h * 64 + lane];
  }
  size_t o = (size_t)node * OD + h * 64 + lane;
  float r_ = res ? res[o] : 0.f;
  out[o] = acc + bias[h * 64 + lane] + r_;
}

// ---------------- GraphNorm: chunked stats -> coef -> vectorized apply ----------------
#define NCHUNK 16
__global__ __launch_bounds__(256) void k_gnorm_stats(const float* __restrict__ y,
                                                     const int* __restrict__ ptrg,
                                                     float* __restrict__ psum,
                                                     float* __restrict__ psq,
                                                     int OD){
  int g = blockIdx.x, chunk = blockIdx.z;
  int lane = threadIdx.x & 63, sub = threadIdx.x >> 6;
  int c = blockIdx.y * 64 + lane;
  int lo = ptrg[g], hi = ptrg[g + 1], len = hi - lo;
  int c0 = lo + (len * chunk) / NCHUNK, c1 = lo + (len * (chunk + 1)) / NCHUNK;
  float s = 0.f, q = 0.f;
  for (int i = c0 + sub; i < c1; i += 4){
    float v = y[(size_t)i * OD + c];
    s += v; q += v * v;
  }
  __shared__ float sm[4][64], sq2[4][64];
  sm[sub][lane] = s; sq2[sub][lane] = q;
  __syncthreads();
  if (sub == 0){
    s = sm[0][lane] + sm[1][lane] + sm[2][lane] + sm[3][lane];
    q = sq2[0][lane] + sq2[1][lane] + sq2[2][lane] + sq2[3][lane];
    size_t o = (size_t)(g * NCHUNK + chunk) * OD + c;
    psum[o] = s; psq[o] = q;
  }
}

__global__ __launch_bounds__(256) void k_gnorm_coef(const float* __restrict__ psum,
                                                    const float* __restrict__ psq,
                                                    const float* __restrict__ w,
                                                    const float* __restrict__ b,
                                                    const float* __restrict__ ms,
                                                    const int* __restrict__ ptrg,
                                                    float* __restrict__ cA,
                                                    float* __restrict__ cC,
                                                    int OD){
  int g = blockIdx.x;
  int len = ptrg[g + 1] - ptrg[g];
  float inv_n = 1.f / (float)len;
  for (int c = threadIdx.x; c < OD; c += 256){
    float s = 0.f, q = 0.f;
    for (int k = 0; k < NCHUNK; k++){
      size_t o = (size_t)(g * NCHUNK + k) * OD + c;
      s += psum[o]; q += psq[o];
    }
    float mean = s * inv_n, ey2 = q * inv_n;
    float m = ms[c];
    float var = ey2 - mean * mean * (2.f * m - m * m);
    float inv = rsqrtf(var + EPSI);
    float A = w[c] * inv;
    cA[(size_t)g * OD + c] = A;
    cC[(size_t)g * OD + c] = b[c] - A * m * mean;
  }
}

__global__ __launch_bounds__(256) void k_gnorm_apply(const float* __restrict__ y,
                                                     const int* __restrict__ batch,
                                                     const float* __restrict__ cA,
                                                     const float* __restrict__ cC,
                                                     float* __restrict__ out,
                                                     int OD, int total4, int do_elu){
  int idx = blockIdx.x * 256 + threadIdx.x;
  if (idx >= total4) return;
  int od4 = OD >> 2;
  int node = idx / od4;
  int c = (idx - node * od4) << 2;
  int g = batch[node];
  float4 v = ((const float4*)y)[idx];
  float4 A = *(const float4*)&cA[(size_t)g * OD + c];
  float4 Cc = *(const float4*)&cC[(size_t)g * OD + c];
  float4 r;
  r.x = A.x * v.x + Cc.x;
  r.y = A.y * v.y + Cc.y;
  r.z = A.z * v.z + Cc.z;
  r.w = A.w * v.w + Cc.w;
  if (do_elu){
    r.x = r.x > 0.f ? r.x : expf(r.x) - 1.f;
    r.y = r.y > 0.f ? r.y : expf(r.y) - 1.f;
    r.z = r.z > 0.f ? r.z : expf(r.z) - 1.f;
    r.w = r.w > 0.f ? r.w : expf(r.w) - 1.f;
  }
  ((float4*)out)[idx] = r;
}

// ---------------- extract summary rows into JK concat buffer ----------------
__global__ __launch_bounds__(64) void k_extract(const float* __restrict__ srcb,
                                                float* __restrict__ cat,
                                                const int* __restrict__ ptrg,
                                                int OD, int off, int FD){
  int g = blockIdx.x;
  int c = blockIdx.y * 64 + threadIdx.x;
  cat[(size_t)g * FD + off + c] = srcb[(size_t)ptrg[g] * OD + c];
}

// ---------------- final linear on 50 summary rows ----------------
__global__ __launch_bounds__(256) void k_final(const float* __restrict__ cat,
                                               const float* __restrict__ lin_w,
                                               const float* __restrict__ lin_b,
                                               float* __restrict__ out, int FD){
  int g = blockIdx.x;
  float s = 0.f;
  for (int c = threadIdx.x; c < FD; c += 256) s += cat[(size_t)g * FD + c] * lin_w[c];
  s = wred_sum(s);
  __shared__ float sm[4];
  if ((threadIdx.x & 63) == 0) sm[threadIdx.x >> 6] = s;
  __syncthreads();
  if (threadIdx.x == 0) out[g] = sm[0] + sm[1] + sm[2] + sm[3] + lin_b[0];
}

extern "C" void kernel_launch(void* const* d_in, const int* in_sizes, int n_in,
                              void* d_out, int out_size, void* d_ws, size_t ws_size,
                              hipStream_t stream) {
  const int TD = 768, HC = 64, H = 8;
  const float* x     = (const float*)d_in[0];
  const int*   ei    = (const int*)d_in[1];
  const int*   batch = (const int*)d_in[2];
  const int*   ptrg  = (const int*)d_in[3];
  const float* tp_w  = (const float*)d_in[4];
  const float* tp_b  = (const float*)d_in[5];
  const float* lin_w = (const float*)d_in[6];
  const float* lin_b = (const float*)d_in[7];
  const float* cw[4][6];
  for (int l = 0; l < 4; l++)
    for (int j = 0; j < 6; j++) cw[l][j] = (const float*)d_in[8 + 6 * l + j];
  const float* nw[4][3];
  for (int l = 0; l < 4; l++)
    for (int j = 0; j < 3; j++) nw[l][j] = (const float*)d_in[32 + 3 * l + j];

  const int N  = in_sizes[0] / TD;   // 20000
  const int E  = in_sizes[1] / 2;    // 240000
  const int EP = E + N;              // 260000
  const int G  = in_sizes[3] - 1;    // 50
  const int FD = 3 * HC * H + HC;    // 1600

  char* wsp = (char*)d_ws;
  size_t off = 0;
  auto alloc = [&](size_t b) -> void* {
    void* p = wsp + off;
    off += (b + 255) & ~(size_t)255;
    return p;
  };
  float* xl    = (float*)alloc((size_t)N * 512 * 4);
  float* xr    = (float*)alloc((size_t)N * 512 * 4);
  float* bufP  = (float*)alloc((size_t)N * 512 * 4);
  float* bufQ  = (float*)alloc((size_t)N * 512 * 4);
  float* h0    = (float*)alloc((size_t)N * 64 * 4);
  float* logit = (float*)alloc((size_t)EP * H * 4);
  int*   rowptr= (int*)alloc((size_t)(N + 1) * 4);
  int*   cursor= (int*)alloc((size_t)N * 4);
  int*   srcn  = (int*)alloc((size_t)EP * 4);
  int*   eidv  = (int*)alloc((size_t)EP * 4);
  float* cat   = (float*)alloc((size_t)G * FD * 4);
  float* psum  = (float*)alloc((size_t)G * NCHUNK * 512 * 4);
  float* psq   = (float*)alloc((size_t)G * NCHUNK * 512 * 4);
  float* cA    = (float*)alloc((size_t)G * 512 * 4);
  float* cC    = (float*)alloc((size_t)G * 512 * 4);
  unsigned int* maxb = (unsigned int*)alloc((size_t)N * 8 * 4);
  (void)ws_size; (void)n_in; (void)out_size;

  float* out = (float*)d_out;

  // ---- CSR build ----
  hipMemsetAsync(cursor, 0, (size_t)N * 4, stream);
  int eblk = (EP + 255) / 256;
  k_count<<<eblk, 256, 0, stream>>>(ei, cursor, E, EP);
  k_scan<<<1, 256, 0, stream>>>(cursor, rowptr, N);
  k_copy<<<(N + 255) / 256, 256, 0, stream>>>(rowptr, cursor, N);
  k_fill<<<eblk, 256, 0, stream>>>(ei, cursor, srcn, eidv, E, EP);

  const int rowBlocks = (N + GBM - 1) / GBM;
  int ewav = (EP + 3) / 4;

  k_gemm2<<<dim3(1, rowBlocks), 256, 0, stream>>>(x, tp_w, tp_b, h0, N, TD, 64);

  auto layer8 = [&](const float* hin, int l, const float* res, float* yout,
                    int catoff, int Kin){
    k_gemm2<<<dim3(8, rowBlocks), 256, 0, stream>>>(hin, cw[l][0], cw[l][1], xl, N, Kin, 512);
    k_gemm2<<<dim3(8, rowBlocks), 256, 0, stream>>>(hin, cw[l][2], cw[l][3], xr, N, Kin, 512);
    hipMemsetAsync(maxb, 0, (size_t)N * 8 * 4, stream);
    k_edge_logit8<<<ewav, 256, 0, stream>>>(xl, xr, cw[l][4], ei, logit, maxb, E, EP);
    k_aggregate8<<<(N + 3) / 4, 256, 0, stream>>>(xl, logit, maxb, rowptr, srcn, eidv,
                                                  cw[l][5], res, xr, N);
    k_gnorm_stats<<<dim3(G, 8, NCHUNK), 256, 0, stream>>>(xr, ptrg, psum, psq, 512);
    k_gnorm_coef<<<G, 256, 0, stream>>>(psum, psq, nw[l][0], nw[l][1], nw[l][2], ptrg, cA, cC, 512);
    int total4 = N * 128;
    k_gnorm_apply<<<(total4 + 255) / 256, 256, 0, stream>>>(xr, batch, cA, cC, yout, 512, total4, 1);
    k_extract<<<dim3(G, 8), 64, 0, stream>>>(yout, cat, ptrg, 512, catoff, FD);
  };

  layer8(h0,   0, nullptr, bufP, 0,    64);
  layer8(bufP, 1, bufP,    bufQ, 512,  512);
  layer8(bufQ, 2, bufQ,    bufP, 1024, 512);

  // ---- layer 4 (heads=1, OD=64) ----
  k_gemm2<<<dim3(1, rowBlocks), 256, 0, stream>>>(bufP, cw[3][0], cw[3][1], xl, N, 512, 64);
  k_gemm2<<<dim3(1, rowBlocks), 256, 0, stream>>>(bufP, cw[3][2], cw[3][3], xr, N, 512, 64);
  k_edge_logit<<<ewav, 256, 0, stream>>>(xl, xr, cw[3][4], ei, logit, E, EP, 1, 64);
  k_aggregate<<<(N + 3) / 4, 256, 0, stream>>>(xl, logit, rowptr, srcn, eidv,
                                               cw[3][5], nullptr, xr, N, 1, 64);
  k_gnorm_stats<<<dim3(G, 1, NCHUNK), 256, 0, stream>>>(xr, ptrg, psum, psq, 64);
  k_gnorm_coef<<<G, 256, 0, stream>>>(psum, psq, nw[3][0], nw[3][1], nw[3][2], ptrg, cA, cC, 64);
  k_gnorm_apply<<<(N * 16 + 255) / 256, 256, 0, stream>>>(xr, batch, cA, cC, h0, 64, N * 16, 0);
  k_extract<<<dim3(G, 1), 64, 0, stream>>>(h0, cat, ptrg, 64, 1536, FD);

  k_final<<<G, 256, 0, stream>>>(cat, lin_w, lin_b, out, FD);
}

// Round 4
// 1300.532 us; speedup vs baseline: 2.9673x; 1.3441x over previous
//
#include <hip/hip_runtime.h>
#include <hip/hip_bf16.h>

#define NEG_SLOPE 0.2f
#define EPSI 1e-5f

typedef __attribute__((ext_vector_type(8))) short bf16x8;
typedef __attribute__((ext_vector_type(4))) float f32x4;

__device__ __forceinline__ float wred_sum(float v){
#pragma unroll
  for (int o = 32; o > 0; o >>= 1) v += __shfl_xor(v, o);
  return v;
}
__device__ __forceinline__ float wred_max(float v){
#pragma unroll
  for (int o = 32; o > 0; o >>= 1) v = fmaxf(v, __shfl_xor(v, o));
  return v;
}

__device__ __forceinline__ unsigned int fenc(float x){
  unsigned int u = __float_as_uint(x);
  return (u & 0x80000000u) ? ~u : (u | 0x80000000u);
}
__device__ __forceinline__ float fdec(unsigned int e){
  return __uint_as_float((e & 0x80000000u) ? (e ^ 0x80000000u) : ~e);
}

__device__ __forceinline__ unsigned short f2bf(float f){
  __hip_bfloat16 h = __float2bfloat16(f);
  return *reinterpret_cast<unsigned short*>(&h);
}

__device__ __forceinline__ void gload16(const void* g, void* l){
  __builtin_amdgcn_global_load_lds((const __attribute__((address_space(1))) unsigned int*)g,
                                   (__attribute__((address_space(3))) unsigned int*)l, 16, 0, 0);
}

// ---------------- CSR build (by dst), deterministic ----------------
__global__ __launch_bounds__(256) void k_count(const int* __restrict__ ei, int* __restrict__ deg,
                                               int E, int EP){
  int e = blockIdx.x * 256 + threadIdx.x;
  if (e >= EP) return;
  int d = (e < E) ? ei[E + e] : (e - E);
  atomicAdd(&deg[d], 1);
}

__global__ __launch_bounds__(256) void k_scan(const int* __restrict__ deg, int* __restrict__ rowptr, int n){
  __shared__ int part[256];
  int t = threadIdx.x;
  int L = (n + 255) / 256;
  int lo = t * L, hi = min(lo + L, n);
  int s = 0;
  for (int i = lo; i < hi; i++) s += deg[i];
  part[t] = s;
  __syncthreads();
  if (t == 0){
    int acc = 0;
    for (int i = 0; i < 256; i++){ int v = part[i]; part[i] = acc; acc += v; }
  }
  __syncthreads();
  int acc = part[t];
  for (int i = lo; i < hi; i++){ rowptr[i] = acc; acc += deg[i]; }
  if (t == 255) rowptr[n] = acc;
}

__global__ __launch_bounds__(256) void k_copy(const int* __restrict__ a, int* __restrict__ b, int n){
  int i = blockIdx.x * 256 + threadIdx.x;
  if (i < n) b[i] = a[i];
}

__global__ __launch_bounds__(256) void k_fill(const int* __restrict__ ei, int* __restrict__ cursor,
                                              int* __restrict__ srcn, int* __restrict__ eidv,
                                              int E, int EP){
  int e = blockIdx.x * 256 + threadIdx.x;
  if (e >= EP) return;
  int s, d;
  if (e < E){ s = ei[e]; d = ei[E + e]; } else { s = d = e - E; }
  int pos = atomicAdd(&cursor[d], 1);
  srcn[pos] = s;
  eidv[pos] = e;
}

// ---------------- fp32 GEMM (text proj + layer4, N=64) ----------------
#define GBM 128
#define GBN 64
#define GBK 16
__global__ __launch_bounds__(256) void k_gemm2(const float* __restrict__ A,
                                               const float* __restrict__ W,
                                               const float* __restrict__ bias,
                                               float* __restrict__ C,
                                               int M, int K, int Ncol){
  __shared__ float Ast[GBK][GBM + 4];
  __shared__ float Ws[GBK][GBN];
  const int tid = threadIdx.x;
  const int tx = tid & 15;
  const int ty = tid >> 4;
  const int row0 = blockIdx.y * GBM, col0 = blockIdx.x * GBN;
  float acc[8][4] = {};

  for (int k0 = 0; k0 < K; k0 += GBK){
#pragma unroll
    for (int l = tid; l < 512; l += 256){
      int r = l >> 2, kq = l & 3;
      int gr = row0 + r;
      float4 v = make_float4(0.f, 0.f, 0.f, 0.f);
      if (gr < M) v = *(const float4*)&A[(size_t)gr * K + k0 + kq * 4];
      Ast[kq * 4 + 0][r] = v.x;
      Ast[kq * 4 + 1][r] = v.y;
      Ast[kq * 4 + 2][r] = v.z;
      Ast[kq * 4 + 3][r] = v.w;
    }
    {
      int r = tid >> 4, cq = tid & 15;
      float4 v = *(const float4*)&W[(size_t)(k0 + r) * Ncol + col0 + cq * 4];
      *(float4*)&Ws[r][cq * 4] = v;
    }
    __syncthreads();
#pragma unroll
    for (int kk = 0; kk < GBK; kk++){
      float4 a0 = *(const float4*)&Ast[kk][ty * 8];
      float4 a1 = *(const float4*)&Ast[kk][ty * 8 + 4];
      float4 wv = *(const float4*)&Ws[kk][tx * 4];
      float a[8] = {a0.x, a0.y, a0.z, a0.w, a1.x, a1.y, a1.z, a1.w};
      float wb[4] = {wv.x, wv.y, wv.z, wv.w};
#pragma unroll
      for (int i = 0; i < 8; i++)
#pragma unroll
        for (int j = 0; j < 4; j++) acc[i][j] += a[i] * wb[j];
    }
    __syncthreads();
  }
  float4 bv = *(const float4*)&bias[col0 + tx * 4];
#pragma unroll
  for (int i = 0; i < 8; i++){
    int gr = row0 + ty * 8 + i;
    if (gr >= M) continue;
    float4 o;
    o.x = acc[i][0] + bv.x; o.y = acc[i][1] + bv.y;
    o.z = acc[i][2] + bv.z; o.w = acc[i][3] + bv.w;
    *(float4*)&C[(size_t)gr * Ncol + col0 + tx * 4] = o;
  }
}

// ---------------- bf16 conversions ----------------
__global__ __launch_bounds__(256) void k_cvt_act(const float* __restrict__ in,
                                                 unsigned short* __restrict__ ob, int total4){
  int i = blockIdx.x * 256 + threadIdx.x;
  if (i >= total4) return;
  float4 v = ((const float4*)in)[i];
  ushort4 o;
  o.x = f2bf(v.x); o.y = f2bf(v.y); o.z = f2bf(v.z); o.w = f2bf(v.w);
  ((ushort4*)ob)[i] = o;
}

// W[K][Ncol] fp32 -> Wt[Ncol][K] bf16 (tiled transpose)
__global__ __launch_bounds__(256) void k_cvt_wt(const float* __restrict__ W,
                                                unsigned short* __restrict__ Wt,
                                                int K, int Ncol){
  __shared__ float t[32][33];
  int bx = blockIdx.x, by = blockIdx.y;
  int tx = threadIdx.x & 31, ty = threadIdx.x >> 5;   // 32 x 8
#pragma unroll
  for (int i = 0; i < 4; i++)
    t[ty + i * 8][tx] = W[(size_t)(by * 32 + ty + i * 8) * Ncol + bx * 32 + tx];
  __syncthreads();
#pragma unroll
  for (int i = 0; i < 4; i++)
    Wt[(size_t)(bx * 32 + ty + i * 8) * K + by * 32 + tx] = f2bf(t[tx][ty + i * 8]);
}

// ---------------- bf16 MFMA GEMM: C[M,512] = A[M,K]@W[K,512] + bias ----------------
// A: bf16 row-major [M][K]; Wt: bf16 [512][K] (transposed). 128x128 tile, BK=32,
// 4 waves (2x2), each 64x64 via 4x4 fragments of mfma_f32_16x16x32_bf16.
__global__ __launch_bounds__(256) void k_gemm_mfma(const unsigned short* __restrict__ A,
                                                   const unsigned short* __restrict__ Wt,
                                                   const float* __restrict__ bias,
                                                   float* __restrict__ C,
                                                   int M, int K){
  __shared__ unsigned short As[128 * 32];
  __shared__ unsigned short Bs[128 * 32];
  const int tid = threadIdx.x;
  const int w = tid >> 6, lane = tid & 63;
  const int wr = w >> 1, wc = w & 1;
  const int row0 = blockIdx.y * 128, col0 = blockIdx.x * 128;
  const int lr = lane & 15, lk = lane >> 4;
  const int swz = (lr >> 1) & 3;

  f32x4 acc[4][4];
#pragma unroll
  for (int i = 0; i < 4; i++)
#pragma unroll
    for (int j = 0; j < 4; j++) acc[i][j] = (f32x4){0.f, 0.f, 0.f, 0.f};

  // per-thread staging geometry: 2 granule-batches of 64 for A, 2 for B
  for (int k0 = 0; k0 < K; k0 += 32){
#pragma unroll
    for (int c = 0; c < 2; c++){
      int g = w * 128 + c * 64 + lane;         // granule id 0..511
      int row = g >> 2, slot = g & 3;
      int kq = slot ^ ((row >> 1) & 3);        // inverse swizzle on global source
      int srow = row0 + row; if (srow >= M) srow = M - 1;
      gload16(&A[(size_t)srow * K + k0 + kq * 8], &As[(size_t)(w * 128 + c * 64) * 8]);
    }
#pragma unroll
    for (int c = 0; c < 2; c++){
      int g = w * 128 + c * 64 + lane;
      int col = g >> 2, slot = g & 3;
      int kq = slot ^ ((col >> 1) & 3);
      gload16(&Wt[(size_t)(col0 + col) * K + k0 + kq * 8], &Bs[(size_t)(w * 128 + c * 64) * 8]);
    }
    __syncthreads();   // drains vmcnt -> LDS tiles ready

    bf16x8 af[4], bf_[4];
#pragma unroll
    for (int mi = 0; mi < 4; mi++){
      int rl = wr * 64 + mi * 16 + lr;
      af[mi] = *(const bf16x8*)&As[(rl * 4 + (lk ^ swz)) * 8];
    }
#pragma unroll
    for (int ni = 0; ni < 4; ni++){
      int cl = wc * 64 + ni * 16 + lr;
      bf_[ni] = *(const bf16x8*)&Bs[(cl * 4 + (lk ^ swz)) * 8];
    }
#pragma unroll
    for (int mi = 0; mi < 4; mi++)
#pragma unroll
      for (int ni = 0; ni < 4; ni++)
        acc[mi][ni] = __builtin_amdgcn_mfma_f32_16x16x32_bf16(af[mi], bf_[ni], acc[mi][ni], 0, 0, 0);
    __syncthreads();   // protect LDS before next stage
  }

  // C/D layout: col = lane&15, row = (lane>>4)*4 + reg
#pragma unroll
  for (int mi = 0; mi < 4; mi++){
#pragma unroll
    for (int ni = 0; ni < 4; ni++){
      int gc = col0 + wc * 64 + ni * 16 + lr;
      float bv = bias[gc];
#pragma unroll
      for (int r = 0; r < 4; r++){
        int gr = row0 + wr * 64 + mi * 16 + lk * 4 + r;
        if (gr < M) C[(size_t)gr * 512 + gc] = acc[mi][ni][r] + bv;
      }
    }
  }
}

// ---------------- edge logits, 8 heads, OD=512 ----------------
__global__ __launch_bounds__(256) void k_edge_logit8(const float* __restrict__ xl,
                                                     const float* __restrict__ xr,
                                                     const float* __restrict__ att,
                                                     const int* __restrict__ ei,
                                                     float* __restrict__ logit,
                                                     unsigned int* __restrict__ maxb,
                                                     int E, int EP){
  int wid = (blockIdx.x * 256 + threadIdx.x) >> 6;
  int lane = threadIdx.x & 63;
  if (wid >= EP) return;
  int s, d;
  if (wid < E){ s = ei[wid]; d = ei[E + wid]; } else { s = d = wid - E; }
  const float4* pl = (const float4*)&xl[(size_t)s * 512 + lane * 8];
  const float4* pr = (const float4*)&xr[(size_t)d * 512 + lane * 8];
  const float4* pa = (const float4*)&att[lane * 8];
  float4 a0 = pl[0], a1 = pl[1];
  float4 b0 = pr[0], b1 = pr[1];
  float4 w0 = pa[0], w1 = pa[1];
  float t, sum = 0.f;
  t = a0.x + b0.x; t = t > 0.f ? t : NEG_SLOPE * t; sum += t * w0.x;
  t = a0.y + b0.y; t = t > 0.f ? t : NEG_SLOPE * t; sum += t * w0.y;
  t = a0.z + b0.z; t = t > 0.f ? t : NEG_SLOPE * t; sum += t * w0.z;
  t = a0.w + b0.w; t = t > 0.f ? t : NEG_SLOPE * t; sum += t * w0.w;
  t = a1.x + b1.x; t = t > 0.f ? t : NEG_SLOPE * t; sum += t * w1.x;
  t = a1.y + b1.y; t = t > 0.f ? t : NEG_SLOPE * t; sum += t * w1.y;
  t = a1.z + b1.z; t = t > 0.f ? t : NEG_SLOPE * t; sum += t * w1.z;
  t = a1.w + b1.w; t = t > 0.f ? t : NEG_SLOPE * t; sum += t * w1.w;
  sum += __shfl_xor(sum, 1);
  sum += __shfl_xor(sum, 2);
  sum += __shfl_xor(sum, 4);
  int h = lane >> 3;
  if ((lane & 7) == 0){
    logit[(size_t)wid * 8 + h] = sum;
    atomicMax(&maxb[(size_t)d * 8 + h], fenc(sum));
  }
}

// ---------------- aggregate, 8 heads, OD=512 ----------------
__global__ __launch_bounds__(256) void k_aggregate8(const float* __restrict__ xl,
                                                    const float* __restrict__ logit,
                                                    const unsigned int* __restrict__ maxb,
                                                    const int* __restrict__ rowptr,
                                                    const int* __restrict__ srcn,
                                                    const int* __restrict__ eidv,
                                                    const float* __restrict__ bias,
                                                    const float* __restrict__ res,
                                                    float* __restrict__ out,
                                                    int N){
  int node = (blockIdx.x * 256 + threadIdx.x) >> 6;
  int lane = threadIdx.x & 63;
  if (node >= N) return;
  int h = lane >> 3;
  int e0 = rowptr[node], e1 = rowptr[node + 1];
  float m = fdec(maxb[(size_t)node * 8 + h]);
  float s = 0.f;
  float acc[8] = {};
  for (int base = e0; base < e1; base += 64){
    int cnt = min(64, e1 - base);
    int eid = 0, sn = 0;
    if (lane < cnt){
      eid = eidv[base + lane];
      sn  = srcn[base + lane];
    }
    for (int k = 0; k < cnt; k++){
      int ek = __shfl(eid, k);
      int sk = __shfl(sn, k);
      float p = __expf(logit[(size_t)ek * 8 + h] - m);
      s += p;
      const float4* px = (const float4*)&xl[(size_t)sk * 512 + lane * 8];
      float4 v0 = px[0], v1 = px[1];
      acc[0] += p * v0.x; acc[1] += p * v0.y; acc[2] += p * v0.z; acc[3] += p * v0.w;
      acc[4] += p * v1.x; acc[5] += p * v1.y; acc[6] += p * v1.z; acc[7] += p * v1.w;
    }
  }
  float inv = 1.f / s;
  size_t o = (size_t)node * 512 + lane * 8;
  float4 bv0 = *(const float4*)&bias[lane * 8];
  float4 bv1 = *(const float4*)&bias[lane * 8 + 4];
  float4 r0 = make_float4(0.f,0.f,0.f,0.f), r1 = make_float4(0.f,0.f,0.f,0.f);
  if (res){ r0 = *(const float4*)&res[o]; r1 = *(const float4*)&res[o + 4]; }
  float4 o0, o1;
  o0.x = acc[0] * inv + bv0.x + r0.x;
  o0.y = acc[1] * inv + bv0.y + r0.y;
  o0.z = acc[2] * inv + bv0.z + r0.z;
  o0.w = acc[3] * inv + bv0.w + r0.w;
  o1.x = acc[4] * inv + bv1.x + r1.x;
  o1.y = acc[5] * inv + bv1.y + r1.y;
  o1.z = acc[6] * inv + bv1.z + r1.z;
  o1.w = acc[7] * inv + bv1.w + r1.w;
  *(float4*)&out[o] = o0;
  *(float4*)&out[o + 4] = o1;
}

// ---------------- generic per-edge logits (layer 4) ----------------
__global__ __launch_bounds__(256) void k_edge_logit(const float* __restrict__ xl,
                                                    const float* __restrict__ xr,
                                                    const float* __restrict__ att,
                                                    const int* __restrict__ ei,
                                                    float* __restrict__ logit,
                                                    int E, int EP, int heads, int OD){
  int wid = (blockIdx.x * 256 + threadIdx.x) >> 6;
  int lane = threadIdx.x & 63;
  if (wid >= EP) return;
  int s, d;
  if (wid < E){ s = ei[wid]; d = ei[E + wid]; } else { s = d = wid - E; }
  for (int h = 0; h < heads; h++){
    float v = xl[(size_t)s * OD + h * 64 + lane] + xr[(size_t)d * OD + h * 64 + lane];
    v = (v > 0.f) ? v : NEG_SLOPE * v;
    v *= att[h * 64 + lane];
    v = wred_sum(v);
    if (lane == 0) logit[(size_t)wid * heads + h] = v;
  }
}

// ---------------- generic aggregate (layer 4) ----------------
__global__ __launch_bounds__(256) void k_aggregate(const float* __restrict__ xl,
                                                   const float* __restrict__ logit,
                                                   const int* __restrict__ rowptr,
                                                   const int* __restrict__ srcn,
                                                   const int* __restrict__ eidv,
                                                   const float* __restrict__ bias,
                                                   const float* __restrict__ res,
                                                   float* __restrict__ out,
                                                   int N, int heads, int OD){
  int wid = (blockIdx.x * 256 + threadIdx.x) >> 6;
  int lane = threadIdx.x & 63;
  int node = wid / heads, h = wid - node * heads;
  if (node >= N) return;
  int e0 = rowptr[node], e1 = rowptr[node + 1];
  float m = -1e30f;
  for (int k = e0 + lane; k < e1; k += 64) m = fmaxf(m, logit[(size_t)eidv[k] * heads + h]);
  m = wred_max(m);
  float s = 0.f;
  for (int k = e0 + lane; k < e1; k += 64) s += __expf(logit[(size_t)eidv[k] * heads + h] - m);
  s = wred_sum(s);
  float inv = 1.0f / s;
  float acc = 0.f;
  for (int k = e0; k < e1; k++){
    float w = __expf(logit[(size_t)eidv[k] * heads + h] - m) * inv;
    acc += w * xl[(size_t)srcn[k] * OD + h * 64 + lane];
  }
  size_t o = (size_t)node * OD + h * 64 + lane;
  float r_ = res ? res[o] : 0.f;
  out[o] = acc + bias[h * 64 + lane] + r_;
}

// ---------------- GraphNorm: chunked stats -> coef -> vectorized apply ----------------
#define NCHUNK 16
__global__ __launch_bounds__(256) void k_gnorm_stats(const float* __restrict__ y,
                                                     const int* __restrict__ ptrg,
                                                     float* __restrict__ psum,
                                                     float* __restrict__ psq,
                                                     int OD){
  int g = blockIdx.x, chunk = blockIdx.z;
  int lane = threadIdx.x & 63, sub = threadIdx.x >> 6;
  int c = blockIdx.y * 64 + lane;
  int lo = ptrg[g], hi = ptrg[g + 1], len = hi - lo;
  int c0 = lo + (len * chunk) / NCHUNK, c1 = lo + (len * (chunk + 1)) / NCHUNK;
  float s = 0.f, q = 0.f;
  for (int i = c0 + sub; i < c1; i += 4){
    float v = y[(size_t)i * OD + c];
    s += v; q += v * v;
  }
  __shared__ float sm[4][64], sq2[4][64];
  sm[sub][lane] = s; sq2[sub][lane] = q;
  __syncthreads();
  if (sub == 0){
    s = sm[0][lane] + sm[1][lane] + sm[2][lane] + sm[3][lane];
    q = sq2[0][lane] + sq2[1][lane] + sq2[2][lane] + sq2[3][lane];
    size_t o = (size_t)(g * NCHUNK + chunk) * OD + c;
    psum[o] = s; psq[o] = q;
  }
}

__global__ __launch_bounds__(256) void k_gnorm_coef(const float* __restrict__ psum,
                                                    const float* __restrict__ psq,
                                                    const float* __restrict__ w,
                                                    const float* __restrict__ b,
                                                    const float* __restrict__ ms,
                                                    const int* __restrict__ ptrg,
                                                    float* __restrict__ cA,
                                                    float* __restrict__ cC,
                                                    int OD){
  int g = blockIdx.x;
  int len = ptrg[g + 1] - ptrg[g];
  float inv_n = 1.f / (float)len;
  for (int c = threadIdx.x; c < OD; c += 256){
    float s = 0.f, q = 0.f;
    for (int k = 0; k < NCHUNK; k++){
      size_t o = (size_t)(g * NCHUNK + k) * OD + c;
      s += psum[o]; q += psq[o];
    }
    float mean = s * inv_n, ey2 = q * inv_n;
    float m = ms[c];
    float var = ey2 - mean * mean * (2.f * m - m * m);
    float inv = rsqrtf(var + EPSI);
    float A = w[c] * inv;
    cA[(size_t)g * OD + c] = A;
    cC[(size_t)g * OD + c] = b[c] - A * m * mean;
  }
}

__global__ __launch_bounds__(256) void k_gnorm_apply(const float* __restrict__ y,
                                                     const int* __restrict__ batch,
                                                     const float* __restrict__ cA,
                                                     const float* __restrict__ cC,
                                                     float* __restrict__ out,
                                                     unsigned short* __restrict__ outb,
                                                     int OD, int total4, int do_elu){
  int idx = blockIdx.x * 256 + threadIdx.x;
  if (idx >= total4) return;
  int od4 = OD >> 2;
  int node = idx / od4;
  int c = (idx - node * od4) << 2;
  int g = batch[node];
  float4 v = ((const float4*)y)[idx];
  float4 A = *(const float4*)&cA[(size_t)g * OD + c];
  float4 Cc = *(const float4*)&cC[(size_t)g * OD + c];
  float4 r;
  r.x = A.x * v.x + Cc.x;
  r.y = A.y * v.y + Cc.y;
  r.z = A.z * v.z + Cc.z;
  r.w = A.w * v.w + Cc.w;
  if (do_elu){
    r.x = r.x > 0.f ? r.x : expf(r.x) - 1.f;
    r.y = r.y > 0.f ? r.y : expf(r.y) - 1.f;
    r.z = r.z > 0.f ? r.z : expf(r.z) - 1.f;
    r.w = r.w > 0.f ? r.w : expf(r.w) - 1.f;
  }
  ((float4*)out)[idx] = r;
  if (outb){
    ushort4 ob;
    ob.x = f2bf(r.x); ob.y = f2bf(r.y); ob.z = f2bf(r.z); ob.w = f2bf(r.w);
    ((ushort4*)outb)[idx] = ob;
  }
}

// ---------------- extract summary rows into JK concat buffer ----------------
__global__ __launch_bounds__(64) void k_extract(const float* __restrict__ srcb,
                                                float* __restrict__ cat,
                                                const int* __restrict__ ptrg,
                                                int OD, int off, int FD){
  int g = blockIdx.x;
  int c = blockIdx.y * 64 + threadIdx.x;
  cat[(size_t)g * FD + off + c] = srcb[(size_t)ptrg[g] * OD + c];
}

// ---------------- final linear on 50 summary rows ----------------
__global__ __launch_bounds__(256) void k_final(const float* __restrict__ cat,
                                               const float* __restrict__ lin_w,
                                               const float* __restrict__ lin_b,
                                               float* __restrict__ out, int FD){
  int g = blockIdx.x;
  float s = 0.f;
  for (int c = threadIdx.x; c < FD; c += 256) s += cat[(size_t)g * FD + c] * lin_w[c];
  s = wred_sum(s);
  __shared__ float sm[4];
  if ((threadIdx.x & 63) == 0) sm[threadIdx.x >> 6] = s;
  __syncthreads();
  if (threadIdx.x == 0) out[g] = sm[0] + sm[1] + sm[2] + sm[3] + lin_b[0];
}

extern "C" void kernel_launch(void* const* d_in, const int* in_sizes, int n_in,
                              void* d_out, int out_size, void* d_ws, size_t ws_size,
                              hipStream_t stream) {
  const int TD = 768, HC = 64, H = 8;
  const float* x     = (const float*)d_in[0];
  const int*   ei    = (const int*)d_in[1];
  const int*   batch = (const int*)d_in[2];
  const int*   ptrg  = (const int*)d_in[3];
  const float* tp_w  = (const float*)d_in[4];
  const float* tp_b  = (const float*)d_in[5];
  const float* lin_w = (const float*)d_in[6];
  const float* lin_b = (const float*)d_in[7];
  const float* cw[4][6];
  for (int l = 0; l < 4; l++)
    for (int j = 0; j < 6; j++) cw[l][j] = (const float*)d_in[8 + 6 * l + j];
  const float* nw[4][3];
  for (int l = 0; l < 4; l++)
    for (int j = 0; j < 3; j++) nw[l][j] = (const float*)d_in[32 + 3 * l + j];

  const int N  = in_sizes[0] / TD;   // 20000
  const int E  = in_sizes[1] / 2;    // 240000
  const int EP = E + N;              // 260000
  const int G  = in_sizes[3] - 1;    // 50
  const int FD = 3 * HC * H + HC;    // 1600

  char* wsp = (char*)d_ws;
  size_t off = 0;
  auto alloc = [&](size_t b) -> void* {
    void* p = wsp + off;
    off += (b + 255) & ~(size_t)255;
    return p;
  };
  float* xl    = (float*)alloc((size_t)N * 512 * 4);
  float* xr    = (float*)alloc((size_t)N * 512 * 4);
  float* bufP  = (float*)alloc((size_t)N * 512 * 4);
  float* bufQ  = (float*)alloc((size_t)N * 512 * 4);
  float* h0    = (float*)alloc((size_t)N * 64 * 4);
  float* logit = (float*)alloc((size_t)EP * H * 4);
  int*   rowptr= (int*)alloc((size_t)(N + 1) * 4);
  int*   cursor= (int*)alloc((size_t)N * 4);
  int*   srcn  = (int*)alloc((size_t)EP * 4);
  int*   eidv  = (int*)alloc((size_t)EP * 4);
  float* cat   = (float*)alloc((size_t)G * FD * 4);
  float* psum  = (float*)alloc((size_t)G * NCHUNK * 512 * 4);
  float* psq   = (float*)alloc((size_t)G * NCHUNK * 512 * 4);
  float* cA    = (float*)alloc((size_t)G * 512 * 4);
  float* cC    = (float*)alloc((size_t)G * 512 * 4);
  unsigned int* maxb = (unsigned int*)alloc((size_t)N * 8 * 4);
  unsigned short* actA = (unsigned short*)alloc((size_t)N * 512 * 2);  // bf16 activations
  unsigned short* actB = (unsigned short*)alloc((size_t)N * 512 * 2);
  unsigned short* h0h  = (unsigned short*)alloc((size_t)N * 64 * 2);
  unsigned short* WtL  = (unsigned short*)alloc((size_t)512 * 512 * 2);
  unsigned short* WtR  = (unsigned short*)alloc((size_t)512 * 512 * 2);
  (void)ws_size; (void)n_in; (void)out_size;

  float* out = (float*)d_out;

  // ---- CSR build ----
  hipMemsetAsync(cursor, 0, (size_t)N * 4, stream);
  int eblk = (EP + 255) / 256;
  k_count<<<eblk, 256, 0, stream>>>(ei, cursor, E, EP);
  k_scan<<<1, 256, 0, stream>>>(cursor, rowptr, N);
  k_copy<<<(N + 255) / 256, 256, 0, stream>>>(rowptr, cursor, N);
  k_fill<<<eblk, 256, 0, stream>>>(ei, cursor, srcn, eidv, E, EP);

  const int rowBlocks = (N + GBM - 1) / GBM;          // fp32 GEMM row blocks
  const int mfmaRows  = (N + 127) / 128;              // 157
  int ewav = (EP + 3) / 4;

  // ---- text projection (fp32) + bf16 cast of h0 ----
  k_gemm2<<<dim3(1, rowBlocks), 256, 0, stream>>>(x, tp_w, tp_b, h0, N, TD, 64);
  k_cvt_act<<<(N * 16 + 255) / 256, 256, 0, stream>>>(h0, h0h, N * 16);

  auto layer8 = [&](const unsigned short* actbf, int Kin, int l, const float* res,
                    float* yout, unsigned short* youtb, int catoff){
    k_cvt_wt<<<dim3(16, Kin / 32), 256, 0, stream>>>(cw[l][0], WtL, Kin, 512);
    k_cvt_wt<<<dim3(16, Kin / 32), 256, 0, stream>>>(cw[l][2], WtR, Kin, 512);
    k_gemm_mfma<<<dim3(4, mfmaRows), 256, 0, stream>>>(actbf, WtL, cw[l][1], xl, N, Kin);
    k_gemm_mfma<<<dim3(4, mfmaRows), 256, 0, stream>>>(actbf, WtR, cw[l][3], xr, N, Kin);
    hipMemsetAsync(maxb, 0, (size_t)N * 8 * 4, stream);
    k_edge_logit8<<<ewav, 256, 0, stream>>>(xl, xr, cw[l][4], ei, logit, maxb, E, EP);
    k_aggregate8<<<(N + 3) / 4, 256, 0, stream>>>(xl, logit, maxb, rowptr, srcn, eidv,
                                                  cw[l][5], res, xr, N);
    k_gnorm_stats<<<dim3(G, 8, NCHUNK), 256, 0, stream>>>(xr, ptrg, psum, psq, 512);
    k_gnorm_coef<<<G, 256, 0, stream>>>(psum, psq, nw[l][0], nw[l][1], nw[l][2], ptrg, cA, cC, 512);
    int total4 = N * 128;
    k_gnorm_apply<<<(total4 + 255) / 256, 256, 0, stream>>>(xr, batch, cA, cC, yout, youtb,
                                                            512, total4, 1);
    k_extract<<<dim3(G, 8), 64, 0, stream>>>(yout, cat, ptrg, 512, catoff, FD);
  };

  layer8(h0h,  64,  0, nullptr, bufP, actA, 0);
  layer8(actA, 512, 1, bufP,    bufQ, actB, 512);
  layer8(actB, 512, 2, bufQ,    bufP, nullptr, 1024);

  // ---- layer 4 (heads=1, OD=64, fp32 path) ----
  k_gemm2<<<dim3(1, rowBlocks), 256, 0, stream>>>(bufP, cw[3][0], cw[3][1], xl, N, 512, 64);
  k_gemm2<<<dim3(1, rowBlocks), 256, 0, stream>>>(bufP, cw[3][2], cw[3][3], xr, N, 512, 64);
  k_edge_logit<<<ewav, 256, 0, stream>>>(xl, xr, cw[3][4], ei, logit, E, EP, 1, 64);
  k_aggregate<<<(N + 3) / 4, 256, 0, stream>>>(xl, logit, rowptr, srcn, eidv,
                                               cw[3][5], nullptr, xr, N, 1, 64);
  k_gnorm_stats<<<dim3(G, 1, NCHUNK), 256, 0, stream>>>(xr, ptrg, psum, psq, 64);
  k_gnorm_coef<<<G, 256, 0, stream>>>(psum, psq, nw[3][0], nw[3][1], nw[3][2], ptrg, cA, cC, 64);
  k_gnorm_apply<<<(N * 16 + 255) / 256, 256, 0, stream>>>(xr, batch, cA, cC, h0, nullptr,
                                                          64, N * 16, 0);
  k_extract<<<dim3(G, 1), 64, 0, stream>>>(h0, cat, ptrg, 64, 1536, FD);

  k_final<<<G, 256, 0, stream>>>(cat, lin_w, lin_b, out, FD);
}

// Round 5
// 725.348 us; speedup vs baseline: 5.3204x; 1.7930x over previous
//
#include <hip/hip_runtime.h>
#include <hip/hip_bf16.h>

#define NEG_SLOPE 0.2f
#define EPSI 1e-5f

typedef __attribute__((ext_vector_type(8))) short bf16x8;
typedef __attribute__((ext_vector_type(4))) float f32x4;

__device__ __forceinline__ float wred_sum(float v){
#pragma unroll
  for (int o = 32; o > 0; o >>= 1) v += __shfl_xor(v, o);
  return v;
}

__device__ __forceinline__ unsigned short f2bf(float f){
  __hip_bfloat16 h = __float2bfloat16(f);
  return *reinterpret_cast<unsigned short*>(&h);
}
__device__ __forceinline__ float bf2f(unsigned short u){
  return __uint_as_float((unsigned int)u << 16);
}

__device__ __forceinline__ void gload16(const void* g, void* l){
  __builtin_amdgcn_global_load_lds((const __attribute__((address_space(1))) unsigned int*)g,
                                   (__attribute__((address_space(3))) unsigned int*)l, 16, 0, 0);
}

// ---------------- CSR build (by dst) ----------------
__global__ __launch_bounds__(256) void k_count(const int* __restrict__ ei, int* __restrict__ deg,
                                               int E, int EP){
  int e = blockIdx.x * 256 + threadIdx.x;
  if (e >= EP) return;
  int d = (e < E) ? ei[E + e] : (e - E);
  atomicAdd(&deg[d], 1);
}

__global__ __launch_bounds__(256) void k_scan(const int* __restrict__ deg, int* __restrict__ rowptr, int n){
  __shared__ int part[256];
  int t = threadIdx.x;
  int L = (n + 255) / 256;
  int lo = t * L, hi = min(lo + L, n);
  int s = 0;
  for (int i = lo; i < hi; i++) s += deg[i];
  part[t] = s;
  __syncthreads();
  if (t == 0){
    int acc = 0;
    for (int i = 0; i < 256; i++){ int v = part[i]; part[i] = acc; acc += v; }
  }
  __syncthreads();
  int acc = part[t];
  for (int i = lo; i < hi; i++){ rowptr[i] = acc; acc += deg[i]; }
  if (t == 255) rowptr[n] = acc;
}

__global__ __launch_bounds__(256) void k_copy(const int* __restrict__ a, int* __restrict__ b, int n){
  int i = blockIdx.x * 256 + threadIdx.x;
  if (i < n) b[i] = a[i];
}

__global__ __launch_bounds__(256) void k_fill(const int* __restrict__ ei, int* __restrict__ cursor,
                                              int* __restrict__ srcn, int E, int EP){
  int e = blockIdx.x * 256 + threadIdx.x;
  if (e >= EP) return;
  int s, d;
  if (e < E){ s = ei[e]; d = ei[E + e]; } else { s = d = e - E; }
  int pos = atomicAdd(&cursor[d], 1);
  srcn[pos] = s;
}

// ---------------- fp32 GEMM (text proj + layer4, Ncol=64) ----------------
#define GBM 128
#define GBN 64
#define GBK 16
__global__ __launch_bounds__(256) void k_gemm2(const float* __restrict__ A,
                                               const float* __restrict__ W,
                                               const float* __restrict__ bias,
                                               float* __restrict__ C,
                                               int M, int K, int Ncol){
  __shared__ float Ast[GBK][GBM + 4];
  __shared__ float Ws[GBK][GBN];
  const int tid = threadIdx.x;
  const int tx = tid & 15;
  const int ty = tid >> 4;
  const int row0 = blockIdx.y * GBM, col0 = blockIdx.x * GBN;
  float acc[8][4] = {};

  for (int k0 = 0; k0 < K; k0 += GBK){
#pragma unroll
    for (int l = tid; l < 512; l += 256){
      int r = l >> 2, kq = l & 3;
      int gr = row0 + r;
      float4 v = make_float4(0.f, 0.f, 0.f, 0.f);
      if (gr < M) v = *(const float4*)&A[(size_t)gr * K + k0 + kq * 4];
      Ast[kq * 4 + 0][r] = v.x;
      Ast[kq * 4 + 1][r] = v.y;
      Ast[kq * 4 + 2][r] = v.z;
      Ast[kq * 4 + 3][r] = v.w;
    }
    {
      int r = tid >> 4, cq = tid & 15;
      float4 v = *(const float4*)&W[(size_t)(k0 + r) * Ncol + col0 + cq * 4];
      *(float4*)&Ws[r][cq * 4] = v;
    }
    __syncthreads();
#pragma unroll
    for (int kk = 0; kk < GBK; kk++){
      float4 a0 = *(const float4*)&Ast[kk][ty * 8];
      float4 a1 = *(const float4*)&Ast[kk][ty * 8 + 4];
      float4 wv = *(const float4*)&Ws[kk][tx * 4];
      float a[8] = {a0.x, a0.y, a0.z, a0.w, a1.x, a1.y, a1.z, a1.w};
      float wb[4] = {wv.x, wv.y, wv.z, wv.w};
#pragma unroll
      for (int i = 0; i < 8; i++)
#pragma unroll
        for (int j = 0; j < 4; j++) acc[i][j] += a[i] * wb[j];
    }
    __syncthreads();
  }
  float4 bv = *(const float4*)&bias[col0 + tx * 4];
#pragma unroll
  for (int i = 0; i < 8; i++){
    int gr = row0 + ty * 8 + i;
    if (gr >= M) continue;
    float4 o;
    o.x = acc[i][0] + bv.x; o.y = acc[i][1] + bv.y;
    o.z = acc[i][2] + bv.z; o.w = acc[i][3] + bv.w;
    *(float4*)&C[(size_t)gr * Ncol + col0 + tx * 4] = o;
  }
}

// ---------------- bf16 conversions ----------------
__global__ __launch_bounds__(256) void k_cvt_act(const float* __restrict__ in,
                                                 unsigned short* __restrict__ ob, int total4){
  int i = blockIdx.x * 256 + threadIdx.x;
  if (i >= total4) return;
  float4 v = ((const float4*)in)[i];
  ushort4 o;
  o.x = f2bf(v.x); o.y = f2bf(v.y); o.z = f2bf(v.z); o.w = f2bf(v.w);
  ((ushort4*)ob)[i] = o;
}

// W[K][Ncol] fp32 -> Wt[Ncol][K] bf16 (tiled transpose)
__global__ __launch_bounds__(256) void k_cvt_wt(const float* __restrict__ W,
                                                unsigned short* __restrict__ Wt,
                                                int K, int Ncol){
  __shared__ float t[32][33];
  int bx = blockIdx.x, by = blockIdx.y;
  int tx = threadIdx.x & 31, ty = threadIdx.x >> 5;
#pragma unroll
  for (int i = 0; i < 4; i++)
    t[ty + i * 8][tx] = W[(size_t)(by * 32 + ty + i * 8) * Ncol + bx * 32 + tx];
  __syncthreads();
#pragma unroll
  for (int i = 0; i < 4; i++)
    Wt[(size_t)(bx * 32 + ty + i * 8) * K + by * 32 + tx] = f2bf(t[tx][ty + i * 8]);
}

// ---------------- bf16 MFMA GEMM: Cb[M,512] = bf16(A[M,K]@W[K,512] + bias) ----------------
__global__ __launch_bounds__(256) void k_gemm_mfma(const unsigned short* __restrict__ A,
                                                   const unsigned short* __restrict__ Wt,
                                                   const float* __restrict__ bias,
                                                   unsigned short* __restrict__ Cb,
                                                   int M, int K){
  __shared__ unsigned short As[128 * 32];
  __shared__ unsigned short Bs[128 * 32];
  const int tid = threadIdx.x;
  const int w = tid >> 6, lane = tid & 63;
  const int wr = w >> 1, wc = w & 1;
  const int row0 = blockIdx.y * 128, col0 = blockIdx.x * 128;
  const int lr = lane & 15, lk = lane >> 4;
  const int swz = (lr >> 1) & 3;

  f32x4 acc[4][4];
#pragma unroll
  for (int i = 0; i < 4; i++)
#pragma unroll
    for (int j = 0; j < 4; j++) acc[i][j] = (f32x4){0.f, 0.f, 0.f, 0.f};

  for (int k0 = 0; k0 < K; k0 += 32){
#pragma unroll
    for (int c = 0; c < 2; c++){
      int g = w * 128 + c * 64 + lane;
      int row = g >> 2, slot = g & 3;
      int kq = slot ^ ((row >> 1) & 3);
      int srow = row0 + row; if (srow >= M) srow = M - 1;
      gload16(&A[(size_t)srow * K + k0 + kq * 8], &As[(size_t)(w * 128 + c * 64) * 8]);
    }
#pragma unroll
    for (int c = 0; c < 2; c++){
      int g = w * 128 + c * 64 + lane;
      int col = g >> 2, slot = g & 3;
      int kq = slot ^ ((col >> 1) & 3);
      gload16(&Wt[(size_t)(col0 + col) * K + k0 + kq * 8], &Bs[(size_t)(w * 128 + c * 64) * 8]);
    }
    __syncthreads();

    bf16x8 af[4], bf_[4];
#pragma unroll
    for (int mi = 0; mi < 4; mi++){
      int rl = wr * 64 + mi * 16 + lr;
      af[mi] = *(const bf16x8*)&As[(rl * 4 + (lk ^ swz)) * 8];
    }
#pragma unroll
    for (int ni = 0; ni < 4; ni++){
      int cl = wc * 64 + ni * 16 + lr;
      bf_[ni] = *(const bf16x8*)&Bs[(cl * 4 + (lk ^ swz)) * 8];
    }
#pragma unroll
    for (int mi = 0; mi < 4; mi++)
#pragma unroll
      for (int ni = 0; ni < 4; ni++)
        acc[mi][ni] = __builtin_amdgcn_mfma_f32_16x16x32_bf16(af[mi], bf_[ni], acc[mi][ni], 0, 0, 0);
    __syncthreads();
  }

#pragma unroll
  for (int mi = 0; mi < 4; mi++){
#pragma unroll
    for (int ni = 0; ni < 4; ni++){
      int gc = col0 + wc * 64 + ni * 16 + lr;
      float bv = bias[gc];
#pragma unroll
      for (int r = 0; r < 4; r++){
        int gr = row0 + wr * 64 + mi * 16 + lk * 4 + r;
        if (gr < M) Cb[(size_t)gr * 512 + gc] = f2bf(acc[mi][ni][r] + bv);
      }
    }
  }
}

// ---------------- fused GATv2 edge phase, 8 heads, OD=512 (flash-style) ----------------
// one wave per node; lane owns channels lane*8..lane*8+7 (head = lane>>3)
__global__ __launch_bounds__(256) void k_gat_fused8(const unsigned short* __restrict__ xlb,
                                                    const unsigned short* __restrict__ xrb,
                                                    const float* __restrict__ att,
                                                    const int* __restrict__ rowptr,
                                                    const int* __restrict__ srcn,
                                                    const float* __restrict__ bias,
                                                    const float* __restrict__ res,
                                                    float* __restrict__ out,
                                                    int N){
  int node = (blockIdx.x * 256 + threadIdx.x) >> 6;
  int lane = threadIdx.x & 63;
  if (node >= N) return;
  float xr[8], av[8];
  {
    bf16x8 r8 = *(const bf16x8*)&xrb[(size_t)node * 512 + lane * 8];
    float4 a0 = *(const float4*)&att[lane * 8];
    float4 a1 = *(const float4*)&att[lane * 8 + 4];
#pragma unroll
    for (int j = 0; j < 8; j++) xr[j] = bf2f((unsigned short)r8[j]);
    av[0] = a0.x; av[1] = a0.y; av[2] = a0.z; av[3] = a0.w;
    av[4] = a1.x; av[5] = a1.y; av[6] = a1.z; av[7] = a1.w;
  }
  int e0 = rowptr[node], e1 = rowptr[node + 1];
  float m = -1e30f, s = 0.f;
  float acc[8] = {};
  for (int base = e0; base < e1; base += 64){
    int cnt = min(64, e1 - base);
    int sn = 0;
    if (lane < cnt) sn = srcn[base + lane];
    for (int k = 0; k < cnt; k++){
      int sk = __shfl(sn, k);
      bf16x8 v8 = *(const bf16x8*)&xlb[(size_t)sk * 512 + lane * 8];
      float v[8];
#pragma unroll
      for (int j = 0; j < 8; j++) v[j] = bf2f((unsigned short)v8[j]);
      float sum = 0.f;
#pragma unroll
      for (int j = 0; j < 8; j++){
        float t = v[j] + xr[j];
        t = t > 0.f ? t : NEG_SLOPE * t;
        sum += t * av[j];
      }
      sum += __shfl_xor(sum, 1);
      sum += __shfl_xor(sum, 2);
      sum += __shfl_xor(sum, 4);
      float mo = m;
      m = fmaxf(m, sum);
      float cs = __expf(mo - m);
      float p  = __expf(sum - m);
      s = s * cs + p;
#pragma unroll
      for (int j = 0; j < 8; j++) acc[j] = acc[j] * cs + p * v[j];
    }
  }
  float inv = 1.f / s;
  size_t o = (size_t)node * 512 + lane * 8;
  float4 bv0 = *(const float4*)&bias[lane * 8];
  float4 bv1 = *(const float4*)&bias[lane * 8 + 4];
  float4 r0 = make_float4(0.f, 0.f, 0.f, 0.f), r1 = make_float4(0.f, 0.f, 0.f, 0.f);
  if (res){ r0 = *(const float4*)&res[o]; r1 = *(const float4*)&res[o + 4]; }
  float4 o0, o1;
  o0.x = acc[0] * inv + bv0.x + r0.x;
  o0.y = acc[1] * inv + bv0.y + r0.y;
  o0.z = acc[2] * inv + bv0.z + r0.z;
  o0.w = acc[3] * inv + bv0.w + r0.w;
  o1.x = acc[4] * inv + bv1.x + r1.x;
  o1.y = acc[5] * inv + bv1.y + r1.y;
  o1.z = acc[6] * inv + bv1.z + r1.z;
  o1.w = acc[7] * inv + bv1.w + r1.w;
  *(float4*)&out[o] = o0;
  *(float4*)&out[o + 4] = o1;
}

// ---------------- fused GATv2 edge phase, 1 head, OD=64 (layer 4) ----------------
__global__ __launch_bounds__(256) void k_gat_fused1(const float* __restrict__ xl,
                                                    const float* __restrict__ xr,
                                                    const float* __restrict__ att,
                                                    const int* __restrict__ rowptr,
                                                    const int* __restrict__ srcn,
                                                    const float* __restrict__ bias,
                                                    float* __restrict__ out,
                                                    int N){
  int node = (blockIdx.x * 256 + threadIdx.x) >> 6;
  int lane = threadIdx.x & 63;
  if (node >= N) return;
  float xrv = xl == xr ? 0.f : xr[(size_t)node * 64 + lane];  // (never equal; keeps compiler honest)
  float attv = att[lane];
  int e0 = rowptr[node], e1 = rowptr[node + 1];
  float m = -1e30f, s = 0.f, acc = 0.f;
  for (int base = e0; base < e1; base += 64){
    int cnt = min(64, e1 - base);
    int sn = 0;
    if (lane < cnt) sn = srcn[base + lane];
    for (int k = 0; k < cnt; k++){
      int sk = __shfl(sn, k);
      float v = xl[(size_t)sk * 64 + lane];
      float t = v + xrv;
      t = t > 0.f ? t : NEG_SLOPE * t;
      float sum = wred_sum(t * attv);
      float mo = m;
      m = fmaxf(m, sum);
      float cs = __expf(mo - m);
      float p  = __expf(sum - m);
      s = s * cs + p;
      acc = acc * cs + p * v;
    }
  }
  out[(size_t)node * 64 + lane] = acc / s + bias[lane];
}

// ---------------- GraphNorm: chunked stats -> coef -> vectorized apply ----------------
#define NCHUNK 16
__global__ __launch_bounds__(256) void k_gnorm_stats(const float* __restrict__ y,
                                                     const int* __restrict__ ptrg,
                                                     float* __restrict__ psum,
                                                     float* __restrict__ psq,
                                                     int OD){
  int g = blockIdx.x, chunk = blockIdx.z;
  int lane = threadIdx.x & 63, sub = threadIdx.x >> 6;
  int c = blockIdx.y * 64 + lane;
  int lo = ptrg[g], hi = ptrg[g + 1], len = hi - lo;
  int c0 = lo + (len * chunk) / NCHUNK, c1 = lo + (len * (chunk + 1)) / NCHUNK;
  float s = 0.f, q = 0.f;
  for (int i = c0 + sub; i < c1; i += 4){
    float v = y[(size_t)i * OD + c];
    s += v; q += v * v;
  }
  __shared__ float sm[4][64], sq2[4][64];
  sm[sub][lane] = s; sq2[sub][lane] = q;
  __syncthreads();
  if (sub == 0){
    s = sm[0][lane] + sm[1][lane] + sm[2][lane] + sm[3][lane];
    q = sq2[0][lane] + sq2[1][lane] + sq2[2][lane] + sq2[3][lane];
    size_t o = (size_t)(g * NCHUNK + chunk) * OD + c;
    psum[o] = s; psq[o] = q;
  }
}

__global__ __launch_bounds__(256) void k_gnorm_coef(const float* __restrict__ psum,
                                                    const float* __restrict__ psq,
                                                    const float* __restrict__ w,
                                                    const float* __restrict__ b,
                                                    const float* __restrict__ ms,
                                                    const int* __restrict__ ptrg,
                                                    float* __restrict__ cA,
                                                    float* __restrict__ cC,
                                                    int OD){
  int g = blockIdx.x;
  int len = ptrg[g + 1] - ptrg[g];
  float inv_n = 1.f / (float)len;
  for (int c = threadIdx.x; c < OD; c += 256){
    float s = 0.f, q = 0.f;
    for (int k = 0; k < NCHUNK; k++){
      size_t o = (size_t)(g * NCHUNK + k) * OD + c;
      s += psum[o]; q += psq[o];
    }
    float mean = s * inv_n, ey2 = q * inv_n;
    float m = ms[c];
    float var = ey2 - mean * mean * (2.f * m - m * m);
    float inv = rsqrtf(var + EPSI);
    float A = w[c] * inv;
    cA[(size_t)g * OD + c] = A;
    cC[(size_t)g * OD + c] = b[c] - A * m * mean;
  }
}

__global__ __launch_bounds__(256) void k_gnorm_apply(const float* __restrict__ y,
                                                     const int* __restrict__ batch,
                                                     const float* __restrict__ cA,
                                                     const float* __restrict__ cC,
                                                     float* __restrict__ out,
                                                     unsigned short* __restrict__ outb,
                                                     int OD, int total4, int do_elu){
  int idx = blockIdx.x * 256 + threadIdx.x;
  if (idx >= total4) return;
  int od4 = OD >> 2;
  int node = idx / od4;
  int c = (idx - node * od4) << 2;
  int g = batch[node];
  float4 v = ((const float4*)y)[idx];
  float4 A = *(const float4*)&cA[(size_t)g * OD + c];
  float4 Cc = *(const float4*)&cC[(size_t)g * OD + c];
  float4 r;
  r.x = A.x * v.x + Cc.x;
  r.y = A.y * v.y + Cc.y;
  r.z = A.z * v.z + Cc.z;
  r.w = A.w * v.w + Cc.w;
  if (do_elu){
    r.x = r.x > 0.f ? r.x : expf(r.x) - 1.f;
    r.y = r.y > 0.f ? r.y : expf(r.y) - 1.f;
    r.z = r.z > 0.f ? r.z : expf(r.z) - 1.f;
    r.w = r.w > 0.f ? r.w : expf(r.w) - 1.f;
  }
  ((float4*)out)[idx] = r;
  if (outb){
    ushort4 ob;
    ob.x = f2bf(r.x); ob.y = f2bf(r.y); ob.z = f2bf(r.z); ob.w = f2bf(r.w);
    ((ushort4*)outb)[idx] = ob;
  }
}

// ---------------- extract summary rows into JK concat buffer ----------------
__global__ __launch_bounds__(64) void k_extract(const float* __restrict__ srcb,
                                                float* __restrict__ cat,
                                                const int* __restrict__ ptrg,
                                                int OD, int off, int FD){
  int g = blockIdx.x;
  int c = blockIdx.y * 64 + threadIdx.x;
  cat[(size_t)g * FD + off + c] = srcb[(size_t)ptrg[g] * OD + c];
}

// ---------------- final linear on 50 summary rows ----------------
__global__ __launch_bounds__(256) void k_final(const float* __restrict__ cat,
                                               const float* __restrict__ lin_w,
                                               const float* __restrict__ lin_b,
                                               float* __restrict__ out, int FD){
  int g = blockIdx.x;
  float s = 0.f;
  for (int c = threadIdx.x; c < FD; c += 256) s += cat[(size_t)g * FD + c] * lin_w[c];
  s = wred_sum(s);
  __shared__ float sm[4];
  if ((threadIdx.x & 63) == 0) sm[threadIdx.x >> 6] = s;
  __syncthreads();
  if (threadIdx.x == 0) out[g] = sm[0] + sm[1] + sm[2] + sm[3] + lin_b[0];
}

extern "C" void kernel_launch(void* const* d_in, const int* in_sizes, int n_in,
                              void* d_out, int out_size, void* d_ws, size_t ws_size,
                              hipStream_t stream) {
  const int TD = 768, HC = 64, H = 8;
  const float* x     = (const float*)d_in[0];
  const int*   ei    = (const int*)d_in[1];
  const int*   batch = (const int*)d_in[2];
  const int*   ptrg  = (const int*)d_in[3];
  const float* tp_w  = (const float*)d_in[4];
  const float* tp_b  = (const float*)d_in[5];
  const float* lin_w = (const float*)d_in[6];
  const float* lin_b = (const float*)d_in[7];
  const float* cw[4][6];
  for (int l = 0; l < 4; l++)
    for (int j = 0; j < 6; j++) cw[l][j] = (const float*)d_in[8 + 6 * l + j];
  const float* nw[4][3];
  for (int l = 0; l < 4; l++)
    for (int j = 0; j < 3; j++) nw[l][j] = (const float*)d_in[32 + 3 * l + j];

  const int N  = in_sizes[0] / TD;   // 20000
  const int E  = in_sizes[1] / 2;    // 240000
  const int EP = E + N;              // 260000
  const int G  = in_sizes[3] - 1;    // 50
  const int FD = 3 * HC * H + HC;    // 1600

  char* wsp = (char*)d_ws;
  size_t off = 0;
  auto alloc = [&](size_t b) -> void* {
    void* p = wsp + off;
    off += (b + 255) & ~(size_t)255;
    return p;
  };
  float* tmpF  = (float*)alloc((size_t)N * 512 * 4);   // fused output / layer4 scratch
  float* bufP  = (float*)alloc((size_t)N * 512 * 4);
  float* bufQ  = (float*)alloc((size_t)N * 512 * 4);
  unsigned short* xlb = (unsigned short*)alloc((size_t)N * 512 * 2);
  unsigned short* xrb = (unsigned short*)alloc((size_t)N * 512 * 2);
  unsigned short* actA = (unsigned short*)alloc((size_t)N * 512 * 2);
  unsigned short* actB = (unsigned short*)alloc((size_t)N * 512 * 2);
  float* h0    = (float*)alloc((size_t)N * 64 * 4);
  unsigned short* h0h = (unsigned short*)alloc((size_t)N * 64 * 2);
  int*   rowptr= (int*)alloc((size_t)(N + 1) * 4);
  int*   cursor= (int*)alloc((size_t)N * 4);
  int*   srcn  = (int*)alloc((size_t)EP * 4);
  float* cat   = (float*)alloc((size_t)G * FD * 4);
  float* psum  = (float*)alloc((size_t)G * NCHUNK * 512 * 4);
  float* psq   = (float*)alloc((size_t)G * NCHUNK * 512 * 4);
  float* cA    = (float*)alloc((size_t)G * 512 * 4);
  float* cC    = (float*)alloc((size_t)G * 512 * 4);
  unsigned short* WtL = (unsigned short*)alloc((size_t)512 * 512 * 2);
  unsigned short* WtR = (unsigned short*)alloc((size_t)512 * 512 * 2);
  (void)ws_size; (void)n_in; (void)out_size;

  float* out = (float*)d_out;

  // layer-4 fp32 scratch carved from tmpF (used only after layers 1-3 done with it per-step)
  float* xl4  = tmpF;                 // N*64
  float* xr4  = tmpF + (size_t)N * 64;
  float* agg4 = tmpF + (size_t)N * 128;

  // ---- CSR build ----
  hipMemsetAsync(cursor, 0, (size_t)N * 4, stream);
  int eblk = (EP + 255) / 256;
  k_count<<<eblk, 256, 0, stream>>>(ei, cursor, E, EP);
  k_scan<<<1, 256, 0, stream>>>(cursor, rowptr, N);
  k_copy<<<(N + 255) / 256, 256, 0, stream>>>(rowptr, cursor, N);
  k_fill<<<eblk, 256, 0, stream>>>(ei, cursor, srcn, E, EP);

  const int rowBlocks = (N + GBM - 1) / GBM;
  const int mfmaRows  = (N + 127) / 128;
  const int nodeBlocks = (N + 3) / 4;

  // ---- text projection (fp32) + bf16 cast ----
  k_gemm2<<<dim3(1, rowBlocks), 256, 0, stream>>>(x, tp_w, tp_b, h0, N, TD, 64);
  k_cvt_act<<<(N * 16 + 255) / 256, 256, 0, stream>>>(h0, h0h, N * 16);

  auto layer8 = [&](const unsigned short* actbf, int Kin, int l, const float* res,
                    float* yout, unsigned short* youtb, int catoff){
    k_cvt_wt<<<dim3(16, Kin / 32), 256, 0, stream>>>(cw[l][0], WtL, Kin, 512);
    k_cvt_wt<<<dim3(16, Kin / 32), 256, 0, stream>>>(cw[l][2], WtR, Kin, 512);
    k_gemm_mfma<<<dim3(4, mfmaRows), 256, 0, stream>>>(actbf, WtL, cw[l][1], xlb, N, Kin);
    k_gemm_mfma<<<dim3(4, mfmaRows), 256, 0, stream>>>(actbf, WtR, cw[l][3], xrb, N, Kin);
    k_gat_fused8<<<nodeBlocks, 256, 0, stream>>>(xlb, xrb, cw[l][4], rowptr, srcn,
                                                 cw[l][5], res, tmpF, N);
    k_gnorm_stats<<<dim3(G, 8, NCHUNK), 256, 0, stream>>>(tmpF, ptrg, psum, psq, 512);
    k_gnorm_coef<<<G, 256, 0, stream>>>(psum, psq, nw[l][0], nw[l][1], nw[l][2], ptrg, cA, cC, 512);
    int total4 = N * 128;
    k_gnorm_apply<<<(total4 + 255) / 256, 256, 0, stream>>>(tmpF, batch, cA, cC, yout, youtb,
                                                            512, total4, 1);
    k_extract<<<dim3(G, 8), 64, 0, stream>>>(yout, cat, ptrg, 512, catoff, FD);
  };

  layer8(h0h,  64,  0, nullptr, bufP, actA, 0);
  layer8(actA, 512, 1, bufP,    bufQ, actB, 512);
  layer8(actB, 512, 2, bufQ,    bufP, nullptr, 1024);

  // ---- layer 4 (heads=1, OD=64, fp32 path) ----
  k_gemm2<<<dim3(1, rowBlocks), 256, 0, stream>>>(bufP, cw[3][0], cw[3][1], xl4, N, 512, 64);
  k_gemm2<<<dim3(1, rowBlocks), 256, 0, stream>>>(bufP, cw[3][2], cw[3][3], xr4, N, 512, 64);
  k_gat_fused1<<<nodeBlocks, 256, 0, stream>>>(xl4, xr4, cw[3][4], rowptr, srcn,
                                               cw[3][5], agg4, N);
  k_gnorm_stats<<<dim3(G, 1, NCHUNK), 256, 0, stream>>>(agg4, ptrg, psum, psq, 64);
  k_gnorm_coef<<<G, 256, 0, stream>>>(psum, psq, nw[3][0], nw[3][1], nw[3][2], ptrg, cA, cC, 64);
  k_gnorm_apply<<<(N * 16 + 255) / 256, 256, 0, stream>>>(agg4, batch, cA, cC, h0, nullptr,
                                                          64, N * 16, 0);
  k_extract<<<dim3(G, 1), 64, 0, stream>>>(h0, cat, ptrg, 64, 1536, FD);

  k_final<<<G, 256, 0, stream>>>(cat, lin_w, lin_b, out, FD);
}

// Round 6
// 586.232 us; speedup vs baseline: 6.5829x; 1.2373x over previous
//
#include <hip/hip_runtime.h>
#include <hip/hip_bf16.h>

#define NEG_SLOPE 0.2f
#define EPSI 1e-5f

typedef __attribute__((ext_vector_type(8))) short bf16x8;
typedef __attribute__((ext_vector_type(4))) float f32x4;

__device__ __forceinline__ float wred_sum(float v){
#pragma unroll
  for (int o = 32; o > 0; o >>= 1) v += __shfl_xor(v, o);
  return v;
}

__device__ __forceinline__ unsigned short f2bf(float f){
  __hip_bfloat16 h = __float2bfloat16(f);
  return *reinterpret_cast<unsigned short*>(&h);
}
__device__ __forceinline__ float bf2f(unsigned short u){
  return __uint_as_float((unsigned int)u << 16);
}

__device__ __forceinline__ void gload16(const void* g, void* l){
  __builtin_amdgcn_global_load_lds((const __attribute__((address_space(1))) unsigned int*)g,
                                   (__attribute__((address_space(3))) unsigned int*)l, 16, 0, 0);
}

// ---------------- CSR build (by dst) ----------------
__global__ __launch_bounds__(256) void k_count(const int* __restrict__ ei, int* __restrict__ deg,
                                               int E, int EP){
  int e = blockIdx.x * 256 + threadIdx.x;
  if (e >= EP) return;
  int d = (e < E) ? ei[E + e] : (e - E);
  atomicAdd(&deg[d], 1);
}

__global__ __launch_bounds__(256) void k_scan(const int* __restrict__ deg, int* __restrict__ rowptr, int n){
  __shared__ int part[256];
  int t = threadIdx.x;
  int L = (n + 255) / 256;
  int lo = t * L, hi = min(lo + L, n);
  int s = 0;
  for (int i = lo; i < hi; i++) s += deg[i];
  part[t] = s;
  __syncthreads();
  if (t == 0){
    int acc = 0;
    for (int i = 0; i < 256; i++){ int v = part[i]; part[i] = acc; acc += v; }
  }
  __syncthreads();
  int acc = part[t];
  for (int i = lo; i < hi; i++){ rowptr[i] = acc; acc += deg[i]; }
  if (t == 255) rowptr[n] = acc;
}

__global__ __launch_bounds__(256) void k_copy(const int* __restrict__ a, int* __restrict__ b, int n){
  int i = blockIdx.x * 256 + threadIdx.x;
  if (i < n) b[i] = a[i];
}

__global__ __launch_bounds__(256) void k_fill(const int* __restrict__ ei, int* __restrict__ cursor,
                                              int* __restrict__ srcn, int E, int EP){
  int e = blockIdx.x * 256 + threadIdx.x;
  if (e >= EP) return;
  int s, d;
  if (e < E){ s = ei[e]; d = ei[E + e]; } else { s = d = e - E; }
  int pos = atomicAdd(&cursor[d], 1);
  srcn[pos] = s;
}

// ---------------- bf16 conversions ----------------
__global__ __launch_bounds__(256) void k_cvt_act(const float* __restrict__ in,
                                                 unsigned short* __restrict__ ob, int total4){
  int i = blockIdx.x * 256 + threadIdx.x;
  if (i >= total4) return;
  float4 v = ((const float4*)in)[i];
  ushort4 o;
  o.x = f2bf(v.x); o.y = f2bf(v.y); o.z = f2bf(v.z); o.w = f2bf(v.w);
  ((ushort4*)ob)[i] = o;
}

// W[K][Ncol] fp32 -> Wt[Ncol][K] bf16 (tiled transpose)
__global__ __launch_bounds__(256) void k_cvt_wt(const float* __restrict__ W,
                                                unsigned short* __restrict__ Wt,
                                                int K, int Ncol){
  __shared__ float t[32][33];
  int bx = blockIdx.x, by = blockIdx.y;
  int tx = threadIdx.x & 31, ty = threadIdx.x >> 5;
#pragma unroll
  for (int i = 0; i < 4; i++)
    t[ty + i * 8][tx] = W[(size_t)(by * 32 + ty + i * 8) * Ncol + bx * 32 + tx];
  __syncthreads();
#pragma unroll
  for (int i = 0; i < 4; i++)
    Wt[(size_t)(bx * 32 + ty + i * 8) * K + by * 32 + tx] = f2bf(t[tx][ty + i * 8]);
}

__global__ __launch_bounds__(64) void k_cat2(const float* __restrict__ a,
                                             const float* __restrict__ b,
                                             float* __restrict__ o){
  int i = threadIdx.x;
  o[i] = a[i];
  o[64 + i] = b[i];
}

// ---------------- bf16 MFMA GEMM: Cb[M,Ncol] = bf16(A[M,K]@W[K,*] + bias) ----------------
// A: bf16 [M][K]; Wt: bf16 [cols][K] transposed. Tile 128 x BN, BK=32, 4 waves (2x2).
template<int BN>
__global__ __launch_bounds__(256) void k_gemm_mfma_t(const unsigned short* __restrict__ A,
                                                     const unsigned short* __restrict__ Wt,
                                                     const float* __restrict__ bias,
                                                     unsigned short* __restrict__ Cb,
                                                     int M, int K, int Ncol){
  constexpr int NF = BN / 32;      // col fragments per wave
  __shared__ unsigned short As[128 * 32];
  __shared__ unsigned short Bs[BN * 32];
  const int tid = threadIdx.x;
  const int w = tid >> 6, lane = tid & 63;
  const int wr = w >> 1, wc = w & 1;
  const int row0 = blockIdx.y * 128, col0 = blockIdx.x * BN;
  const int lr = lane & 15, lk = lane >> 4;
  const int swz = (lr >> 1) & 3;

  f32x4 acc[4][NF];
#pragma unroll
  for (int i = 0; i < 4; i++)
#pragma unroll
    for (int j = 0; j < NF; j++) acc[i][j] = (f32x4){0.f, 0.f, 0.f, 0.f};

  for (int k0 = 0; k0 < K; k0 += 32){
#pragma unroll
    for (int c = 0; c < 2; c++){
      int g = w * 128 + c * 64 + lane;       // A granule 0..511
      int row = g >> 2, slot = g & 3;
      int kq = slot ^ ((row >> 1) & 3);
      int srow = row0 + row; if (srow >= M) srow = M - 1;
      gload16(&A[(size_t)srow * K + k0 + kq * 8], &As[(size_t)(w * 128 + c * 64) * 8]);
    }
#pragma unroll
    for (int c = 0; c < BN / 64; c++){
      int g = w * BN + c * 64 + lane;        // B granule 0..BN*4-1
      int col = g >> 2, slot = g & 3;
      int kq = slot ^ ((col >> 1) & 3);
      gload16(&Wt[(size_t)(col0 + col) * K + k0 + kq * 8], &Bs[(size_t)(w * BN + c * 64) * 8]);
    }
    __syncthreads();

    bf16x8 af[4], bf_[NF];
#pragma unroll
    for (int mi = 0; mi < 4; mi++){
      int rl = wr * 64 + mi * 16 + lr;
      af[mi] = *(const bf16x8*)&As[(rl * 4 + (lk ^ swz)) * 8];
    }
#pragma unroll
    for (int ni = 0; ni < NF; ni++){
      int cl = wc * (BN / 2) + ni * 16 + lr;
      bf_[ni] = *(const bf16x8*)&Bs[(cl * 4 + (lk ^ swz)) * 8];
    }
#pragma unroll
    for (int mi = 0; mi < 4; mi++)
#pragma unroll
      for (int ni = 0; ni < NF; ni++)
        acc[mi][ni] = __builtin_amdgcn_mfma_f32_16x16x32_bf16(af[mi], bf_[ni], acc[mi][ni], 0, 0, 0);
    __syncthreads();
  }

#pragma unroll
  for (int mi = 0; mi < 4; mi++){
#pragma unroll
    for (int ni = 0; ni < NF; ni++){
      int gc = col0 + wc * (BN / 2) + ni * 16 + lr;
      float bv = bias[gc];
#pragma unroll
      for (int r = 0; r < 4; r++){
        int gr = row0 + wr * 64 + mi * 16 + lk * 4 + r;
        if (gr < M) Cb[(size_t)gr * Ncol + gc] = f2bf(acc[mi][ni][r] + bv);
      }
    }
  }
}

// ---------------- fused GATv2 edge phase, 8 heads, OD=512 (flash-style) ----------------
__global__ __launch_bounds__(256) void k_gat_fused8(const unsigned short* __restrict__ xlb,
                                                    const unsigned short* __restrict__ xrb,
                                                    const float* __restrict__ att,
                                                    const int* __restrict__ rowptr,
                                                    const int* __restrict__ srcn,
                                                    const float* __restrict__ bias,
                                                    const float* __restrict__ res,
                                                    float* __restrict__ out,
                                                    int N){
  int node = (blockIdx.x * 256 + threadIdx.x) >> 6;
  int lane = threadIdx.x & 63;
  if (node >= N) return;
  float xr[8], av[8];
  {
    bf16x8 r8 = *(const bf16x8*)&xrb[(size_t)node * 512 + lane * 8];
    float4 a0 = *(const float4*)&att[lane * 8];
    float4 a1 = *(const float4*)&att[lane * 8 + 4];
#pragma unroll
    for (int j = 0; j < 8; j++) xr[j] = bf2f((unsigned short)r8[j]);
    av[0] = a0.x; av[1] = a0.y; av[2] = a0.z; av[3] = a0.w;
    av[4] = a1.x; av[5] = a1.y; av[6] = a1.z; av[7] = a1.w;
  }
  int e0 = rowptr[node], e1 = rowptr[node + 1];
  float m = -1e30f, s = 0.f;
  float acc[8] = {};
  for (int base = e0; base < e1; base += 64){
    int cnt = min(64, e1 - base);
    int sn = 0;
    if (lane < cnt) sn = srcn[base + lane];
    for (int k = 0; k < cnt; k++){
      int sk = __shfl(sn, k);
      bf16x8 v8 = *(const bf16x8*)&xlb[(size_t)sk * 512 + lane * 8];
      float v[8];
#pragma unroll
      for (int j = 0; j < 8; j++) v[j] = bf2f((unsigned short)v8[j]);
      float sum = 0.f;
#pragma unroll
      for (int j = 0; j < 8; j++){
        float t = v[j] + xr[j];
        t = t > 0.f ? t : NEG_SLOPE * t;
        sum += t * av[j];
      }
      sum += __shfl_xor(sum, 1);
      sum += __shfl_xor(sum, 2);
      sum += __shfl_xor(sum, 4);
      float mo = m;
      m = fmaxf(m, sum);
      float cs = __expf(mo - m);
      float p  = __expf(sum - m);
      s = s * cs + p;
#pragma unroll
      for (int j = 0; j < 8; j++) acc[j] = acc[j] * cs + p * v[j];
    }
  }
  float inv = 1.f / s;
  size_t o = (size_t)node * 512 + lane * 8;
  float4 bv0 = *(const float4*)&bias[lane * 8];
  float4 bv1 = *(const float4*)&bias[lane * 8 + 4];
  float4 r0 = make_float4(0.f, 0.f, 0.f, 0.f), r1 = make_float4(0.f, 0.f, 0.f, 0.f);
  if (res){ r0 = *(const float4*)&res[o]; r1 = *(const float4*)&res[o + 4]; }
  float4 o0, o1;
  o0.x = acc[0] * inv + bv0.x + r0.x;
  o0.y = acc[1] * inv + bv0.y + r0.y;
  o0.z = acc[2] * inv + bv0.z + r0.z;
  o0.w = acc[3] * inv + bv0.w + r0.w;
  o1.x = acc[4] * inv + bv1.x + r1.x;
  o1.y = acc[5] * inv + bv1.y + r1.y;
  o1.z = acc[6] * inv + bv1.z + r1.z;
  o1.w = acc[7] * inv + bv1.w + r1.w;
  *(float4*)&out[o] = o0;
  *(float4*)&out[o + 4] = o1;
}

// ---------------- fused GATv2 edge phase, 1 head, OD=64 (layer 4, combined bf16 xl|xr) ----------------
__global__ __launch_bounds__(256) void k_gat_fused1(const unsigned short* __restrict__ xlr,
                                                    const float* __restrict__ att,
                                                    const int* __restrict__ rowptr,
                                                    const int* __restrict__ srcn,
                                                    const float* __restrict__ bias,
                                                    float* __restrict__ out,
                                                    int N){
  int node = (blockIdx.x * 256 + threadIdx.x) >> 6;
  int lane = threadIdx.x & 63;
  if (node >= N) return;
  float xrv = bf2f(xlr[(size_t)node * 128 + 64 + lane]);
  float attv = att[lane];
  int e0 = rowptr[node], e1 = rowptr[node + 1];
  float m = -1e30f, s = 0.f, acc = 0.f;
  for (int base = e0; base < e1; base += 64){
    int cnt = min(64, e1 - base);
    int sn = 0;
    if (lane < cnt) sn = srcn[base + lane];
    for (int k = 0; k < cnt; k++){
      int sk = __shfl(sn, k);
      float v = bf2f(xlr[(size_t)sk * 128 + lane]);
      float t = v + xrv;
      t = t > 0.f ? t : NEG_SLOPE * t;
      float sum = wred_sum(t * attv);
      float mo = m;
      m = fmaxf(m, sum);
      float cs = __expf(mo - m);
      float p  = __expf(sum - m);
      s = s * cs + p;
      acc = acc * cs + p * v;
    }
  }
  out[(size_t)node * 64 + lane] = acc / s + bias[lane];
}

// ---------------- GraphNorm: chunked stats -> coef -> vectorized apply ----------------
#define NCHUNK 16
__global__ __launch_bounds__(256) void k_gnorm_stats(const float* __restrict__ y,
                                                     const int* __restrict__ ptrg,
                                                     float* __restrict__ psum,
                                                     float* __restrict__ psq,
                                                     int OD){
  int g = blockIdx.x, chunk = blockIdx.z;
  int lane = threadIdx.x & 63, sub = threadIdx.x >> 6;
  int c = blockIdx.y * 64 + lane;
  int lo = ptrg[g], hi = ptrg[g + 1], len = hi - lo;
  int c0 = lo + (len * chunk) / NCHUNK, c1 = lo + (len * (chunk + 1)) / NCHUNK;
  float s = 0.f, q = 0.f;
  for (int i = c0 + sub; i < c1; i += 4){
    float v = y[(size_t)i * OD + c];
    s += v; q += v * v;
  }
  __shared__ float sm[4][64], sq2[4][64];
  sm[sub][lane] = s; sq2[sub][lane] = q;
  __syncthreads();
  if (sub == 0){
    s = sm[0][lane] + sm[1][lane] + sm[2][lane] + sm[3][lane];
    q = sq2[0][lane] + sq2[1][lane] + sq2[2][lane] + sq2[3][lane];
    size_t o = (size_t)(g * NCHUNK + chunk) * OD + c;
    psum[o] = s; psq[o] = q;
  }
}

__global__ __launch_bounds__(256) void k_gnorm_coef(const float* __restrict__ psum,
                                                    const float* __restrict__ psq,
                                                    const float* __restrict__ w,
                                                    const float* __restrict__ b,
                                                    const float* __restrict__ ms,
                                                    const int* __restrict__ ptrg,
                                                    float* __restrict__ cA,
                                                    float* __restrict__ cC,
                                                    int OD){
  int g = blockIdx.x;
  int len = ptrg[g + 1] - ptrg[g];
  float inv_n = 1.f / (float)len;
  for (int c = threadIdx.x; c < OD; c += 256){
    float s = 0.f, q = 0.f;
    for (int k = 0; k < NCHUNK; k++){
      size_t o = (size_t)(g * NCHUNK + k) * OD + c;
      s += psum[o]; q += psq[o];
    }
    float mean = s * inv_n, ey2 = q * inv_n;
    float m = ms[c];
    float var = ey2 - mean * mean * (2.f * m - m * m);
    float inv = rsqrtf(var + EPSI);
    float A = w[c] * inv;
    cA[(size_t)g * OD + c] = A;
    cC[(size_t)g * OD + c] = b[c] - A * m * mean;
  }
}

__global__ __launch_bounds__(256) void k_gnorm_apply(const float* __restrict__ y,
                                                     const int* __restrict__ batch,
                                                     const float* __restrict__ cA,
                                                     const float* __restrict__ cC,
                                                     float* __restrict__ out,
                                                     unsigned short* __restrict__ outb,
                                                     int OD, int total4, int do_elu){
  int idx = blockIdx.x * 256 + threadIdx.x;
  if (idx >= total4) return;
  int od4 = OD >> 2;
  int node = idx / od4;
  int c = (idx - node * od4) << 2;
  int g = batch[node];
  float4 v = ((const float4*)y)[idx];
  float4 A = *(const float4*)&cA[(size_t)g * OD + c];
  float4 Cc = *(const float4*)&cC[(size_t)g * OD + c];
  float4 r;
  r.x = A.x * v.x + Cc.x;
  r.y = A.y * v.y + Cc.y;
  r.z = A.z * v.z + Cc.z;
  r.w = A.w * v.w + Cc.w;
  if (do_elu){
    r.x = r.x > 0.f ? r.x : expf(r.x) - 1.f;
    r.y = r.y > 0.f ? r.y : expf(r.y) - 1.f;
    r.z = r.z > 0.f ? r.z : expf(r.z) - 1.f;
    r.w = r.w > 0.f ? r.w : expf(r.w) - 1.f;
  }
  ((float4*)out)[idx] = r;
  if (outb){
    ushort4 ob;
    ob.x = f2bf(r.x); ob.y = f2bf(r.y); ob.z = f2bf(r.z); ob.w = f2bf(r.w);
    ((ushort4*)outb)[idx] = ob;
  }
}

// ---------------- extract summary rows into JK concat buffer ----------------
__global__ __launch_bounds__(64) void k_extract(const float* __restrict__ srcb,
                                                float* __restrict__ cat,
                                                const int* __restrict__ ptrg,
                                                int OD, int off, int FD){
  int g = blockIdx.x;
  int c = blockIdx.y * 64 + threadIdx.x;
  cat[(size_t)g * FD + off + c] = srcb[(size_t)ptrg[g] * OD + c];
}

// ---------------- final linear on 50 summary rows ----------------
__global__ __launch_bounds__(256) void k_final(const float* __restrict__ cat,
                                               const float* __restrict__ lin_w,
                                               const float* __restrict__ lin_b,
                                               float* __restrict__ out, int FD){
  int g = blockIdx.x;
  float s = 0.f;
  for (int c = threadIdx.x; c < FD; c += 256) s += cat[(size_t)g * FD + c] * lin_w[c];
  s = wred_sum(s);
  __shared__ float sm[4];
  if ((threadIdx.x & 63) == 0) sm[threadIdx.x >> 6] = s;
  __syncthreads();
  if (threadIdx.x == 0) out[g] = sm[0] + sm[1] + sm[2] + sm[3] + lin_b[0];
}

extern "C" void kernel_launch(void* const* d_in, const int* in_sizes, int n_in,
                              void* d_out, int out_size, void* d_ws, size_t ws_size,
                              hipStream_t stream) {
  const int TD = 768, HC = 64, H = 8;
  const float* x     = (const float*)d_in[0];
  const int*   ei    = (const int*)d_in[1];
  const int*   batch = (const int*)d_in[2];
  const int*   ptrg  = (const int*)d_in[3];
  const float* tp_w  = (const float*)d_in[4];
  const float* tp_b  = (const float*)d_in[5];
  const float* lin_w = (const float*)d_in[6];
  const float* lin_b = (const float*)d_in[7];
  const float* cw[4][6];
  for (int l = 0; l < 4; l++)
    for (int j = 0; j < 6; j++) cw[l][j] = (const float*)d_in[8 + 6 * l + j];
  const float* nw[4][3];
  for (int l = 0; l < 4; l++)
    for (int j = 0; j < 3; j++) nw[l][j] = (const float*)d_in[32 + 3 * l + j];

  const int N  = in_sizes[0] / TD;   // 20000
  const int E  = in_sizes[1] / 2;    // 240000
  const int EP = E + N;              // 260000
  const int G  = in_sizes[3] - 1;    // 50
  const int FD = 3 * HC * H + HC;    // 1600

  char* wsp = (char*)d_ws;
  size_t off = 0;
  auto alloc = [&](size_t b) -> void* {
    void* p = wsp + off;
    off += (b + 255) & ~(size_t)255;
    return p;
  };
  float* tmpF  = (float*)alloc((size_t)N * 512 * 4);   // fused output / layer4 scratch
  float* bufP  = (float*)alloc((size_t)N * 512 * 4);
  float* bufQ  = (float*)alloc((size_t)N * 512 * 4);
  unsigned short* xlb = (unsigned short*)alloc((size_t)N * 512 * 2);  // also aliases xbf + xlr4b
  unsigned short* xrb = (unsigned short*)alloc((size_t)N * 512 * 2);  // contiguous after xlb
  unsigned short* actA = (unsigned short*)alloc((size_t)N * 512 * 2);
  unsigned short* actB = (unsigned short*)alloc((size_t)N * 512 * 2);
  unsigned short* h0h = (unsigned short*)alloc((size_t)N * 64 * 2);
  int*   rowptr= (int*)alloc((size_t)(N + 1) * 4);
  int*   cursor= (int*)alloc((size_t)N * 4);
  int*   srcn  = (int*)alloc((size_t)EP * 4);
  float* cat   = (float*)alloc((size_t)G * FD * 4);
  float* psum  = (float*)alloc((size_t)G * NCHUNK * 512 * 4);
  float* psq   = (float*)alloc((size_t)G * NCHUNK * 512 * 4);
  float* cA    = (float*)alloc((size_t)G * 512 * 4);
  float* cC    = (float*)alloc((size_t)G * 512 * 4);
  unsigned short* WtL = (unsigned short*)alloc((size_t)512 * 512 * 2);
  unsigned short* WtR = (unsigned short*)alloc((size_t)512 * 512 * 2);
  unsigned short* WtTP = (unsigned short*)alloc((size_t)64 * 768 * 2);
  unsigned short* Wt4  = (unsigned short*)alloc((size_t)128 * 512 * 2);
  float* cbias4 = (float*)alloc(128 * 4);
  (void)ws_size; (void)n_in; (void)out_size;

  float* out = (float*)d_out;

  // aliases (lifetimes disjoint):
  unsigned short* xbf   = xlb;              // bf16 x [N,768] spans xlb+xrb (dead before layer1 GEMMs)
  unsigned short* xlr4b = xlb;              // layer4 combined [N,128] bf16
  float* agg4 = tmpF;                       // layer4 aggregate [N,64]
  float* out4 = tmpF + (size_t)N * 64;      // layer4 post-norm [N,64]

  // ---- CSR build ----
  hipMemsetAsync(cursor, 0, (size_t)N * 4, stream);
  int eblk = (EP + 255) / 256;
  k_count<<<eblk, 256, 0, stream>>>(ei, cursor, E, EP);
  k_scan<<<1, 256, 0, stream>>>(cursor, rowptr, N);
  k_copy<<<(N + 255) / 256, 256, 0, stream>>>(rowptr, cursor, N);
  k_fill<<<eblk, 256, 0, stream>>>(ei, cursor, srcn, E, EP);

  const int mfmaRows = (N + 127) / 128;     // 157
  const int nodeBlocks = (N + 3) / 4;

  // ---- text projection: bf16 MFMA ----
  k_cvt_act<<<(N * TD / 4 + 255) / 256, 256, 0, stream>>>(x, xbf, N * TD / 4);
  k_cvt_wt<<<dim3(2, TD / 32), 256, 0, stream>>>(tp_w, WtTP, TD, 64);
  k_gemm_mfma_t<64><<<dim3(1, mfmaRows), 256, 0, stream>>>(xbf, WtTP, tp_b, h0h, N, TD, 64);

  auto layer8 = [&](const unsigned short* actbf, int Kin, int l, const float* res,
                    float* yout, unsigned short* youtb, int catoff){
    k_cvt_wt<<<dim3(16, Kin / 32), 256, 0, stream>>>(cw[l][0], WtL, Kin, 512);
    k_cvt_wt<<<dim3(16, Kin / 32), 256, 0, stream>>>(cw[l][2], WtR, Kin, 512);
    k_gemm_mfma_t<128><<<dim3(4, mfmaRows), 256, 0, stream>>>(actbf, WtL, cw[l][1], xlb, N, Kin, 512);
    k_gemm_mfma_t<128><<<dim3(4, mfmaRows), 256, 0, stream>>>(actbf, WtR, cw[l][3], xrb, N, Kin, 512);
    k_gat_fused8<<<nodeBlocks, 256, 0, stream>>>(xlb, xrb, cw[l][4], rowptr, srcn,
                                                 cw[l][5], res, tmpF, N);
    k_gnorm_stats<<<dim3(G, 8, NCHUNK), 256, 0, stream>>>(tmpF, ptrg, psum, psq, 512);
    k_gnorm_coef<<<G, 256, 0, stream>>>(psum, psq, nw[l][0], nw[l][1], nw[l][2], ptrg, cA, cC, 512);
    int total4 = N * 128;
    k_gnorm_apply<<<(total4 + 255) / 256, 256, 0, stream>>>(tmpF, batch, cA, cC, yout, youtb,
                                                            512, total4, 1);
    k_extract<<<dim3(G, 8), 64, 0, stream>>>(yout, cat, ptrg, 512, catoff, FD);
  };

  layer8(h0h,  64,  0, nullptr, bufP, actA, 0);
  layer8(actA, 512, 1, bufP,    bufQ, actB, 512);
  layer8(actB, 512, 2, bufQ,    bufP, actA, 1024);   // actA reborn as layer4 bf16 input

  // ---- layer 4: combined xl|xr MFMA (Ncol=128) + fused edge + gnorm ----
  k_cvt_wt<<<dim3(2, 16), 256, 0, stream>>>(cw[3][0], Wt4, 512, 64);
  k_cvt_wt<<<dim3(2, 16), 256, 0, stream>>>(cw[3][2], Wt4 + (size_t)64 * 512, 512, 64);
  k_cat2<<<1, 64, 0, stream>>>(cw[3][1], cw[3][3], cbias4);
  k_gemm_mfma_t<64><<<dim3(2, mfmaRows), 256, 0, stream>>>(actA, Wt4, cbias4, xlr4b, N, 512, 128);
  k_gat_fused1<<<nodeBlocks, 256, 0, stream>>>(xlr4b, cw[3][4], rowptr, srcn,
                                               cw[3][5], agg4, N);
  k_gnorm_stats<<<dim3(G, 1, NCHUNK), 256, 0, stream>>>(agg4, ptrg, psum, psq, 64);
  k_gnorm_coef<<<G, 256, 0, stream>>>(psum, psq, nw[3][0], nw[3][1], nw[3][2], ptrg, cA, cC, 64);
  k_gnorm_apply<<<(N * 16 + 255) / 256, 256, 0, stream>>>(agg4, batch, cA, cC, out4, nullptr,
                                                          64, N * 16, 0);
  k_extract<<<dim3(G, 1), 64, 0, stream>>>(out4, cat, ptrg, 64, 1536, FD);

  k_final<<<G, 256, 0, stream>>>(cat, lin_w, lin_b, out, FD);
}

// Round 7
// 551.233 us; speedup vs baseline: 7.0009x; 1.0635x over previous
//
#include <hip/hip_runtime.h>
#include <hip/hip_bf16.h>

#define NEG_SLOPE 0.2f
#define EPSI 1e-5f
#define THR 8.0f

typedef __attribute__((ext_vector_type(8))) short bf16x8;
typedef __attribute__((ext_vector_type(4))) float f32x4;

__device__ __forceinline__ float wred_sum(float v){
#pragma unroll
  for (int o = 32; o > 0; o >>= 1) v += __shfl_xor(v, o);
  return v;
}

__device__ __forceinline__ unsigned short f2bf(float f){
  __hip_bfloat16 h = __float2bfloat16(f);
  return *reinterpret_cast<unsigned short*>(&h);
}
__device__ __forceinline__ float bf2f(unsigned short u){
  return __uint_as_float((unsigned int)u << 16);
}

__device__ __forceinline__ void gload16(const void* g, void* l){
  __builtin_amdgcn_global_load_lds((const __attribute__((address_space(1))) unsigned int*)g,
                                   (__attribute__((address_space(3))) unsigned int*)l, 16, 0, 0);
}

// ---------------- CSR build (by dst) ----------------
__global__ __launch_bounds__(256) void k_count(const int* __restrict__ ei, int* __restrict__ deg,
                                               int E, int EP){
  int e = blockIdx.x * 256 + threadIdx.x;
  if (e >= EP) return;
  int d = (e < E) ? ei[E + e] : (e - E);
  atomicAdd(&deg[d], 1);
}

__global__ __launch_bounds__(256) void k_scan(const int* __restrict__ deg, int* __restrict__ rowptr, int n){
  __shared__ int part[256];
  int t = threadIdx.x;
  int L = (n + 255) / 256;
  int lo = t * L, hi = min(lo + L, n);
  int s = 0;
  for (int i = lo; i < hi; i++) s += deg[i];
  part[t] = s;
  __syncthreads();
  if (t == 0){
    int acc = 0;
    for (int i = 0; i < 256; i++){ int v = part[i]; part[i] = acc; acc += v; }
  }
  __syncthreads();
  int acc = part[t];
  for (int i = lo; i < hi; i++){ rowptr[i] = acc; acc += deg[i]; }
  if (t == 255) rowptr[n] = acc;
}

__global__ __launch_bounds__(256) void k_copy(const int* __restrict__ a, int* __restrict__ b, int n){
  int i = blockIdx.x * 256 + threadIdx.x;
  if (i < n) b[i] = a[i];
}

__global__ __launch_bounds__(256) void k_fill(const int* __restrict__ ei, int* __restrict__ cursor,
                                              int* __restrict__ srcn, int E, int EP){
  int e = blockIdx.x * 256 + threadIdx.x;
  if (e >= EP) return;
  int s, d;
  if (e < E){ s = ei[e]; d = ei[E + e]; } else { s = d = e - E; }
  int pos = atomicAdd(&cursor[d], 1);
  srcn[pos] = s;
}

// ---------------- bf16 conversions ----------------
__global__ __launch_bounds__(256) void k_cvt_act(const float* __restrict__ in,
                                                 unsigned short* __restrict__ ob, int total4){
  int i = blockIdx.x * 256 + threadIdx.x;
  if (i >= total4) return;
  float4 v = ((const float4*)in)[i];
  ushort4 o;
  o.x = f2bf(v.x); o.y = f2bf(v.y); o.z = f2bf(v.z); o.w = f2bf(v.w);
  ((ushort4*)ob)[i] = o;
}

// W[K][Ncol] fp32 -> Wt[Ncol][K] bf16 (tiled transpose)
__global__ __launch_bounds__(256) void k_cvt_wt(const float* __restrict__ W,
                                                unsigned short* __restrict__ Wt,
                                                int K, int Ncol){
  __shared__ float t[32][33];
  int bx = blockIdx.x, by = blockIdx.y;
  int tx = threadIdx.x & 31, ty = threadIdx.x >> 5;
#pragma unroll
  for (int i = 0; i < 4; i++)
    t[ty + i * 8][tx] = W[(size_t)(by * 32 + ty + i * 8) * Ncol + bx * 32 + tx];
  __syncthreads();
#pragma unroll
  for (int i = 0; i < 4; i++)
    Wt[(size_t)(bx * 32 + ty + i * 8) * K + by * 32 + tx] = f2bf(t[tx][ty + i * 8]);
}

__global__ __launch_bounds__(256) void k_catb(const float* __restrict__ a,
                                              const float* __restrict__ b,
                                              float* __restrict__ o, int n){
  int i = blockIdx.x * 256 + threadIdx.x;
  if (i < n) o[i] = a[i];
  else if (i < 2 * n) o[i] = b[i - n];
}

// ---------------- bf16 MFMA GEMM: Cb[M,Ncol] = bf16(A[M,K]@W[K,*] + bias) ----------------
template<int BN>
__global__ __launch_bounds__(256) void k_gemm_mfma_t(const unsigned short* __restrict__ A,
                                                     const unsigned short* __restrict__ Wt,
                                                     const float* __restrict__ bias,
                                                     unsigned short* __restrict__ Cb,
                                                     int M, int K, int Ncol){
  constexpr int NF = BN / 32;
  __shared__ unsigned short As[128 * 32];
  __shared__ unsigned short Bs[BN * 32];
  const int tid = threadIdx.x;
  const int w = tid >> 6, lane = tid & 63;
  const int wr = w >> 1, wc = w & 1;
  const int row0 = blockIdx.y * 128, col0 = blockIdx.x * BN;
  const int lr = lane & 15, lk = lane >> 4;
  const int swz = (lr >> 1) & 3;

  f32x4 acc[4][NF];
#pragma unroll
  for (int i = 0; i < 4; i++)
#pragma unroll
    for (int j = 0; j < NF; j++) acc[i][j] = (f32x4){0.f, 0.f, 0.f, 0.f};

  for (int k0 = 0; k0 < K; k0 += 32){
#pragma unroll
    for (int c = 0; c < 2; c++){
      int g = w * 128 + c * 64 + lane;
      int row = g >> 2, slot = g & 3;
      int kq = slot ^ ((row >> 1) & 3);
      int srow = row0 + row; if (srow >= M) srow = M - 1;
      gload16(&A[(size_t)srow * K + k0 + kq * 8], &As[(size_t)(w * 128 + c * 64) * 8]);
    }
#pragma unroll
    for (int c = 0; c < BN / 64; c++){
      int g = w * BN + c * 64 + lane;
      int col = g >> 2, slot = g & 3;
      int kq = slot ^ ((col >> 1) & 3);
      gload16(&Wt[(size_t)(col0 + col) * K + k0 + kq * 8], &Bs[(size_t)(w * BN + c * 64) * 8]);
    }
    __syncthreads();

    bf16x8 af[4], bf_[NF];
#pragma unroll
    for (int mi = 0; mi < 4; mi++){
      int rl = wr * 64 + mi * 16 + lr;
      af[mi] = *(const bf16x8*)&As[(rl * 4 + (lk ^ swz)) * 8];
    }
#pragma unroll
    for (int ni = 0; ni < NF; ni++){
      int cl = wc * (BN / 2) + ni * 16 + lr;
      bf_[ni] = *(const bf16x8*)&Bs[(cl * 4 + (lk ^ swz)) * 8];
    }
#pragma unroll
    for (int mi = 0; mi < 4; mi++)
#pragma unroll
      for (int ni = 0; ni < NF; ni++)
        acc[mi][ni] = __builtin_amdgcn_mfma_f32_16x16x32_bf16(af[mi], bf_[ni], acc[mi][ni], 0, 0, 0);
    __syncthreads();
  }

#pragma unroll
  for (int mi = 0; mi < 4; mi++){
#pragma unroll
    for (int ni = 0; ni < NF; ni++){
      int gc = col0 + wc * (BN / 2) + ni * 16 + lr;
      float bv = bias[gc];
#pragma unroll
      for (int r = 0; r < 4; r++){
        int gr = row0 + wr * 64 + mi * 16 + lk * 4 + r;
        if (gr < M) Cb[(size_t)gr * Ncol + gc] = f2bf(acc[mi][ni][r] + bv);
      }
    }
  }
}

// ---------------- fused GATv2 edge phase, 8 heads (flash-style, dual-state, defer-max) ----------------
// xlrb: [N][1024] bf16 = xl | xr. One wave per node; lane owns 8 channels (head = lane>>3).
__global__ __launch_bounds__(256) void k_gat_fused8(const unsigned short* __restrict__ xlrb,
                                                    const float* __restrict__ att,
                                                    const int* __restrict__ rowptr,
                                                    const int* __restrict__ srcn,
                                                    const float* __restrict__ bias,
                                                    const unsigned short* __restrict__ resb,
                                                    float* __restrict__ out,
                                                    int N){
  int node = (blockIdx.x * 256 + threadIdx.x) >> 6;
  int lane = threadIdx.x & 63;
  if (node >= N) return;
  float xr[8], av[8];
  {
    bf16x8 r8 = *(const bf16x8*)&xlrb[(size_t)node * 1024 + 512 + lane * 8];
    float4 a0 = *(const float4*)&att[lane * 8];
    float4 a1 = *(const float4*)&att[lane * 8 + 4];
#pragma unroll
    for (int j = 0; j < 8; j++) xr[j] = bf2f((unsigned short)r8[j]);
    av[0] = a0.x; av[1] = a0.y; av[2] = a0.z; av[3] = a0.w;
    av[4] = a1.x; av[5] = a1.y; av[6] = a1.z; av[7] = a1.w;
  }
  int e0 = rowptr[node], e1 = rowptr[node + 1];
  float m0 = -1e30f, s0 = 0.f, m1 = -1e30f, s1 = 0.f;
  float acc0[8] = {}, acc1[8] = {};

  for (int base = e0; base < e1; base += 64){
    int cnt = min(64, e1 - base);
    int sn = 0;
    if (lane < cnt) sn = srcn[base + lane];
    int k = 0;
    for (; k + 1 < cnt; k += 2){
      int ska = __shfl(sn, k);
      int skb = __shfl(sn, k + 1);
      bf16x8 va8 = *(const bf16x8*)&xlrb[(size_t)ska * 1024 + lane * 8];
      bf16x8 vb8 = *(const bf16x8*)&xlrb[(size_t)skb * 1024 + lane * 8];
      float va[8], vb[8];
#pragma unroll
      for (int j = 0; j < 8; j++){ va[j] = bf2f((unsigned short)va8[j]); vb[j] = bf2f((unsigned short)vb8[j]); }
      float suma = 0.f, sumb = 0.f;
#pragma unroll
      for (int j = 0; j < 8; j++){
        float ta = va[j] + xr[j]; ta = ta > 0.f ? ta : NEG_SLOPE * ta; suma += ta * av[j];
        float tb = vb[j] + xr[j]; tb = tb > 0.f ? tb : NEG_SLOPE * tb; sumb += tb * av[j];
      }
      suma += __shfl_xor(suma, 1); sumb += __shfl_xor(sumb, 1);
      suma += __shfl_xor(suma, 2); sumb += __shfl_xor(sumb, 2);
      suma += __shfl_xor(suma, 4); sumb += __shfl_xor(sumb, 4);
      // state 0 <- a
      if (__builtin_expect(__any(suma > m0 + THR), 0)){
        float mn = fmaxf(m0, suma);
        float cs = __expf(m0 - mn);
        float p  = __expf(suma - mn);
        s0 = s0 * cs + p;
#pragma unroll
        for (int j = 0; j < 8; j++) acc0[j] = acc0[j] * cs + p * va[j];
        m0 = mn;
      } else {
        float p = __expf(suma - m0);
        s0 += p;
#pragma unroll
        for (int j = 0; j < 8; j++) acc0[j] += p * va[j];
      }
      // state 1 <- b
      if (__builtin_expect(__any(sumb > m1 + THR), 0)){
        float mn = fmaxf(m1, sumb);
        float cs = __expf(m1 - mn);
        float p  = __expf(sumb - mn);
        s1 = s1 * cs + p;
#pragma unroll
        for (int j = 0; j < 8; j++) acc1[j] = acc1[j] * cs + p * vb[j];
        m1 = mn;
      } else {
        float p = __expf(sumb - m1);
        s1 += p;
#pragma unroll
        for (int j = 0; j < 8; j++) acc1[j] += p * vb[j];
      }
    }
    if (k < cnt){
      int ska = __shfl(sn, k);
      bf16x8 va8 = *(const bf16x8*)&xlrb[(size_t)ska * 1024 + lane * 8];
      float va[8];
#pragma unroll
      for (int j = 0; j < 8; j++) va[j] = bf2f((unsigned short)va8[j]);
      float suma = 0.f;
#pragma unroll
      for (int j = 0; j < 8; j++){
        float ta = va[j] + xr[j]; ta = ta > 0.f ? ta : NEG_SLOPE * ta; suma += ta * av[j];
      }
      suma += __shfl_xor(suma, 1);
      suma += __shfl_xor(suma, 2);
      suma += __shfl_xor(suma, 4);
      if (__builtin_expect(__any(suma > m0 + THR), 0)){
        float mn = fmaxf(m0, suma);
        float cs = __expf(m0 - mn);
        float p  = __expf(suma - mn);
        s0 = s0 * cs + p;
#pragma unroll
        for (int j = 0; j < 8; j++) acc0[j] = acc0[j] * cs + p * va[j];
        m0 = mn;
      } else {
        float p = __expf(suma - m0);
        s0 += p;
#pragma unroll
        for (int j = 0; j < 8; j++) acc0[j] += p * va[j];
      }
    }
  }
  // merge states (s1 may be 0 with m1=-inf: exp(-inf)=0 kills it)
  float m = fmaxf(m0, m1);
  float c0 = __expf(m0 - m), c1 = __expf(m1 - m);
  float s = s0 * c0 + s1 * c1;
  float inv = 1.f / s;
  size_t o = (size_t)node * 512 + lane * 8;
  float4 bv0 = *(const float4*)&bias[lane * 8];
  float4 bv1 = *(const float4*)&bias[lane * 8 + 4];
  float rr[8] = {};
  if (resb){
    bf16x8 r8 = *(const bf16x8*)&resb[o];
#pragma unroll
    for (int j = 0; j < 8; j++) rr[j] = bf2f((unsigned short)r8[j]);
  }
  float bb[8] = {bv0.x, bv0.y, bv0.z, bv0.w, bv1.x, bv1.y, bv1.z, bv1.w};
  float4 o0, o1;
  float res8[8];
#pragma unroll
  for (int j = 0; j < 8; j++)
    res8[j] = (acc0[j] * c0 + acc1[j] * c1) * inv + bb[j] + rr[j];
  o0.x = res8[0]; o0.y = res8[1]; o0.z = res8[2]; o0.w = res8[3];
  o1.x = res8[4]; o1.y = res8[5]; o1.z = res8[6]; o1.w = res8[7];
  *(float4*)&out[o] = o0;
  *(float4*)&out[o + 4] = o1;
}

// ---------------- fused GATv2 edge phase, 1 head, OD=64 (layer 4) ----------------
__global__ __launch_bounds__(256) void k_gat_fused1(const unsigned short* __restrict__ xlr,
                                                    const float* __restrict__ att,
                                                    const int* __restrict__ rowptr,
                                                    const int* __restrict__ srcn,
                                                    const float* __restrict__ bias,
                                                    float* __restrict__ out,
                                                    int N){
  int node = (blockIdx.x * 256 + threadIdx.x) >> 6;
  int lane = threadIdx.x & 63;
  if (node >= N) return;
  float xrv = bf2f(xlr[(size_t)node * 128 + 64 + lane]);
  float attv = att[lane];
  int e0 = rowptr[node], e1 = rowptr[node + 1];
  float m = -1e30f, s = 0.f, acc = 0.f;
  for (int base = e0; base < e1; base += 64){
    int cnt = min(64, e1 - base);
    int sn = 0;
    if (lane < cnt) sn = srcn[base + lane];
    for (int k = 0; k < cnt; k++){
      int sk = __shfl(sn, k);
      float v = bf2f(xlr[(size_t)sk * 128 + lane]);
      float t = v + xrv;
      t = t > 0.f ? t : NEG_SLOPE * t;
      float sum = wred_sum(t * attv);
      if (sum > m + THR){
        float mn = fmaxf(m, sum);
        float cs = __expf(m - mn);
        float p  = __expf(sum - mn);
        s = s * cs + p;
        acc = acc * cs + p * v;
        m = mn;
      } else {
        float p = __expf(sum - m);
        s += p;
        acc += p * v;
      }
    }
  }
  out[(size_t)node * 64 + lane] = acc / s + bias[lane];
}

// ---------------- GraphNorm: chunked stats -> coef -> vectorized apply (bf16 out) ----------------
#define NCHUNK 16
__global__ __launch_bounds__(256) void k_gnorm_stats(const float* __restrict__ y,
                                                     const int* __restrict__ ptrg,
                                                     float* __restrict__ psum,
                                                     float* __restrict__ psq,
                                                     int OD){
  int g = blockIdx.x, chunk = blockIdx.z;
  int lane = threadIdx.x & 63, sub = threadIdx.x >> 6;
  int c = blockIdx.y * 64 + lane;
  int lo = ptrg[g], hi = ptrg[g + 1], len = hi - lo;
  int c0 = lo + (len * chunk) / NCHUNK, c1 = lo + (len * (chunk + 1)) / NCHUNK;
  float s = 0.f, q = 0.f;
  for (int i = c0 + sub; i < c1; i += 4){
    float v = y[(size_t)i * OD + c];
    s += v; q += v * v;
  }
  __shared__ float sm[4][64], sq2[4][64];
  sm[sub][lane] = s; sq2[sub][lane] = q;
  __syncthreads();
  if (sub == 0){
    s = sm[0][lane] + sm[1][lane] + sm[2][lane] + sm[3][lane];
    q = sq2[0][lane] + sq2[1][lane] + sq2[2][lane] + sq2[3][lane];
    size_t o = (size_t)(g * NCHUNK + chunk) * OD + c;
    psum[o] = s; psq[o] = q;
  }
}

__global__ __launch_bounds__(256) void k_gnorm_coef(const float* __restrict__ psum,
                                                    const float* __restrict__ psq,
                                                    const float* __restrict__ w,
                                                    const float* __restrict__ b,
                                                    const float* __restrict__ ms,
                                                    const int* __restrict__ ptrg,
                                                    float* __restrict__ cA,
                                                    float* __restrict__ cC,
                                                    int OD){
  int g = blockIdx.x;
  int len = ptrg[g + 1] - ptrg[g];
  float inv_n = 1.f / (float)len;
  for (int c = threadIdx.x; c < OD; c += 256){
    float s = 0.f, q = 0.f;
    for (int k = 0; k < NCHUNK; k++){
      size_t o = (size_t)(g * NCHUNK + k) * OD + c;
      s += psum[o]; q += psq[o];
    }
    float mean = s * inv_n, ey2 = q * inv_n;
    float m = ms[c];
    float var = ey2 - mean * mean * (2.f * m - m * m);
    float inv = rsqrtf(var + EPSI);
    float A = w[c] * inv;
    cA[(size_t)g * OD + c] = A;
    cC[(size_t)g * OD + c] = b[c] - A * m * mean;
  }
}

__global__ __launch_bounds__(256) void k_gnorm_apply(const float* __restrict__ y,
                                                     const int* __restrict__ batch,
                                                     const float* __restrict__ cA,
                                                     const float* __restrict__ cC,
                                                     unsigned short* __restrict__ outb,
                                                     int OD, int total4, int do_elu){
  int idx = blockIdx.x * 256 + threadIdx.x;
  if (idx >= total4) return;
  int od4 = OD >> 2;
  int node = idx / od4;
  int c = (idx - node * od4) << 2;
  int g = batch[node];
  float4 v = ((const float4*)y)[idx];
  float4 A = *(const float4*)&cA[(size_t)g * OD + c];
  float4 Cc = *(const float4*)&cC[(size_t)g * OD + c];
  float4 r;
  r.x = A.x * v.x + Cc.x;
  r.y = A.y * v.y + Cc.y;
  r.z = A.z * v.z + Cc.z;
  r.w = A.w * v.w + Cc.w;
  if (do_elu){
    r.x = r.x > 0.f ? r.x : expf(r.x) - 1.f;
    r.y = r.y > 0.f ? r.y : expf(r.y) - 1.f;
    r.z = r.z > 0.f ? r.z : expf(r.z) - 1.f;
    r.w = r.w > 0.f ? r.w : expf(r.w) - 1.f;
  }
  ushort4 ob;
  ob.x = f2bf(r.x); ob.y = f2bf(r.y); ob.z = f2bf(r.z); ob.w = f2bf(r.w);
  ((ushort4*)outb)[idx] = ob;
}

// ---------------- extract summary rows (bf16 src) into JK concat buffer ----------------
__global__ __launch_bounds__(64) void k_extract(const unsigned short* __restrict__ srcb,
                                                float* __restrict__ cat,
                                                const int* __restrict__ ptrg,
                                                int OD, int off, int FD){
  int g = blockIdx.x;
  int c = blockIdx.y * 64 + threadIdx.x;
  cat[(size_t)g * FD + off + c] = bf2f(srcb[(size_t)ptrg[g] * OD + c]);
}

// ---------------- final linear on 50 summary rows ----------------
__global__ __launch_bounds__(256) void k_final(const float* __restrict__ cat,
                                               const float* __restrict__ lin_w,
                                               const float* __restrict__ lin_b,
                                               float* __restrict__ out, int FD){
  int g = blockIdx.x;
  float s = 0.f;
  for (int c = threadIdx.x; c < FD; c += 256) s += cat[(size_t)g * FD + c] * lin_w[c];
  s = wred_sum(s);
  __shared__ float sm[4];
  if ((threadIdx.x & 63) == 0) sm[threadIdx.x >> 6] = s;
  __syncthreads();
  if (threadIdx.x == 0) out[g] = sm[0] + sm[1] + sm[2] + sm[3] + lin_b[0];
}

extern "C" void kernel_launch(void* const* d_in, const int* in_sizes, int n_in,
                              void* d_out, int out_size, void* d_ws, size_t ws_size,
                              hipStream_t stream) {
  const int TD = 768, HC = 64, H = 8;
  const float* x     = (const float*)d_in[0];
  const int*   ei    = (const int*)d_in[1];
  const int*   batch = (const int*)d_in[2];
  const int*   ptrg  = (const int*)d_in[3];
  const float* tp_w  = (const float*)d_in[4];
  const float* tp_b  = (const float*)d_in[5];
  const float* lin_w = (const float*)d_in[6];
  const float* lin_b = (const float*)d_in[7];
  const float* cw[4][6];
  for (int l = 0; l < 4; l++)
    for (int j = 0; j < 6; j++) cw[l][j] = (const float*)d_in[8 + 6 * l + j];
  const float* nw[4][3];
  for (int l = 0; l < 4; l++)
    for (int j = 0; j < 3; j++) nw[l][j] = (const float*)d_in[32 + 3 * l + j];

  const int N  = in_sizes[0] / TD;   // 20000
  const int E  = in_sizes[1] / 2;    // 240000
  const int EP = E + N;              // 260000
  const int G  = in_sizes[3] - 1;    // 50
  const int FD = 3 * HC * H + HC;    // 1600

  char* wsp = (char*)d_ws;
  size_t off = 0;
  auto alloc = [&](size_t b) -> void* {
    void* p = wsp + off;
    off += (b + 255) & ~(size_t)255;
    return p;
  };
  float* tmpF  = (float*)alloc((size_t)N * 512 * 4);            // fused8 fp32 out / layer4 scratch
  unsigned short* xlrb = (unsigned short*)alloc((size_t)N * 1024 * 2);  // xl|xr combined; aliases xbf, xlr4b
  unsigned short* actA = (unsigned short*)alloc((size_t)N * 512 * 2);   // the single bf16 activation buffer
  unsigned short* h0h  = (unsigned short*)alloc((size_t)N * 64 * 2);    // proj out; layer4 out reuse
  int*   rowptr= (int*)alloc((size_t)(N + 1) * 4);
  int*   cursor= (int*)alloc((size_t)N * 4);
  int*   srcn  = (int*)alloc((size_t)EP * 4);
  float* cat   = (float*)alloc((size_t)G * FD * 4);
  float* psum  = (float*)alloc((size_t)G * NCHUNK * 512 * 4);
  float* psq   = (float*)alloc((size_t)G * NCHUNK * 512 * 4);
  float* cA    = (float*)alloc((size_t)G * 512 * 4);
  float* cC    = (float*)alloc((size_t)G * 512 * 4);
  unsigned short* WtLR = (unsigned short*)alloc((size_t)1024 * 512 * 2);
  unsigned short* WtTP = (unsigned short*)alloc((size_t)64 * 768 * 2);
  unsigned short* Wt4  = (unsigned short*)alloc((size_t)128 * 512 * 2);
  float* cbias = (float*)alloc(1024 * 4);
  (void)ws_size; (void)n_in; (void)out_size;

  float* out = (float*)d_out;

  // aliases (lifetimes disjoint)
  unsigned short* xbf   = xlrb;             // bf16 x [N,768]
  unsigned short* xlr4b = xlrb;             // layer4 combined [N,128]
  float* agg4 = tmpF;                       // layer4 aggregate [N,64]

  // ---- CSR build ----
  hipMemsetAsync(cursor, 0, (size_t)N * 4, stream);
  int eblk = (EP + 255) / 256;
  k_count<<<eblk, 256, 0, stream>>>(ei, cursor, E, EP);
  k_scan<<<1, 256, 0, stream>>>(cursor, rowptr, N);
  k_copy<<<(N + 255) / 256, 256, 0, stream>>>(rowptr, cursor, N);
  k_fill<<<eblk, 256, 0, stream>>>(ei, cursor, srcn, E, EP);

  const int mfmaRows = (N + 127) / 128;     // 157
  const int nodeBlocks = (N + 3) / 4;

  // ---- text projection: bf16 MFMA ----
  k_cvt_act<<<(N * TD / 4 + 255) / 256, 256, 0, stream>>>(x, xbf, N * TD / 4);
  k_cvt_wt<<<dim3(2, TD / 32), 256, 0, stream>>>(tp_w, WtTP, TD, 64);
  k_gemm_mfma_t<64><<<dim3(1, mfmaRows), 256, 0, stream>>>(xbf, WtTP, tp_b, h0h, N, TD, 64);

  auto layer8 = [&](const unsigned short* actbf, int Kin, int l,
                    const unsigned short* resb, unsigned short* youtb, int catoff){
    k_cvt_wt<<<dim3(16, Kin / 32), 256, 0, stream>>>(cw[l][0], WtLR, Kin, 512);
    k_cvt_wt<<<dim3(16, Kin / 32), 256, 0, stream>>>(cw[l][2], WtLR + (size_t)512 * Kin, Kin, 512);
    k_catb<<<4, 256, 0, stream>>>(cw[l][1], cw[l][3], cbias, 512);
    k_gemm_mfma_t<128><<<dim3(8, mfmaRows), 256, 0, stream>>>(actbf, WtLR, cbias, xlrb, N, Kin, 1024);
    k_gat_fused8<<<nodeBlocks, 256, 0, stream>>>(xlrb, cw[l][4], rowptr, srcn,
                                                 cw[l][5], resb, tmpF, N);
    k_gnorm_stats<<<dim3(G, 8, NCHUNK), 256, 0, stream>>>(tmpF, ptrg, psum, psq, 512);
    k_gnorm_coef<<<G, 256, 0, stream>>>(psum, psq, nw[l][0], nw[l][1], nw[l][2], ptrg, cA, cC, 512);
    int total4 = N * 128;
    k_gnorm_apply<<<(total4 + 255) / 256, 256, 0, stream>>>(tmpF, batch, cA, cC, youtb,
                                                            512, total4, 1);
    k_extract<<<dim3(G, 8), 64, 0, stream>>>(youtb, cat, ptrg, 512, catoff, FD);
  };

  // single bf16 activation buffer: overwritten in-place each layer (safe: apply reads only tmpF)
  layer8(h0h,  64,  0, nullptr, actA, 0);
  layer8(actA, 512, 1, actA,    actA, 512);
  layer8(actA, 512, 2, actA,    actA, 1024);

  // ---- layer 4: combined xl|xr MFMA (Ncol=128) + fused edge + gnorm ----
  k_cvt_wt<<<dim3(2, 16), 256, 0, stream>>>(cw[3][0], Wt4, 512, 64);
  k_cvt_wt<<<dim3(2, 16), 256, 0, stream>>>(cw[3][2], Wt4 + (size_t)64 * 512, 512, 64);
  k_catb<<<1, 256, 0, stream>>>(cw[3][1], cw[3][3], cbias, 64);
  k_gemm_mfma_t<64><<<dim3(2, mfmaRows), 256, 0, stream>>>(actA, Wt4, cbias, xlr4b, N, 512, 128);
  k_gat_fused1<<<nodeBlocks, 256, 0, stream>>>(xlr4b, cw[3][4], rowptr, srcn,
                                               cw[3][5], agg4, N);
  k_gnorm_stats<<<dim3(G, 1, NCHUNK), 256, 0, stream>>>(agg4, ptrg, psum, psq, 64);
  k_gnorm_coef<<<G, 256, 0, stream>>>(psum, psq, nw[3][0], nw[3][1], nw[3][2], ptrg, cA, cC, 64);
  k_gnorm_apply<<<(N * 16 + 255) / 256, 256, 0, stream>>>(agg4, batch, cA, cC, h0h,
                                                          64, N * 16, 0);
  k_extract<<<dim3(G, 1), 64, 0, stream>>>(h0h, cat, ptrg, 64, 1536, FD);

  k_final<<<G, 256, 0, stream>>>(cat, lin_w, lin_b, out, FD);
}

// Round 8
// 507.555 us; speedup vs baseline: 7.6034x; 1.0861x over previous
//
#include <hip/hip_runtime.h>
#include <hip/hip_bf16.h>

#define NEG_SLOPE 0.2f
#define EPSI 1e-5f
#define THR 8.0f

typedef __attribute__((ext_vector_type(8))) short bf16x8;
typedef __attribute__((ext_vector_type(4))) float f32x4;
typedef __attribute__((ext_vector_type(2))) float f32x2;

__device__ __forceinline__ float wred_sum(float v){
#pragma unroll
  for (int o = 32; o > 0; o >>= 1) v += __shfl_xor(v, o);
  return v;
}

__device__ __forceinline__ unsigned short f2bf(float f){
  __hip_bfloat16 h = __float2bfloat16(f);
  return *reinterpret_cast<unsigned short*>(&h);
}
__device__ __forceinline__ float bf2f(unsigned short u){
  return __uint_as_float((unsigned int)u << 16);
}
// two packed bf16 (in a u32) -> f32x2
__device__ __forceinline__ f32x2 bfpair(unsigned int u){
  f32x2 r;
  r.x = __uint_as_float(u << 16);
  r.y = __uint_as_float(u & 0xffff0000u);
  return r;
}
__device__ __forceinline__ f32x2 vmax2(f32x2 a, f32x2 b){
#if __has_builtin(__builtin_elementwise_max)
  return __builtin_elementwise_max(a, b);
#else
  f32x2 r; r.x = fmaxf(a.x, b.x); r.y = fmaxf(a.y, b.y); return r;
#endif
}

__device__ __forceinline__ void gload16(const void* g, void* l){
  __builtin_amdgcn_global_load_lds((const __attribute__((address_space(1))) unsigned int*)g,
                                   (__attribute__((address_space(3))) unsigned int*)l, 16, 0, 0);
}

// ---------------- CSR build (by dst) ----------------
__global__ __launch_bounds__(256) void k_count(const int* __restrict__ ei, int* __restrict__ deg,
                                               int E, int EP){
  int e = blockIdx.x * 256 + threadIdx.x;
  if (e >= EP) return;
  int d = (e < E) ? ei[E + e] : (e - E);
  atomicAdd(&deg[d], 1);
}

// in-place: deg[] -> exclusive offsets (cursor), also writes rowptr
__global__ __launch_bounds__(256) void k_scan(int* __restrict__ deg, int* __restrict__ rowptr, int n){
  __shared__ int part[256];
  int t = threadIdx.x;
  int L = (n + 255) / 256;
  int lo = t * L, hi = min(lo + L, n);
  int s = 0;
  for (int i = lo; i < hi; i++) s += deg[i];
  part[t] = s;
  __syncthreads();
  if (t == 0){
    int acc = 0;
    for (int i = 0; i < 256; i++){ int v = part[i]; part[i] = acc; acc += v; }
  }
  __syncthreads();
  int acc = part[t];
  for (int i = lo; i < hi; i++){
    int d = deg[i];
    rowptr[i] = acc;
    deg[i] = acc;
    acc += d;
  }
  if (t == 255) rowptr[n] = acc;
}

__global__ __launch_bounds__(256) void k_fill(const int* __restrict__ ei, int* __restrict__ cursor,
                                              int* __restrict__ srcn, int E, int EP){
  int e = blockIdx.x * 256 + threadIdx.x;
  if (e >= EP) return;
  int s, d;
  if (e < E){ s = ei[e]; d = ei[E + e]; } else { s = d = e - E; }
  int pos = atomicAdd(&cursor[d], 1);
  srcn[pos] = s;
}

// ---------------- bf16 conversions ----------------
__global__ __launch_bounds__(256) void k_cvt_act(const float* __restrict__ in,
                                                 unsigned short* __restrict__ ob, int total4){
  int i = blockIdx.x * 256 + threadIdx.x;
  if (i >= total4) return;
  float4 v = ((const float4*)in)[i];
  ushort4 o;
  o.x = f2bf(v.x); o.y = f2bf(v.y); o.z = f2bf(v.z); o.w = f2bf(v.w);
  ((ushort4*)ob)[i] = o;
}

// W[K][Ncol] fp32 -> Wt[Ncol][K] bf16 (tiled transpose)
__global__ __launch_bounds__(256) void k_cvt_wt(const float* __restrict__ W,
                                                unsigned short* __restrict__ Wt,
                                                int K, int Ncol){
  __shared__ float t[32][33];
  int bx = blockIdx.x, by = blockIdx.y;
  int tx = threadIdx.x & 31, ty = threadIdx.x >> 5;
#pragma unroll
  for (int i = 0; i < 4; i++)
    t[ty + i * 8][tx] = W[(size_t)(by * 32 + ty + i * 8) * Ncol + bx * 32 + tx];
  __syncthreads();
#pragma unroll
  for (int i = 0; i < 4; i++)
    Wt[(size_t)(bx * 32 + ty + i * 8) * K + by * 32 + tx] = f2bf(t[tx][ty + i * 8]);
}

// two weights at once: Wa -> Wt[0:Ncol], Wb -> Wt[Ncol:2*Ncol]
__global__ __launch_bounds__(256) void k_cvt_wt2(const float* __restrict__ Wa,
                                                 const float* __restrict__ Wb,
                                                 unsigned short* __restrict__ Wt,
                                                 int K, int Ncol){
  __shared__ float t[32][33];
  int half = gridDim.x >> 1;
  int isB = blockIdx.x >= half;
  const float* W = isB ? Wb : Wa;
  unsigned short* out = Wt + (isB ? (size_t)Ncol * K : 0);
  int bx = isB ? blockIdx.x - half : blockIdx.x;
  int by = blockIdx.y;
  int tx = threadIdx.x & 31, ty = threadIdx.x >> 5;
#pragma unroll
  for (int i = 0; i < 4; i++)
    t[ty + i * 8][tx] = W[(size_t)(by * 32 + ty + i * 8) * Ncol + bx * 32 + tx];
  __syncthreads();
#pragma unroll
  for (int i = 0; i < 4; i++)
    out[(size_t)(bx * 32 + ty + i * 8) * K + by * 32 + tx] = f2bf(t[tx][ty + i * 8]);
}

// ---------------- bf16 MFMA GEMM, 8 waves, 128 x BN tile ----------------
// A: bf16 [M][K]; Wt: bf16 [cols][K]. bias = ba[0:bsplit] | bb[bsplit:...]
template<int BN>
__global__ __launch_bounds__(512) void k_gemm_mfma8(const unsigned short* __restrict__ A,
                                                    const unsigned short* __restrict__ Wt,
                                                    const float* __restrict__ ba,
                                                    const float* __restrict__ bb,
                                                    int bsplit,
                                                    unsigned short* __restrict__ Cb,
                                                    int M, int K, int Ncol){
  constexpr int NF = BN / 64;              // 16-col fragments per wave (4 col-waves)
  __shared__ unsigned short As[128 * 32];
  __shared__ unsigned short Bs[BN * 32];
  const int tid = threadIdx.x;
  const int w = tid >> 6, lane = tid & 63;
  const int wr = w >> 2, wc = w & 3;       // 2 row-waves x 4 col-waves
  const int row0 = blockIdx.y * 128, col0 = blockIdx.x * BN;
  const int lr = lane & 15, lk = lane >> 4;
  const int swz = (lr >> 1) & 3;

  f32x4 acc[4][NF];
#pragma unroll
  for (int i = 0; i < 4; i++)
#pragma unroll
    for (int j = 0; j < NF; j++) acc[i][j] = (f32x4){0.f, 0.f, 0.f, 0.f};

  for (int k0 = 0; k0 < K; k0 += 32){
    // A tile: 512 granules of 16B
    for (int g0 = w * 64; g0 < 512; g0 += 512){
      int g = g0 + lane;
      int row = g >> 2, slot = g & 3;
      int kq = slot ^ ((row >> 1) & 3);
      int srow = row0 + row; if (srow >= M) srow = M - 1;
      gload16(&A[(size_t)srow * K + k0 + kq * 8], &As[(size_t)g0 * 8]);
    }
    // B tile: BN*4 granules
    for (int g0 = w * 64; g0 < BN * 4; g0 += 512){
      int g = g0 + lane;
      int col = g >> 2, slot = g & 3;
      int kq = slot ^ ((col >> 1) & 3);
      gload16(&Wt[(size_t)(col0 + col) * K + k0 + kq * 8], &Bs[(size_t)g0 * 8]);
    }
    __syncthreads();

    bf16x8 af[4], bf_[NF];
#pragma unroll
    for (int mi = 0; mi < 4; mi++){
      int rl = wr * 64 + mi * 16 + lr;
      af[mi] = *(const bf16x8*)&As[(rl * 4 + (lk ^ swz)) * 8];
    }
#pragma unroll
    for (int ni = 0; ni < NF; ni++){
      int cl = wc * (BN / 4) + ni * 16 + lr;
      bf_[ni] = *(const bf16x8*)&Bs[(cl * 4 + (lk ^ swz)) * 8];
    }
#pragma unroll
    for (int mi = 0; mi < 4; mi++)
#pragma unroll
      for (int ni = 0; ni < NF; ni++)
        acc[mi][ni] = __builtin_amdgcn_mfma_f32_16x16x32_bf16(af[mi], bf_[ni], acc[mi][ni], 0, 0, 0);
    __syncthreads();
  }

#pragma unroll
  for (int mi = 0; mi < 4; mi++){
#pragma unroll
    for (int ni = 0; ni < NF; ni++){
      int gc = col0 + wc * (BN / 4) + ni * 16 + lr;
      float bv = gc < bsplit ? ba[gc] : bb[gc - bsplit];
#pragma unroll
      for (int r = 0; r < 4; r++){
        int gr = row0 + wr * 64 + mi * 16 + lk * 4 + r;
        if (gr < M) Cb[(size_t)gr * Ncol + gc] = f2bf(acc[mi][ni][r] + bv);
      }
    }
  }
}

// ---------------- fused GATv2 edge phase, 8 heads (dual-state, defer-max, packed f32x2) ----------------
// xlrb: [N][1024] bf16 = xl | xr. One wave per node; lane owns 8 channels (head = lane>>3).
__global__ __launch_bounds__(256) void k_gat_fused8(const unsigned short* __restrict__ xlrb,
                                                    const float* __restrict__ att,
                                                    const int* __restrict__ rowptr,
                                                    const int* __restrict__ srcn,
                                                    const float* __restrict__ bias,
                                                    const unsigned short* __restrict__ resb,
                                                    unsigned short* __restrict__ yb,
                                                    int N){
  int node = (blockIdx.x * 256 + threadIdx.x) >> 6;
  int lane = threadIdx.x & 63;
  if (node >= N) return;
  f32x2 xr2[4], av2[4];
  {
    uint4 ur = *(const uint4*)&xlrb[(size_t)node * 1024 + 512 + lane * 8];
    xr2[0] = bfpair(ur.x); xr2[1] = bfpair(ur.y); xr2[2] = bfpair(ur.z); xr2[3] = bfpair(ur.w);
    float4 a0 = *(const float4*)&att[lane * 8];
    float4 a1 = *(const float4*)&att[lane * 8 + 4];
    av2[0] = (f32x2){a0.x, a0.y}; av2[1] = (f32x2){a0.z, a0.w};
    av2[2] = (f32x2){a1.x, a1.y}; av2[3] = (f32x2){a1.z, a1.w};
  }
  int e0 = rowptr[node], e1 = rowptr[node + 1];
  float m0 = -1e30f, s0 = 0.f, m1 = -1e30f, s1 = 0.f;
  f32x2 acc0[4] = {}, acc1[4] = {};

  for (int base = e0; base < e1; base += 64){
    int cnt = min(64, e1 - base);
    int sn = 0;
    if (lane < cnt) sn = srcn[base + lane];
    int k = 0;
    for (; k + 1 < cnt; k += 2){
      int ska = __shfl(sn, k);
      int skb = __shfl(sn, k + 1);
      uint4 ua = *(const uint4*)&xlrb[(size_t)ska * 1024 + lane * 8];
      uint4 ub = *(const uint4*)&xlrb[(size_t)skb * 1024 + lane * 8];
      f32x2 va[4], vb[4];
      va[0] = bfpair(ua.x); va[1] = bfpair(ua.y); va[2] = bfpair(ua.z); va[3] = bfpair(ua.w);
      vb[0] = bfpair(ub.x); vb[1] = bfpair(ub.y); vb[2] = bfpair(ub.z); vb[3] = bfpair(ub.w);
      f32x2 da = (f32x2){0.f, 0.f}, db = (f32x2){0.f, 0.f};
#pragma unroll
      for (int j = 0; j < 4; j++){
        f32x2 ta = va[j] + xr2[j];
        f32x2 tb = vb[j] + xr2[j];
        ta = vmax2(ta, ta * NEG_SLOPE);
        tb = vmax2(tb, tb * NEG_SLOPE);
        da += ta * av2[j];
        db += tb * av2[j];
      }
      float suma = da.x + da.y, sumb = db.x + db.y;
      suma += __shfl_xor(suma, 1); sumb += __shfl_xor(sumb, 1);
      suma += __shfl_xor(suma, 2); sumb += __shfl_xor(sumb, 2);
      suma += __shfl_xor(suma, 4); sumb += __shfl_xor(sumb, 4);
      if (__builtin_expect(__any(suma > m0 + THR), 0)){
        float mn = fmaxf(m0, suma);
        float cs = __expf(m0 - mn);
        float p  = __expf(suma - mn);
        s0 = s0 * cs + p;
#pragma unroll
        for (int j = 0; j < 4; j++) acc0[j] = acc0[j] * cs + va[j] * p;
        m0 = mn;
      } else {
        float p = __expf(suma - m0);
        s0 += p;
#pragma unroll
        for (int j = 0; j < 4; j++) acc0[j] += va[j] * p;
      }
      if (__builtin_expect(__any(sumb > m1 + THR), 0)){
        float mn = fmaxf(m1, sumb);
        float cs = __expf(m1 - mn);
        float p  = __expf(sumb - mn);
        s1 = s1 * cs + p;
#pragma unroll
        for (int j = 0; j < 4; j++) acc1[j] = acc1[j] * cs + vb[j] * p;
        m1 = mn;
      } else {
        float p = __expf(sumb - m1);
        s1 += p;
#pragma unroll
        for (int j = 0; j < 4; j++) acc1[j] += vb[j] * p;
      }
    }
    if (k < cnt){
      int ska = __shfl(sn, k);
      uint4 ua = *(const uint4*)&xlrb[(size_t)ska * 1024 + lane * 8];
      f32x2 va[4];
      va[0] = bfpair(ua.x); va[1] = bfpair(ua.y); va[2] = bfpair(ua.z); va[3] = bfpair(ua.w);
      f32x2 da = (f32x2){0.f, 0.f};
#pragma unroll
      for (int j = 0; j < 4; j++){
        f32x2 ta = va[j] + xr2[j];
        ta = vmax2(ta, ta * NEG_SLOPE);
        da += ta * av2[j];
      }
      float suma = da.x + da.y;
      suma += __shfl_xor(suma, 1);
      suma += __shfl_xor(suma, 2);
      suma += __shfl_xor(suma, 4);
      if (__builtin_expect(__any(suma > m0 + THR), 0)){
        float mn = fmaxf(m0, suma);
        float cs = __expf(m0 - mn);
        float p  = __expf(suma - mn);
        s0 = s0 * cs + p;
#pragma unroll
        for (int j = 0; j < 4; j++) acc0[j] = acc0[j] * cs + va[j] * p;
        m0 = mn;
      } else {
        float p = __expf(suma - m0);
        s0 += p;
#pragma unroll
        for (int j = 0; j < 4; j++) acc0[j] += va[j] * p;
      }
    }
  }
  float m = fmaxf(m0, m1);
  float c0 = __expf(m0 - m), c1 = __expf(m1 - m);
  float s = s0 * c0 + s1 * c1;
  float inv = 1.f / s;
  float4 b0 = *(const float4*)&bias[lane * 8];
  float4 b1 = *(const float4*)&bias[lane * 8 + 4];
  f32x2 bi2[4] = {(f32x2){b0.x, b0.y}, (f32x2){b0.z, b0.w},
                  (f32x2){b1.x, b1.y}, (f32x2){b1.z, b1.w}};
  f32x2 re2[4] = {};
  size_t o = (size_t)node * 512 + lane * 8;
  if (resb){
    uint4 rr = *(const uint4*)&resb[o];
    re2[0] = bfpair(rr.x); re2[1] = bfpair(rr.y); re2[2] = bfpair(rr.z); re2[3] = bfpair(rr.w);
  }
  bf16x8 ov;
#pragma unroll
  for (int j = 0; j < 4; j++){
    f32x2 r = (acc0[j] * c0 + acc1[j] * c1) * inv + bi2[j] + re2[j];
    ov[2 * j]     = (short)f2bf(r.x);
    ov[2 * j + 1] = (short)f2bf(r.y);
  }
  *(bf16x8*)&yb[o] = ov;
}

// ---------------- fused GATv2 edge phase, 1 head, OD=64 (layer 4) ----------------
__global__ __launch_bounds__(256) void k_gat_fused1(const unsigned short* __restrict__ xlr,
                                                    const float* __restrict__ att,
                                                    const int* __restrict__ rowptr,
                                                    const int* __restrict__ srcn,
                                                    const float* __restrict__ bias,
                                                    unsigned short* __restrict__ yb4,
                                                    int N){
  int node = (blockIdx.x * 256 + threadIdx.x) >> 6;
  int lane = threadIdx.x & 63;
  if (node >= N) return;
  float xrv = bf2f(xlr[(size_t)node * 128 + 64 + lane]);
  float attv = att[lane];
  int e0 = rowptr[node], e1 = rowptr[node + 1];
  float m = -1e30f, s = 0.f, acc = 0.f;
  for (int base = e0; base < e1; base += 64){
    int cnt = min(64, e1 - base);
    int sn = 0;
    if (lane < cnt) sn = srcn[base + lane];
    for (int k = 0; k < cnt; k++){
      int sk = __shfl(sn, k);
      float v = bf2f(xlr[(size_t)sk * 128 + lane]);
      float t = v + xrv;
      t = fmaxf(t, t * NEG_SLOPE);
      float sum = wred_sum(t * attv);
      if (sum > m + THR){
        float mn = fmaxf(m, sum);
        float cs = __expf(m - mn);
        float p  = __expf(sum - mn);
        s = s * cs + p;
        acc = acc * cs + p * v;
        m = mn;
      } else {
        float p = __expf(sum - m);
        s += p;
        acc += p * v;
      }
    }
  }
  yb4[(size_t)node * 64 + lane] = f2bf(acc / s + bias[lane]);
}

// ---------------- GraphNorm: chunked stats (bf16 in) -> coef -> apply (bf16 in/out + cat) ----------------
#define NCHUNK 16
__global__ __launch_bounds__(256) void k_gnorm_stats(const unsigned short* __restrict__ y,
                                                     const int* __restrict__ ptrg,
                                                     float* __restrict__ psum,
                                                     float* __restrict__ psq,
                                                     int OD){
  int g = blockIdx.x, chunk = blockIdx.z;
  int lane = threadIdx.x & 63, sub = threadIdx.x >> 6;
  int c = blockIdx.y * 64 + lane;
  int lo = ptrg[g], hi = ptrg[g + 1], len = hi - lo;
  int c0 = lo + (len * chunk) / NCHUNK, c1 = lo + (len * (chunk + 1)) / NCHUNK;
  float s = 0.f, q = 0.f;
  for (int i = c0 + sub; i < c1; i += 4){
    float v = bf2f(y[(size_t)i * OD + c]);
    s += v; q += v * v;
  }
  __shared__ float sm[4][64], sq2[4][64];
  sm[sub][lane] = s; sq2[sub][lane] = q;
  __syncthreads();
  if (sub == 0){
    s = sm[0][lane] + sm[1][lane] + sm[2][lane] + sm[3][lane];
    q = sq2[0][lane] + sq2[1][lane] + sq2[2][lane] + sq2[3][lane];
    size_t o = (size_t)(g * NCHUNK + chunk) * OD + c;
    psum[o] = s; psq[o] = q;
  }
}

__global__ __launch_bounds__(256) void k_gnorm_coef(const float* __restrict__ psum,
                                                    const float* __restrict__ psq,
                                                    const float* __restrict__ w,
                                                    const float* __restrict__ b,
                                                    const float* __restrict__ ms,
                                                    const int* __restrict__ ptrg,
                                                    float* __restrict__ cA,
                                                    float* __restrict__ cC,
                                                    int OD){
  int g = blockIdx.x;
  int len = ptrg[g + 1] - ptrg[g];
  float inv_n = 1.f / (float)len;
  for (int c = threadIdx.x; c < OD; c += 256){
    float s = 0.f, q = 0.f;
    for (int k = 0; k < NCHUNK; k++){
      size_t o = (size_t)(g * NCHUNK + k) * OD + c;
      s += psum[o]; q += psq[o];
    }
    float mean = s * inv_n, ey2 = q * inv_n;
    float m = ms[c];
    float var = ey2 - mean * mean * (2.f * m - m * m);
    float inv = rsqrtf(var + EPSI);
    float A = w[c] * inv;
    cA[(size_t)g * OD + c] = A;
    cC[(size_t)g * OD + c] = b[c] - A * m * mean;
  }
}

__global__ __launch_bounds__(256) void k_gnorm_apply(const unsigned short* __restrict__ y,
                                                     const int* __restrict__ batch,
                                                     const float* __restrict__ cA,
                                                     const float* __restrict__ cC,
                                                     unsigned short* __restrict__ outb,
                                                     const int* __restrict__ ptrg,
                                                     float* __restrict__ cat,
                                                     int catoff, int FD,
                                                     int OD, int total4, int do_elu){
  int idx = blockIdx.x * 256 + threadIdx.x;
  if (idx >= total4) return;
  int od4 = OD >> 2;
  int node = idx / od4;
  int c = (idx - node * od4) << 2;
  int g = batch[node];
  ushort4 uv = ((const ushort4*)y)[idx];
  float4 v = make_float4(bf2f(uv.x), bf2f(uv.y), bf2f(uv.z), bf2f(uv.w));
  float4 A = *(const float4*)&cA[(size_t)g * OD + c];
  float4 Cc = *(const float4*)&cC[(size_t)g * OD + c];
  float4 r;
  r.x = A.x * v.x + Cc.x;
  r.y = A.y * v.y + Cc.y;
  r.z = A.z * v.z + Cc.z;
  r.w = A.w * v.w + Cc.w;
  if (do_elu){
    r.x = r.x > 0.f ? r.x : expf(r.x) - 1.f;
    r.y = r.y > 0.f ? r.y : expf(r.y) - 1.f;
    r.z = r.z > 0.f ? r.z : expf(r.z) - 1.f;
    r.w = r.w > 0.f ? r.w : expf(r.w) - 1.f;
  }
  ushort4 ob;
  ob.x = f2bf(r.x); ob.y = f2bf(r.y); ob.z = f2bf(r.z); ob.w = f2bf(r.w);
  ((ushort4*)outb)[idx] = ob;
  if (node == ptrg[g])
    *(float4*)&cat[(size_t)g * FD + catoff + c] = r;
}

// ---------------- final linear on 50 summary rows ----------------
__global__ __launch_bounds__(256) void k_final(const float* __restrict__ cat,
                                               const float* __restrict__ lin_w,
                                               const float* __restrict__ lin_b,
                                               float* __restrict__ out, int FD){
  int g = blockIdx.x;
  float s = 0.f;
  for (int c = threadIdx.x; c < FD; c += 256) s += cat[(size_t)g * FD + c] * lin_w[c];
  s = wred_sum(s);
  __shared__ float sm[4];
  if ((threadIdx.x & 63) == 0) sm[threadIdx.x >> 6] = s;
  __syncthreads();
  if (threadIdx.x == 0) out[g] = sm[0] + sm[1] + sm[2] + sm[3] + lin_b[0];
}

extern "C" void kernel_launch(void* const* d_in, const int* in_sizes, int n_in,
                              void* d_out, int out_size, void* d_ws, size_t ws_size,
                              hipStream_t stream) {
  const int TD = 768, HC = 64, H = 8;
  const float* x     = (const float*)d_in[0];
  const int*   ei    = (const int*)d_in[1];
  const int*   batch = (const int*)d_in[2];
  const int*   ptrg  = (const int*)d_in[3];
  const float* tp_w  = (const float*)d_in[4];
  const float* tp_b  = (const float*)d_in[5];
  const float* lin_w = (const float*)d_in[6];
  const float* lin_b = (const float*)d_in[7];
  const float* cw[4][6];
  for (int l = 0; l < 4; l++)
    for (int j = 0; j < 6; j++) cw[l][j] = (const float*)d_in[8 + 6 * l + j];
  const float* nw[4][3];
  for (int l = 0; l < 4; l++)
    for (int j = 0; j < 3; j++) nw[l][j] = (const float*)d_in[32 + 3 * l + j];

  const int N  = in_sizes[0] / TD;   // 20000
  const int E  = in_sizes[1] / 2;    // 240000
  const int EP = E + N;              // 260000
  const int G  = in_sizes[3] - 1;    // 50
  const int FD = 3 * HC * H + HC;    // 1600

  char* wsp = (char*)d_ws;
  size_t off = 0;
  auto alloc = [&](size_t b) -> void* {
    void* p = wsp + off;
    off += (b + 255) & ~(size_t)255;
    return p;
  };
  unsigned short* xlrb = (unsigned short*)alloc((size_t)N * 1024 * 2);  // xl|xr; aliases xbf, xlr4b
  unsigned short* yb   = (unsigned short*)alloc((size_t)N * 512 * 2);   // pre-norm y (bf16); L4 reuse
  unsigned short* actA = (unsigned short*)alloc((size_t)N * 512 * 2);   // activations (bf16)
  unsigned short* h0h  = (unsigned short*)alloc((size_t)N * 64 * 2);    // proj out; L4 out reuse
  int*   rowptr= (int*)alloc((size_t)(N + 1) * 4);
  int*   cursor= (int*)alloc((size_t)N * 4);
  int*   srcn  = (int*)alloc((size_t)EP * 4);
  float* cat   = (float*)alloc((size_t)G * FD * 4);
  float* psum  = (float*)alloc((size_t)G * NCHUNK * 512 * 4);
  float* psq   = (float*)alloc((size_t)G * NCHUNK * 512 * 4);
  float* cA    = (float*)alloc((size_t)G * 512 * 4);
  float* cC    = (float*)alloc((size_t)G * 512 * 4);
  unsigned short* WtLR = (unsigned short*)alloc((size_t)1024 * 512 * 2);
  unsigned short* WtTP = (unsigned short*)alloc((size_t)64 * 768 * 2);
  unsigned short* Wt4  = (unsigned short*)alloc((size_t)128 * 512 * 2);
  (void)ws_size; (void)n_in; (void)out_size;

  float* out = (float*)d_out;

  unsigned short* xbf   = xlrb;   // bf16 x [N,768]
  unsigned short* xlr4b = xlrb;   // layer4 combined [N,128]
  unsigned short* yb4   = yb;     // layer4 pre-norm [N,64]

  // ---- CSR build ----
  hipMemsetAsync(cursor, 0, (size_t)N * 4, stream);
  int eblk = (EP + 255) / 256;
  k_count<<<eblk, 256, 0, stream>>>(ei, cursor, E, EP);
  k_scan<<<1, 256, 0, stream>>>(cursor, rowptr, N);
  k_fill<<<eblk, 256, 0, stream>>>(ei, cursor, srcn, E, EP);

  const int mfmaRows = (N + 127) / 128;     // 157
  const int nodeBlocks = (N + 3) / 4;

  // ---- text projection: bf16 MFMA ----
  k_cvt_act<<<(N * TD / 4 + 255) / 256, 256, 0, stream>>>(x, xbf, N * TD / 4);
  k_cvt_wt<<<dim3(2, TD / 32), 256, 0, stream>>>(tp_w, WtTP, TD, 64);
  k_gemm_mfma8<64><<<dim3(1, mfmaRows), 512, 0, stream>>>(xbf, WtTP, tp_b, tp_b, 64, h0h, N, TD, 64);

  auto layer8 = [&](const unsigned short* actbf, int Kin, int l,
                    const unsigned short* resb, int catoff){
    k_cvt_wt2<<<dim3(32, Kin / 32), 256, 0, stream>>>(cw[l][0], cw[l][2], WtLR, Kin, 512);
    k_gemm_mfma8<256><<<dim3(4, mfmaRows), 512, 0, stream>>>(actbf, WtLR, cw[l][1], cw[l][3], 512,
                                                             xlrb, N, Kin, 1024);
    k_gat_fused8<<<nodeBlocks, 256, 0, stream>>>(xlrb, cw[l][4], rowptr, srcn,
                                                 cw[l][5], resb, yb, N);
    k_gnorm_stats<<<dim3(G, 8, NCHUNK), 256, 0, stream>>>(yb, ptrg, psum, psq, 512);
    k_gnorm_coef<<<G, 256, 0, stream>>>(psum, psq, nw[l][0], nw[l][1], nw[l][2], ptrg, cA, cC, 512);
    int total4 = N * 128;
    k_gnorm_apply<<<(total4 + 255) / 256, 256, 0, stream>>>(yb, batch, cA, cC, actA,
                                                            ptrg, cat, catoff, FD,
                                                            512, total4, 1);
  };

  layer8(h0h,  64,  0, nullptr, 0);
  layer8(actA, 512, 1, actA,    512);
  layer8(actA, 512, 2, actA,    1024);

  // ---- layer 4: combined xl|xr MFMA (Ncol=128) + fused edge + gnorm ----
  k_cvt_wt2<<<dim3(4, 16), 256, 0, stream>>>(cw[3][0], cw[3][2], Wt4, 512, 64);
  k_gemm_mfma8<128><<<dim3(1, mfmaRows), 512, 0, stream>>>(actA, Wt4, cw[3][1], cw[3][3], 64,
                                                           xlr4b, N, 512, 128);
  k_gat_fused1<<<nodeBlocks, 256, 0, stream>>>(xlr4b, cw[3][4], rowptr, srcn,
                                               cw[3][5], yb4, N);
  k_gnorm_stats<<<dim3(G, 1, NCHUNK), 256, 0, stream>>>(yb4, ptrg, psum, psq, 64);
  k_gnorm_coef<<<G, 256, 0, stream>>>(psum, psq, nw[3][0], nw[3][1], nw[3][2], ptrg, cA, cC, 64);
  k_gnorm_apply<<<(N * 16 + 255) / 256, 256, 0, stream>>>(yb4, batch, cA, cC, h0h,
                                                          ptrg, cat, 1536, FD,
                                                          64, N * 16, 0);

  k_final<<<G, 256, 0, stream>>>(cat, lin_w, lin_b, out, FD);
}